// Round 1
// baseline (1051.875 us; speedup 1.0000x reference)
//
#include <hip/hip_runtime.h>

#define NVV 50
#define C1 64
#define C2 128
#define C3 512
#define HW1 64
#define HW2 32
#define SS 64
#define HH 64
#define WW 64

// ---------------- conv1: (50,3,128,128) -> relu -> (50,64,64,64), stride 2, SAME (pad_lo=0) ----------------
__global__ __launch_bounds__(256) void conv1_kernel(const float* __restrict__ img,
                                                    const float* __restrict__ w1,
                                                    const float* __restrict__ b1,
                                                    float* __restrict__ out) {
    int ox = threadIdx.x;                      // 64
    int oy = blockIdx.x * 4 + threadIdx.y;     // 16*4 = 64
    int oc = blockIdx.y;                       // 64
    int v  = blockIdx.z;                       // 50
    const float* ip = img + (size_t)v * 3 * 128 * 128;
    const float* wp = w1 + oc * 27;
    float acc = b1[oc];
    #pragma unroll
    for (int ic = 0; ic < 3; ++ic) {
        #pragma unroll
        for (int ky = 0; ky < 3; ++ky) {
            int iy = oy * 2 + ky;
            if (iy < 128) {
                #pragma unroll
                for (int kx = 0; kx < 3; ++kx) {
                    int ix = ox * 2 + kx;
                    if (ix < 128)
                        acc += ip[(ic * 128 + iy) * 128 + ix] * wp[(ic * 3 + ky) * 3 + kx];
                }
            }
        }
    }
    out[(((size_t)v * C1 + oc) * HW1 + oy) * HW1 + ox] = fmaxf(acc, 0.f);
}

// ---------------- conv2: (50,64,64,64) -> relu -> (50,128,32,32), stride 2, SAME (pad_lo=0) ----------------
// block (32,8); each thread computes 4 consecutive oc; weights for those 4 oc in LDS.
__global__ __launch_bounds__(256) void conv2_kernel(const float* __restrict__ in,
                                                    const float* __restrict__ w2,
                                                    const float* __restrict__ b2,
                                                    float* __restrict__ out) {
    __shared__ float wsm[4 * 576];
    int tid = threadIdx.y * 32 + threadIdx.x;
    int oc0 = blockIdx.y * 4;
    for (int i = tid; i < 4 * 576; i += 256) wsm[i] = w2[(size_t)oc0 * 576 + i];
    __syncthreads();
    int ox = threadIdx.x;                    // 32
    int oy = blockIdx.x * 8 + threadIdx.y;   // 4*8 = 32
    int v  = blockIdx.z;                     // 50
    const float* ip = in + (size_t)v * C1 * HW1 * HW1;
    float acc0 = b2[oc0], acc1 = b2[oc0 + 1], acc2 = b2[oc0 + 2], acc3 = b2[oc0 + 3];
    for (int ic = 0; ic < 64; ++ic) {
        #pragma unroll
        for (int ky = 0; ky < 3; ++ky) {
            int iy = oy * 2 + ky;
            if (iy >= 64) continue;
            #pragma unroll
            for (int kx = 0; kx < 3; ++kx) {
                int ix = ox * 2 + kx;
                if (ix >= 64) continue;
                float x = ip[(ic * 64 + iy) * 64 + ix];
                int wi = ic * 9 + ky * 3 + kx;
                acc0 += x * wsm[wi];
                acc1 += x * wsm[576 + wi];
                acc2 += x * wsm[1152 + wi];
                acc3 += x * wsm[1728 + wi];
            }
        }
    }
    size_t ob = (((size_t)v * C2 + oc0) * HW2 + oy) * HW2 + ox;
    out[ob]                 = fmaxf(acc0, 0.f);
    out[ob + 1 * HW2 * HW2] = fmaxf(acc1, 0.f);
    out[ob + 2 * HW2 * HW2] = fmaxf(acc2, 0.f);
    out[ob + 3 * HW2 * HW2] = fmaxf(acc3, 0.f);
}

// ---------------- mean over views: (50,128,32,32) -> (128,32,32) ----------------
__global__ __launch_bounds__(256) void mean_kernel(const float* __restrict__ in, float* __restrict__ out) {
    int i = blockIdx.x * 256 + threadIdx.x;  // 131072 total
    float acc = 0.f;
    for (int v = 0; v < NVV; ++v) acc += in[(size_t)v * C2 * HW2 * HW2 + i];
    out[i] = acc * (1.0f / NVV);
}

// ---------------- conv3: (128,32,32) -> (512,32,32), stride 1, SAME (pad_lo=1), no relu ----------------
__global__ __launch_bounds__(256) void conv3_kernel(const float* __restrict__ in,
                                                    const float* __restrict__ w3,
                                                    const float* __restrict__ b3,
                                                    float* __restrict__ out) {
    __shared__ float wsm[4 * 1152];
    int tid = threadIdx.y * 32 + threadIdx.x;
    int oc0 = blockIdx.y * 4;                // 128 groups
    for (int i = tid; i < 4 * 1152; i += 256) wsm[i] = w3[(size_t)oc0 * 1152 + i];
    __syncthreads();
    int ox = threadIdx.x;
    int oy = blockIdx.x * 8 + threadIdx.y;
    float acc0 = b3[oc0], acc1 = b3[oc0 + 1], acc2 = b3[oc0 + 2], acc3 = b3[oc0 + 3];
    for (int ic = 0; ic < 128; ++ic) {
        #pragma unroll
        for (int ky = 0; ky < 3; ++ky) {
            int iy = oy + ky - 1;
            if (iy < 0 || iy >= 32) continue;
            #pragma unroll
            for (int kx = 0; kx < 3; ++kx) {
                int ix = ox + kx - 1;
                if (ix < 0 || ix >= 32) continue;
                float x = in[(ic * 32 + iy) * 32 + ix];
                int wi = ic * 9 + ky * 3 + kx;
                acc0 += x * wsm[wi];
                acc1 += x * wsm[1152 + wi];
                acc2 += x * wsm[2304 + wi];
                acc3 += x * wsm[3456 + wi];
            }
        }
    }
    size_t ob = ((size_t)oc0 * 32 + oy) * 32 + ox;
    out[ob]            = acc0;
    out[ob + 1 * 1024] = acc1;
    out[ob + 2 * 1024] = acc2;
    out[ob + 3 * 1024] = acc3;
}

// ---------------- fused trilinear interp + 3-layer MLP: -> raw (S,H,W,4) ----------------
__global__ __launch_bounds__(256) void mlp_kernel(const float* __restrict__ vol,   // (16,32,32,32) as (512,32,32)
                                                  const float* __restrict__ rays,  // (8,64,64)
                                                  const float* __restrict__ mw1, const float* __restrict__ mb1,
                                                  const float* __restrict__ mw2, const float* __restrict__ mb2,
                                                  const float* __restrict__ mw3, const float* __restrict__ mb3,
                                                  float* __restrict__ raw) {
    __shared__ float sw1[16 * 64];
    __shared__ float sw2[64 * 64];
    __shared__ float sw3[64 * 4];
    __shared__ float sb1[64], sb2[64], sb3[4];
    int tid = threadIdx.x;
    for (int i = tid; i < 1024; i += 256) sw1[i] = mw1[i];
    for (int i = tid; i < 4096; i += 256) sw2[i] = mw2[i];
    if (tid < 256) sw3[tid] = mw3[tid];
    if (tid < 64) { sb1[tid] = mb1[tid]; sb2[tid] = mb2[tid]; }
    if (tid < 4) sb3[tid] = mb3[tid];
    __syncthreads();

    int n = blockIdx.x * 256 + tid;          // 0 .. 262143 ; n = s*4096 + h*64 + w
    int pix = n & 4095;
    int s = n >> 12;

    float o0 = rays[0 * 4096 + pix], o1 = rays[1 * 4096 + pix], o2 = rays[2 * 4096 + pix];
    float d0 = rays[3 * 4096 + pix], d1 = rays[4 * 4096 + pix], d2 = rays[5 * 4096 + pix];
    float nearv = rays[6 * 4096 + pix], farv = rays[7 * 4096 + pix];
    float t = (float)s / 63.0f;
    float z = nearv + (farv - nearv) * t;
    float px = o0 + d0 * z, py = o1 + d1 * z, pz = o2 + d2 * z;

    float cx = fminf(fmaxf((px + 1.f) * 15.5f, 0.f), 31.f);
    float cy = fminf(fmaxf((py + 1.f) * 15.5f, 0.f), 31.f);
    float cz = fminf(fmaxf((pz + 1.f) * 15.5f, 0.f), 31.f);
    int ix = min((int)floorf(cx), 30);
    int iy = min((int)floorf(cy), 30);
    int iz = min((int)floorf(cz), 30);
    float fx = cx - (float)ix, fy = cy - (float)iy, fz = cz - (float)iz;

    float gx = 1.f - fx, gy = 1.f - fy, gz = 1.f - fz;
    float w000 = gz * gy * gx, w001 = gz * gy * fx, w010 = gz * fy * gx, w011 = gz * fy * fx;
    float w100 = fz * gy * gx, w101 = fz * gy * fx, w110 = fz * fy * gx, w111 = fz * fy * fx;
    int base = (iz * 32 + iy) * 32 + ix;

    float feat[16];
    #pragma unroll
    for (int c = 0; c < 16; ++c) {
        const float* vp = vol + c * 32768 + base;
        feat[c] = w000 * vp[0]      + w001 * vp[1]
                + w010 * vp[32]     + w011 * vp[33]
                + w100 * vp[1024]   + w101 * vp[1025]
                + w110 * vp[1056]   + w111 * vp[1057];
    }

    float h1[64];
    #pragma unroll
    for (int j = 0; j < 64; ++j) {
        float a = sb1[j];
        #pragma unroll
        for (int k = 0; k < 16; ++k) a += feat[k] * sw1[k * 64 + j];
        h1[j] = fmaxf(a, 0.f);
    }
    float h2[64];
    #pragma unroll
    for (int j = 0; j < 64; ++j) {
        float a = sb2[j];
        #pragma unroll
        for (int k = 0; k < 64; ++k) a += h1[k] * sw2[k * 64 + j];
        h2[j] = fmaxf(a, 0.f);
    }
    #pragma unroll
    for (int j = 0; j < 4; ++j) {
        float a = sb3[j];
        #pragma unroll
        for (int k = 0; k < 64; ++k) a += h2[k] * sw3[k * 4 + j];
        raw[(size_t)n * 4 + j] = a;
    }
}

// ---------------- volume rendering: raw (S,H,W,4) -> rgb (3,H,W) + depth (H,W) ----------------
__global__ __launch_bounds__(256) void render_kernel(const float* __restrict__ raw,
                                                     const float* __restrict__ rays,
                                                     float* __restrict__ out) {
    int pix = blockIdx.x * 256 + threadIdx.x;  // 4096
    float nearv = rays[6 * 4096 + pix], farv = rays[7 * 4096 + pix];
    float T = 1.f, r = 0.f, g = 0.f, b = 0.f, d = 0.f;
    float dz = (farv - nearv) * (1.f / 63.f);
    for (int s = 0; s < 64; ++s) {
        float t = (float)s / 63.0f;
        float z = nearv + (farv - nearv) * t;
        const float* rp = raw + ((size_t)(s * 4096) + pix) * 4;
        float r0 = rp[0], r1 = rp[1], r2 = rp[2], r3 = rp[3];
        float delta = (s == 63) ? 1e10f : dz;
        float sigma = fmaxf(r3, 0.f);
        float alpha = 1.f - expf(-sigma * delta);
        float wt = alpha * T;
        r += wt * (1.f / (1.f + expf(-r0)));
        g += wt * (1.f / (1.f + expf(-r1)));
        b += wt * (1.f / (1.f + expf(-r2)));
        d += wt * z;
        T *= (1.f - alpha + 1e-10f);
    }
    out[0 * 4096 + pix] = r;
    out[1 * 4096 + pix] = g;
    out[2 * 4096 + pix] = b;
    out[12288 + pix]    = d;
}

extern "C" void kernel_launch(void* const* d_in, const int* in_sizes, int n_in,
                              void* d_out, int out_size, void* d_ws, size_t ws_size,
                              hipStream_t stream) {
    const float* images = (const float*)d_in[0];
    const float* rays   = (const float*)d_in[1];
    const float* w1 = (const float*)d_in[2];
    const float* b1 = (const float*)d_in[3];
    const float* w2 = (const float*)d_in[4];
    const float* b2 = (const float*)d_in[5];
    const float* w3 = (const float*)d_in[6];
    const float* b3 = (const float*)d_in[7];
    const float* mw1 = (const float*)d_in[8];
    const float* mb1 = (const float*)d_in[9];
    const float* mw2 = (const float*)d_in[10];
    const float* mb2 = (const float*)d_in[11];
    const float* mw3 = (const float*)d_in[12];
    const float* mb3 = (const float*)d_in[13];
    float* out = (float*)d_out;

    float* ws  = (float*)d_ws;
    float* A1  = ws;                    // 50*64*64*64  = 13107200
    float* A2  = A1 + 13107200;         // 50*128*32*32 =  6553600
    float* XB  = A2 + 6553600;          // 128*32*32    =   131072
    float* VOL = XB + 131072;           // 512*32*32    =   524288
    float* RAW = VOL + 524288;          // 64*64*64*4   =  1048576

    conv1_kernel<<<dim3(16, 64, NVV), dim3(64, 4), 0, stream>>>(images, w1, b1, A1);
    conv2_kernel<<<dim3(4, 32, NVV), dim3(32, 8), 0, stream>>>(A1, w2, b2, A2);
    mean_kernel<<<dim3(512), dim3(256), 0, stream>>>(A2, XB);
    conv3_kernel<<<dim3(4, 128), dim3(32, 8), 0, stream>>>(XB, w3, b3, VOL);
    mlp_kernel<<<dim3(1024), dim3(256), 0, stream>>>(VOL, rays, mw1, mb1, mw2, mb2, mw3, mb3, RAW);
    render_kernel<<<dim3(16), dim3(256), 0, stream>>>(RAW, rays, out);
}

// Round 2
// 747.420 us; speedup vs baseline: 1.4073x; 1.4073x over previous
//
#include <hip/hip_runtime.h>
#include <hip/hip_bf16.h>

#define NVV 50
#define C1 64
#define C2 128
#define HW1 64
#define HW2 32

typedef short bf16x8 __attribute__((ext_vector_type(8)));
typedef float f32x4 __attribute__((ext_vector_type(4)));

// ---------------- conv1: (50,3,128,128) -> relu -> channels-last bf16 (50,64,64,64)=(v,y,x,ic) ----------------
__global__ __launch_bounds__(256) void conv1_kernel(const float* __restrict__ img,
                                                    const float* __restrict__ w1,
                                                    const float* __restrict__ b1,
                                                    __hip_bfloat16* __restrict__ out) {
    int oc = threadIdx.x;                      // 64 (lane = oc -> contiguous bf16 writes)
    int ox = blockIdx.x * 4 + threadIdx.y;     // 16*4 = 64
    int oy = blockIdx.y;                       // 64
    int v  = blockIdx.z;                       // 50
    const float* ip = img + (size_t)v * 3 * 128 * 128;
    const float* wp = w1 + oc * 27;
    float acc = b1[oc];
    #pragma unroll
    for (int ic = 0; ic < 3; ++ic) {
        #pragma unroll
        for (int ky = 0; ky < 3; ++ky) {
            int iy = oy * 2 + ky;
            if (iy < 128) {
                #pragma unroll
                for (int kx = 0; kx < 3; ++kx) {
                    int ix = ox * 2 + kx;
                    if (ix < 128)
                        acc += ip[(ic * 128 + iy) * 128 + ix] * wp[(ic * 3 + ky) * 3 + kx];
                }
            }
        }
    }
    out[(((size_t)v * 64 + oy) * 64 + ox) * 64 + oc] = __float2bfloat16(fmaxf(acc, 0.f));
}

// ---------------- one-time weight repack: w2 (128,64,3,3) fp32 -> MFMA A-fragment order bf16 ----------------
// wpack[ ((kk*2+icb)*8 + mtile)*512 + l*8 + j ] = w2[oc=mtile*16+(l&15)][ic=icb*32+(l>>4)*8+j][ky=kk/3][kx=kk%3]
__global__ __launch_bounds__(256) void wpack2_kernel(const float* __restrict__ w2,
                                                     __hip_bfloat16* __restrict__ wpack) {
    int i = blockIdx.x * 256 + threadIdx.x;    // 73728
    int j = i & 7;
    int l = (i >> 3) & 63;
    int rest = i >> 9;
    int mtile = rest & 7;
    rest >>= 3;
    int icb = rest & 1;
    int kk = rest >> 1;                        // 0..8
    int oc = mtile * 16 + (l & 15);
    int ic = icb * 32 + (l >> 4) * 8 + j;
    int ky = kk / 3, kx = kk % 3;
    wpack[i] = __float2bfloat16(w2[((oc * 64 + ic) * 3 + ky) * 3 + kx]);
}

// ---------------- conv2 as implicit GEMM via MFMA: M=128 oc, N=128 px/block, K=576 ----------------
// block = 4 waves (2M x 2N); wave = 64 oc x 64 px; out fp32 NCHW (50,128,32,32) with bias+relu
__global__ __launch_bounds__(256) void conv2_mfma(const __hip_bfloat16* __restrict__ A1c,
                                                  const __hip_bfloat16* __restrict__ wpack,
                                                  const float* __restrict__ b2,
                                                  float* __restrict__ out) {
    int v   = blockIdx.y;
    int oyb = blockIdx.x;                      // 8 row-blocks of 4 output rows
    int tid = threadIdx.x;
    int l = tid & 63;
    int w = tid >> 6;                          // wave 0..3
    int wm = w >> 1, wn = w & 1;
    int lane16 = l & 15, lgrp = l >> 4;

    // per-nf pixel coords (kk-independent)
    int oxv[4], oyv[4];
    #pragma unroll
    for (int nf = 0; nf < 4; ++nf) {
        int px = wn * 64 + nf * 16 + lane16;   // 0..127 within block
        int dy = px >> 5, ox = px & 31;
        oxv[nf] = ox;
        oyv[nf] = oyb * 4 + dy;
    }

    f32x4 acc[4][4];
    #pragma unroll
    for (int mf = 0; mf < 4; ++mf)
        #pragma unroll
        for (int nf = 0; nf < 4; ++nf)
            acc[mf][nf] = (f32x4){0.f, 0.f, 0.f, 0.f};

    const __hip_bfloat16* ibase = A1c + (size_t)v * 64 * 64 * 64;

    for (int kk = 0; kk < 9; ++kk) {
        int ky = kk / 3, kx = kk % 3;
        #pragma unroll
        for (int icb = 0; icb < 2; ++icb) {
            bf16x8 a[4];
            const __hip_bfloat16* wb = wpack + ((size_t)((kk * 2 + icb) * 8 + wm * 4)) * 512 + l * 8;
            #pragma unroll
            for (int mf = 0; mf < 4; ++mf)
                a[mf] = *(const bf16x8*)(wb + mf * 512);

            bf16x8 b[4];
            #pragma unroll
            for (int nf = 0; nf < 4; ++nf) {
                int iy = 2 * oyv[nf] + ky;
                int ix = 2 * oxv[nf] + kx;
                if (iy >= 64 || ix >= 64) {
                    b[nf] = (bf16x8){0, 0, 0, 0, 0, 0, 0, 0};
                } else {
                    b[nf] = *(const bf16x8*)(ibase + ((size_t)(iy * 64 + ix)) * 64 + icb * 32 + lgrp * 8);
                }
            }
            #pragma unroll
            for (int mf = 0; mf < 4; ++mf)
                #pragma unroll
                for (int nf = 0; nf < 4; ++nf)
                    acc[mf][nf] = __builtin_amdgcn_mfma_f32_16x16x32_bf16(a[mf], b[nf], acc[mf][nf], 0, 0, 0);
        }
    }

    // epilogue: C row=(lgrp*4+r), col=lane16
    #pragma unroll
    for (int mf = 0; mf < 4; ++mf) {
        #pragma unroll
        for (int nf = 0; nf < 4; ++nf) {
            int ox = oxv[nf], oy = oyv[nf];
            #pragma unroll
            for (int r = 0; r < 4; ++r) {
                int oc = wm * 64 + mf * 16 + lgrp * 4 + r;
                float val = acc[mf][nf][r] + b2[oc];
                out[(((size_t)v * C2 + oc) * HW2 + oy) * HW2 + ox] = fmaxf(val, 0.f);
            }
        }
    }
}

// ---------------- mean over views: (50,128,32,32) -> (128,32,32) ----------------
__global__ __launch_bounds__(256) void mean_kernel(const float* __restrict__ in, float* __restrict__ out) {
    int i = blockIdx.x * 256 + threadIdx.x;  // 131072 total
    float acc = 0.f;
    for (int v = 0; v < NVV; ++v) acc += in[(size_t)v * C2 * HW2 * HW2 + i];
    out[i] = acc * (1.0f / NVV);
}

// ---------------- conv3: (128,32,32) -> (512,32,32), stride 1, SAME (pad_lo=1), no relu ----------------
__global__ __launch_bounds__(256) void conv3_kernel(const float* __restrict__ in,
                                                    const float* __restrict__ w3,
                                                    const float* __restrict__ b3,
                                                    float* __restrict__ out) {
    __shared__ float wsm[4 * 1152];
    int tid = threadIdx.y * 32 + threadIdx.x;
    int oc0 = blockIdx.y * 4;                // 128 groups
    for (int i = tid; i < 4 * 1152; i += 256) wsm[i] = w3[(size_t)oc0 * 1152 + i];
    __syncthreads();
    int ox = threadIdx.x;
    int oy = blockIdx.x * 8 + threadIdx.y;
    float acc0 = b3[oc0], acc1 = b3[oc0 + 1], acc2 = b3[oc0 + 2], acc3 = b3[oc0 + 3];
    for (int ic = 0; ic < 128; ++ic) {
        #pragma unroll
        for (int ky = 0; ky < 3; ++ky) {
            int iy = oy + ky - 1;
            if (iy < 0 || iy >= 32) continue;
            #pragma unroll
            for (int kx = 0; kx < 3; ++kx) {
                int ix = ox + kx - 1;
                if (ix < 0 || ix >= 32) continue;
                float x = in[(ic * 32 + iy) * 32 + ix];
                int wi = ic * 9 + ky * 3 + kx;
                acc0 += x * wsm[wi];
                acc1 += x * wsm[1152 + wi];
                acc2 += x * wsm[2304 + wi];
                acc3 += x * wsm[3456 + wi];
            }
        }
    }
    size_t ob = ((size_t)oc0 * 32 + oy) * 32 + ox;
    out[ob]            = acc0;
    out[ob + 1 * 1024] = acc1;
    out[ob + 2 * 1024] = acc2;
    out[ob + 3 * 1024] = acc3;
}

// ---------------- fused trilinear interp + 3-layer MLP: -> raw (S,H,W,4) ----------------
__global__ __launch_bounds__(256) void mlp_kernel(const float* __restrict__ vol,   // (16,32,32,32) as (512,32,32)
                                                  const float* __restrict__ rays,  // (8,64,64)
                                                  const float* __restrict__ mw1, const float* __restrict__ mb1,
                                                  const float* __restrict__ mw2, const float* __restrict__ mb2,
                                                  const float* __restrict__ mw3, const float* __restrict__ mb3,
                                                  float* __restrict__ raw) {
    __shared__ float sw1[16 * 64];
    __shared__ float sw2[64 * 64];
    __shared__ float sw3[64 * 4];
    __shared__ float sb1[64], sb2[64], sb3[4];
    int tid = threadIdx.x;
    for (int i = tid; i < 1024; i += 256) sw1[i] = mw1[i];
    for (int i = tid; i < 4096; i += 256) sw2[i] = mw2[i];
    if (tid < 256) sw3[tid] = mw3[tid];
    if (tid < 64) { sb1[tid] = mb1[tid]; sb2[tid] = mb2[tid]; }
    if (tid < 4) sb3[tid] = mb3[tid];
    __syncthreads();

    int n = blockIdx.x * 256 + tid;          // 0 .. 262143 ; n = s*4096 + h*64 + w
    int pix = n & 4095;
    int s = n >> 12;

    float o0 = rays[0 * 4096 + pix], o1 = rays[1 * 4096 + pix], o2 = rays[2 * 4096 + pix];
    float d0 = rays[3 * 4096 + pix], d1 = rays[4 * 4096 + pix], d2 = rays[5 * 4096 + pix];
    float nearv = rays[6 * 4096 + pix], farv = rays[7 * 4096 + pix];
    float t = (float)s / 63.0f;
    float z = nearv + (farv - nearv) * t;
    float px = o0 + d0 * z, py = o1 + d1 * z, pz = o2 + d2 * z;

    float cx = fminf(fmaxf((px + 1.f) * 15.5f, 0.f), 31.f);
    float cy = fminf(fmaxf((py + 1.f) * 15.5f, 0.f), 31.f);
    float cz = fminf(fmaxf((pz + 1.f) * 15.5f, 0.f), 31.f);
    int ix = min((int)floorf(cx), 30);
    int iy = min((int)floorf(cy), 30);
    int iz = min((int)floorf(cz), 30);
    float fx = cx - (float)ix, fy = cy - (float)iy, fz = cz - (float)iz;

    float gx = 1.f - fx, gy = 1.f - fy, gz = 1.f - fz;
    float w000 = gz * gy * gx, w001 = gz * gy * fx, w010 = gz * fy * gx, w011 = gz * fy * fx;
    float w100 = fz * gy * gx, w101 = fz * gy * fx, w110 = fz * fy * gx, w111 = fz * fy * fx;
    int base = (iz * 32 + iy) * 32 + ix;

    float feat[16];
    #pragma unroll
    for (int c = 0; c < 16; ++c) {
        const float* vp = vol + c * 32768 + base;
        feat[c] = w000 * vp[0]      + w001 * vp[1]
                + w010 * vp[32]     + w011 * vp[33]
                + w100 * vp[1024]   + w101 * vp[1025]
                + w110 * vp[1056]   + w111 * vp[1057];
    }

    float h1[64];
    #pragma unroll
    for (int j = 0; j < 64; ++j) {
        float a = sb1[j];
        #pragma unroll
        for (int k = 0; k < 16; ++k) a += feat[k] * sw1[k * 64 + j];
        h1[j] = fmaxf(a, 0.f);
    }
    float h2[64];
    #pragma unroll
    for (int j = 0; j < 64; ++j) {
        float a = sb2[j];
        #pragma unroll
        for (int k = 0; k < 64; ++k) a += h1[k] * sw2[k * 64 + j];
        h2[j] = fmaxf(a, 0.f);
    }
    #pragma unroll
    for (int j = 0; j < 4; ++j) {
        float a = sb3[j];
        #pragma unroll
        for (int k = 0; k < 64; ++k) a += h2[k] * sw3[k * 4 + j];
        raw[(size_t)n * 4 + j] = a;
    }
}

// ---------------- volume rendering: raw (S,H,W,4) -> rgb (3,H,W) + depth (H,W) ----------------
__global__ __launch_bounds__(256) void render_kernel(const float* __restrict__ raw,
                                                     const float* __restrict__ rays,
                                                     float* __restrict__ out) {
    int pix = blockIdx.x * 256 + threadIdx.x;  // 4096
    float nearv = rays[6 * 4096 + pix], farv = rays[7 * 4096 + pix];
    float T = 1.f, r = 0.f, g = 0.f, b = 0.f, d = 0.f;
    float dz = (farv - nearv) * (1.f / 63.f);
    for (int s = 0; s < 64; ++s) {
        float t = (float)s / 63.0f;
        float z = nearv + (farv - nearv) * t;
        const float* rp = raw + ((size_t)(s * 4096) + pix) * 4;
        float r0 = rp[0], r1 = rp[1], r2 = rp[2], r3 = rp[3];
        float delta = (s == 63) ? 1e10f : dz;
        float sigma = fmaxf(r3, 0.f);
        float alpha = 1.f - expf(-sigma * delta);
        float wt = alpha * T;
        r += wt * (1.f / (1.f + expf(-r0)));
        g += wt * (1.f / (1.f + expf(-r1)));
        b += wt * (1.f / (1.f + expf(-r2)));
        d += wt * z;
        T *= (1.f - alpha + 1e-10f);
    }
    out[0 * 4096 + pix] = r;
    out[1 * 4096 + pix] = g;
    out[2 * 4096 + pix] = b;
    out[12288 + pix]    = d;
}

extern "C" void kernel_launch(void* const* d_in, const int* in_sizes, int n_in,
                              void* d_out, int out_size, void* d_ws, size_t ws_size,
                              hipStream_t stream) {
    const float* images = (const float*)d_in[0];
    const float* rays   = (const float*)d_in[1];
    const float* w1 = (const float*)d_in[2];
    const float* b1 = (const float*)d_in[3];
    const float* w2 = (const float*)d_in[4];
    const float* b2 = (const float*)d_in[5];
    const float* w3 = (const float*)d_in[6];
    const float* b3 = (const float*)d_in[7];
    const float* mw1 = (const float*)d_in[8];
    const float* mb1 = (const float*)d_in[9];
    const float* mw2 = (const float*)d_in[10];
    const float* mb2 = (const float*)d_in[11];
    const float* mw3 = (const float*)d_in[12];
    const float* mb3 = (const float*)d_in[13];
    float* out = (float*)d_out;

    // workspace layout (fp32 region first, then bf16 region; all 16B-aligned)
    float* ws  = (float*)d_ws;
    float* A2  = ws;                    // 50*128*32*32 = 6553600 f
    float* XB  = A2 + 6553600;          // 128*32*32    =  131072 f
    float* VOL = XB + 131072;           // 512*32*32    =  524288 f
    float* RAW = VOL + 524288;          // 64*64*64*4   = 1048576 f
    __hip_bfloat16* A1c   = (__hip_bfloat16*)(RAW + 1048576);  // 50*64*64*64 = 13107200 bf16
    __hip_bfloat16* WPK   = A1c + 13107200;                    // 73728 bf16

    wpack2_kernel<<<dim3(288), dim3(256), 0, stream>>>(w2, WPK);
    conv1_kernel<<<dim3(16, 64, NVV), dim3(64, 4), 0, stream>>>(images, w1, b1, A1c);
    conv2_mfma<<<dim3(8, NVV), dim3(256), 0, stream>>>(A1c, WPK, b2, A2);
    mean_kernel<<<dim3(512), dim3(256), 0, stream>>>(A2, XB);
    conv3_kernel<<<dim3(4, 128), dim3(32, 8), 0, stream>>>(XB, w3, b3, VOL);
    mlp_kernel<<<dim3(1024), dim3(256), 0, stream>>>(VOL, rays, mw1, mb1, mw2, mb2, mw3, mb3, RAW);
    render_kernel<<<dim3(16), dim3(256), 0, stream>>>(RAW, rays, out);
}

// Round 3
// 474.563 us; speedup vs baseline: 2.2165x; 1.5750x over previous
//
#include <hip/hip_runtime.h>
#include <hip/hip_bf16.h>

#define NVV 50
#define C1 64
#define C2 128
#define HW1 64
#define HW2 32

typedef short bf16x8 __attribute__((ext_vector_type(8)));
typedef short s16x4 __attribute__((ext_vector_type(4)));
typedef float f32x4 __attribute__((ext_vector_type(4)));

__device__ inline short f2bf(float x) {
    unsigned u = __builtin_bit_cast(unsigned, x);
    unsigned r = (u + 0x7FFFu + ((u >> 16) & 1u)) >> 16;
    return (short)r;
}

// ---------------- im2col for conv1: (50,3,128,128) fp32 -> (204800 px, 32 K) bf16 ----------------
// k = ic*9 + ky*3 + kx (k<27), pad 27..31 with 0. pixel p = v*4096 + oy*64 + ox.
__global__ __launch_bounds__(256) void im2col1_kernel(const float* __restrict__ img,
                                                      __hip_bfloat16* __restrict__ IM) {
    int p = blockIdx.x * 256 + threadIdx.x;   // 204800
    int v = p >> 12;
    int rem = p & 4095;
    int oy = rem >> 6, ox = rem & 63;
    const float* ip = img + (size_t)v * 3 * 128 * 128;
    bf16x8 ov[4];
    #pragma unroll
    for (int k = 0; k < 32; ++k) {
        float x = 0.f;
        if (k < 27) {
            int ic = k / 9, r = k % 9;
            int ky = r / 3, kx = r % 3;
            int iy = 2 * oy + ky, ix = 2 * ox + kx;
            if (iy < 128 && ix < 128) x = ip[(ic * 128 + iy) * 128 + ix];
        }
        ov[k >> 3][k & 7] = f2bf(x);
    }
    bf16x8* op = (bf16x8*)((short*)IM + (size_t)p * 32);
    #pragma unroll
    for (int q = 0; q < 4; ++q) op[q] = ov[q];
}

// ---------------- one-time weight repack: w1 (64,3,3,3) -> A-frag order bf16 [mtile4][lane64][8] ----------------
__global__ __launch_bounds__(256) void wpack1_kernel(const float* __restrict__ w1,
                                                     __hip_bfloat16* __restrict__ wpack) {
    int i = blockIdx.x * 256 + threadIdx.x;   // 2048
    int j = i & 7;
    int l = (i >> 3) & 63;
    int mf = i >> 9;
    int oc = mf * 16 + (l & 15);
    int k = (l >> 4) * 8 + j;
    wpack[i] = __float2bfloat16(k < 27 ? w1[oc * 27 + k] : 0.f);
}

// ---------------- conv1 as GEMM: M=64 oc, K=32, N=204800 px; block = 4 waves x 64 px ----------------
__global__ __launch_bounds__(256) void conv1_mfma(const __hip_bfloat16* __restrict__ IM,
                                                  const __hip_bfloat16* __restrict__ wpack,
                                                  const float* __restrict__ b1,
                                                  __hip_bfloat16* __restrict__ out) {
    int tid = threadIdx.x;
    int l = tid & 63;
    int w = tid >> 6;
    int lane16 = l & 15, lgrp = l >> 4;
    int px0 = blockIdx.x * 256 + w * 64;

    bf16x8 a[4];
    #pragma unroll
    for (int mf = 0; mf < 4; ++mf)
        a[mf] = *(const bf16x8*)((const short*)wpack + (mf * 64 + l) * 8);

    f32x4 acc[4][4];
    #pragma unroll
    for (int mf = 0; mf < 4; ++mf)
        #pragma unroll
        for (int nf = 0; nf < 4; ++nf)
            acc[mf][nf] = (f32x4){0.f, 0.f, 0.f, 0.f};

    #pragma unroll
    for (int nf = 0; nf < 4; ++nf) {
        bf16x8 b = *(const bf16x8*)((const short*)IM + (size_t)(px0 + nf * 16 + lane16) * 32 + lgrp * 8);
        #pragma unroll
        for (int mf = 0; mf < 4; ++mf)
            acc[mf][nf] = __builtin_amdgcn_mfma_f32_16x16x32_bf16(a[mf], b, acc[mf][nf], 0, 0, 0);
    }

    // C mapping: col(px)=lane16, row(oc within tile)=lgrp*4+r
    #pragma unroll
    for (int mf = 0; mf < 4; ++mf) {
        #pragma unroll
        for (int nf = 0; nf < 4; ++nf) {
            int px = px0 + nf * 16 + lane16;
            s16x4 sv;
            #pragma unroll
            for (int r = 0; r < 4; ++r) {
                int oc = mf * 16 + lgrp * 4 + r;
                sv[r] = f2bf(fmaxf(acc[mf][nf][r] + b1[oc], 0.f));
            }
            *(s16x4*)((short*)out + (size_t)px * 64 + mf * 16 + lgrp * 4) = sv;
        }
    }
}

// ---------------- one-time weight repack: w2 (128,64,3,3) fp32 -> MFMA A-fragment order bf16 ----------------
__global__ __launch_bounds__(256) void wpack2_kernel(const float* __restrict__ w2,
                                                     __hip_bfloat16* __restrict__ wpack) {
    int i = blockIdx.x * 256 + threadIdx.x;    // 73728
    int j = i & 7;
    int l = (i >> 3) & 63;
    int rest = i >> 9;
    int mtile = rest & 7;
    rest >>= 3;
    int icb = rest & 1;
    int kk = rest >> 1;                        // 0..8
    int oc = mtile * 16 + (l & 15);
    int ic = icb * 32 + (l >> 4) * 8 + j;
    int ky = kk / 3, kx = kk % 3;
    wpack[i] = __float2bfloat16(w2[((oc * 64 + ic) * 3 + ky) * 3 + kx]);
}

// ---------------- conv2 as implicit GEMM via MFMA: M=128 oc, N=128 px/block, K=576 ----------------
__global__ __launch_bounds__(256) void conv2_mfma(const __hip_bfloat16* __restrict__ A1c,
                                                  const __hip_bfloat16* __restrict__ wpack,
                                                  const float* __restrict__ b2,
                                                  float* __restrict__ out) {
    int v   = blockIdx.y;
    int oyb = blockIdx.x;                      // 8 row-blocks of 4 output rows
    int tid = threadIdx.x;
    int l = tid & 63;
    int w = tid >> 6;                          // wave 0..3
    int wm = w >> 1, wn = w & 1;
    int lane16 = l & 15, lgrp = l >> 4;

    int oxv[4], oyv[4];
    #pragma unroll
    for (int nf = 0; nf < 4; ++nf) {
        int px = wn * 64 + nf * 16 + lane16;   // 0..127 within block
        int dy = px >> 5, ox = px & 31;
        oxv[nf] = ox;
        oyv[nf] = oyb * 4 + dy;
    }

    f32x4 acc[4][4];
    #pragma unroll
    for (int mf = 0; mf < 4; ++mf)
        #pragma unroll
        for (int nf = 0; nf < 4; ++nf)
            acc[mf][nf] = (f32x4){0.f, 0.f, 0.f, 0.f};

    const __hip_bfloat16* ibase = A1c + (size_t)v * 64 * 64 * 64;

    for (int kk = 0; kk < 9; ++kk) {
        int ky = kk / 3, kx = kk % 3;
        #pragma unroll
        for (int icb = 0; icb < 2; ++icb) {
            bf16x8 a[4];
            const __hip_bfloat16* wb = wpack + ((size_t)((kk * 2 + icb) * 8 + wm * 4)) * 512 + l * 8;
            #pragma unroll
            for (int mf = 0; mf < 4; ++mf)
                a[mf] = *(const bf16x8*)(wb + mf * 512);

            bf16x8 b[4];
            #pragma unroll
            for (int nf = 0; nf < 4; ++nf) {
                int iy = 2 * oyv[nf] + ky;
                int ix = 2 * oxv[nf] + kx;
                if (iy >= 64 || ix >= 64) {
                    b[nf] = (bf16x8){0, 0, 0, 0, 0, 0, 0, 0};
                } else {
                    b[nf] = *(const bf16x8*)(ibase + ((size_t)(iy * 64 + ix)) * 64 + icb * 32 + lgrp * 8);
                }
            }
            #pragma unroll
            for (int mf = 0; mf < 4; ++mf)
                #pragma unroll
                for (int nf = 0; nf < 4; ++nf)
                    acc[mf][nf] = __builtin_amdgcn_mfma_f32_16x16x32_bf16(a[mf], b[nf], acc[mf][nf], 0, 0, 0);
        }
    }

    #pragma unroll
    for (int mf = 0; mf < 4; ++mf) {
        #pragma unroll
        for (int nf = 0; nf < 4; ++nf) {
            int ox = oxv[nf], oy = oyv[nf];
            #pragma unroll
            for (int r = 0; r < 4; ++r) {
                int oc = wm * 64 + mf * 16 + lgrp * 4 + r;
                float val = acc[mf][nf][r] + b2[oc];
                out[(((size_t)v * C2 + oc) * HW2 + oy) * HW2 + ox] = fmaxf(val, 0.f);
            }
        }
    }
}

// ---------------- mean over views: (50,128,32,32) -> (128,32,32) ----------------
__global__ __launch_bounds__(256) void mean_kernel(const float* __restrict__ in, float* __restrict__ out) {
    int i = blockIdx.x * 256 + threadIdx.x;  // 131072 total
    float acc = 0.f;
    for (int v = 0; v < NVV; ++v) acc += in[(size_t)v * C2 * HW2 * HW2 + i];
    out[i] = acc * (1.0f / NVV);
}

// ---------------- conv3: (128,32,32) -> (512,32,32), stride 1, SAME (pad_lo=1), no relu ----------------
// weights packed transposed into LDS as f32x4 over the 4 oc of this block
__global__ __launch_bounds__(256) void conv3_kernel(const float* __restrict__ in,
                                                    const float* __restrict__ w3,
                                                    const float* __restrict__ b3,
                                                    float* __restrict__ out) {
    __shared__ f32x4 wsm4[1152];
    int tid = threadIdx.y * 32 + threadIdx.x;
    int oc0 = blockIdx.y * 4;                // 128 groups
    for (int i = tid; i < 1152; i += 256) {
        f32x4 wv;
        wv[0] = w3[(size_t)(oc0 + 0) * 1152 + i];
        wv[1] = w3[(size_t)(oc0 + 1) * 1152 + i];
        wv[2] = w3[(size_t)(oc0 + 2) * 1152 + i];
        wv[3] = w3[(size_t)(oc0 + 3) * 1152 + i];
        wsm4[i] = wv;
    }
    __syncthreads();
    int ox = threadIdx.x;
    int oy = blockIdx.x * 8 + threadIdx.y;
    f32x4 acc;
    acc[0] = b3[oc0]; acc[1] = b3[oc0 + 1]; acc[2] = b3[oc0 + 2]; acc[3] = b3[oc0 + 3];
    for (int ic = 0; ic < 128; ++ic) {
        #pragma unroll
        for (int ky = 0; ky < 3; ++ky) {
            int iy = oy + ky - 1;
            if (iy < 0 || iy >= 32) continue;
            #pragma unroll
            for (int kx = 0; kx < 3; ++kx) {
                int ix = ox + kx - 1;
                if (ix < 0 || ix >= 32) continue;
                float x = in[(ic * 32 + iy) * 32 + ix];
                acc += x * wsm4[ic * 9 + ky * 3 + kx];
            }
        }
    }
    size_t ob = ((size_t)oc0 * 32 + oy) * 32 + ox;
    out[ob]            = acc[0];
    out[ob + 1 * 1024] = acc[1];
    out[ob + 2 * 1024] = acc[2];
    out[ob + 3 * 1024] = acc[3];
}

// ---------------- fused trilinear interp + 3-layer MLP: -> raw (S,H,W,4) ----------------
__global__ __launch_bounds__(256) void mlp_kernel(const float* __restrict__ vol,   // (16,32,32,32) as (512,32,32)
                                                  const float* __restrict__ rays,  // (8,64,64)
                                                  const float* __restrict__ mw1, const float* __restrict__ mb1,
                                                  const float* __restrict__ mw2, const float* __restrict__ mb2,
                                                  const float* __restrict__ mw3, const float* __restrict__ mb3,
                                                  float* __restrict__ raw) {
    __shared__ f32x4 sw1v[256];   // [k16][jv16]
    __shared__ f32x4 sw2v[1024];  // [k64][jv16]
    __shared__ f32x4 sw3v[64];    // [k64]
    __shared__ f32x4 sb1v[16], sb2v[16], sb3v[1];
    int tid = threadIdx.x;
    {
        float* p1 = (float*)sw1v;
        for (int i = tid; i < 1024; i += 256) p1[i] = mw1[i];
        float* p2 = (float*)sw2v;
        for (int i = tid; i < 4096; i += 256) p2[i] = mw2[i];
        float* p3 = (float*)sw3v;
        if (tid < 256) p3[tid] = mw3[tid];
        float* pb1 = (float*)sb1v;
        float* pb2 = (float*)sb2v;
        if (tid < 64) { pb1[tid] = mb1[tid]; pb2[tid] = mb2[tid]; }
        float* pb3 = (float*)sb3v;
        if (tid < 4) pb3[tid] = mb3[tid];
    }
    __syncthreads();

    int n = blockIdx.x * 256 + tid;          // 0 .. 262143 ; n = s*4096 + h*64 + w
    int pix = n & 4095;
    int s = n >> 12;

    float o0 = rays[0 * 4096 + pix], o1 = rays[1 * 4096 + pix], o2 = rays[2 * 4096 + pix];
    float d0 = rays[3 * 4096 + pix], d1 = rays[4 * 4096 + pix], d2 = rays[5 * 4096 + pix];
    float nearv = rays[6 * 4096 + pix], farv = rays[7 * 4096 + pix];
    float t = (float)s / 63.0f;
    float z = nearv + (farv - nearv) * t;
    float px = o0 + d0 * z, py = o1 + d1 * z, pz = o2 + d2 * z;

    float cx = fminf(fmaxf((px + 1.f) * 15.5f, 0.f), 31.f);
    float cy = fminf(fmaxf((py + 1.f) * 15.5f, 0.f), 31.f);
    float cz = fminf(fmaxf((pz + 1.f) * 15.5f, 0.f), 31.f);
    int ix = min((int)floorf(cx), 30);
    int iy = min((int)floorf(cy), 30);
    int iz = min((int)floorf(cz), 30);
    float fx = cx - (float)ix, fy = cy - (float)iy, fz = cz - (float)iz;

    float gx = 1.f - fx, gy = 1.f - fy, gz = 1.f - fz;
    float w000 = gz * gy * gx, w001 = gz * gy * fx, w010 = gz * fy * gx, w011 = gz * fy * fx;
    float w100 = fz * gy * gx, w101 = fz * gy * fx, w110 = fz * fy * gx, w111 = fz * fy * fx;
    int base = (iz * 32 + iy) * 32 + ix;

    float feat[16];
    #pragma unroll
    for (int c = 0; c < 16; ++c) {
        const float* vp = vol + c * 32768 + base;
        feat[c] = w000 * vp[0]      + w001 * vp[1]
                + w010 * vp[32]     + w011 * vp[33]
                + w100 * vp[1024]   + w101 * vp[1025]
                + w110 * vp[1056]   + w111 * vp[1057];
    }

    float h1[64];
    #pragma unroll
    for (int jv = 0; jv < 16; ++jv) {
        f32x4 a = sb1v[jv];
        #pragma unroll
        for (int k = 0; k < 16; ++k) a += feat[k] * sw1v[k * 16 + jv];
        h1[jv * 4 + 0] = fmaxf(a[0], 0.f);
        h1[jv * 4 + 1] = fmaxf(a[1], 0.f);
        h1[jv * 4 + 2] = fmaxf(a[2], 0.f);
        h1[jv * 4 + 3] = fmaxf(a[3], 0.f);
    }
    float h2[64];
    #pragma unroll
    for (int jv = 0; jv < 16; ++jv) {
        f32x4 a = sb2v[jv];
        #pragma unroll
        for (int k = 0; k < 64; ++k) a += h1[k] * sw2v[k * 16 + jv];
        h2[jv * 4 + 0] = fmaxf(a[0], 0.f);
        h2[jv * 4 + 1] = fmaxf(a[1], 0.f);
        h2[jv * 4 + 2] = fmaxf(a[2], 0.f);
        h2[jv * 4 + 3] = fmaxf(a[3], 0.f);
    }
    f32x4 o = sb3v[0];
    #pragma unroll
    for (int k = 0; k < 64; ++k) o += h2[k] * sw3v[k];
    *(f32x4*)(raw + (size_t)n * 4) = o;
}

// ---------------- volume rendering: raw (S,H,W,4) -> rgb (3,H,W) + depth (H,W) ----------------
__global__ __launch_bounds__(256) void render_kernel(const float* __restrict__ raw,
                                                     const float* __restrict__ rays,
                                                     float* __restrict__ out) {
    int pix = blockIdx.x * 256 + threadIdx.x;  // 4096
    float nearv = rays[6 * 4096 + pix], farv = rays[7 * 4096 + pix];
    float T = 1.f, r = 0.f, g = 0.f, b = 0.f, d = 0.f;
    float dz = (farv - nearv) * (1.f / 63.f);
    for (int s = 0; s < 64; ++s) {
        float t = (float)s / 63.0f;
        float z = nearv + (farv - nearv) * t;
        const float* rp = raw + ((size_t)(s * 4096) + pix) * 4;
        float r0 = rp[0], r1 = rp[1], r2 = rp[2], r3 = rp[3];
        float delta = (s == 63) ? 1e10f : dz;
        float sigma = fmaxf(r3, 0.f);
        float alpha = 1.f - expf(-sigma * delta);
        float wt = alpha * T;
        r += wt * (1.f / (1.f + expf(-r0)));
        g += wt * (1.f / (1.f + expf(-r1)));
        b += wt * (1.f / (1.f + expf(-r2)));
        d += wt * z;
        T *= (1.f - alpha + 1e-10f);
    }
    out[0 * 4096 + pix] = r;
    out[1 * 4096 + pix] = g;
    out[2 * 4096 + pix] = b;
    out[12288 + pix]    = d;
}

extern "C" void kernel_launch(void* const* d_in, const int* in_sizes, int n_in,
                              void* d_out, int out_size, void* d_ws, size_t ws_size,
                              hipStream_t stream) {
    const float* images = (const float*)d_in[0];
    const float* rays   = (const float*)d_in[1];
    const float* w1 = (const float*)d_in[2];
    const float* b1 = (const float*)d_in[3];
    const float* w2 = (const float*)d_in[4];
    const float* b2 = (const float*)d_in[5];
    const float* w3 = (const float*)d_in[6];
    const float* b3 = (const float*)d_in[7];
    const float* mw1 = (const float*)d_in[8];
    const float* mb1 = (const float*)d_in[9];
    const float* mw2 = (const float*)d_in[10];
    const float* mb2 = (const float*)d_in[11];
    const float* mw3 = (const float*)d_in[12];
    const float* mb3 = (const float*)d_in[13];
    float* out = (float*)d_out;

    // workspace layout (fp32 region first, then bf16 region; all 16B-aligned)
    float* ws  = (float*)d_ws;
    float* A2  = ws;                    // 50*128*32*32 = 6553600 f
    float* XB  = A2 + 6553600;          // 128*32*32    =  131072 f
    float* VOL = XB + 131072;           // 512*32*32    =  524288 f
    float* RAW = VOL + 524288;          // 64*64*64*4   = 1048576 f
    __hip_bfloat16* A1c  = (__hip_bfloat16*)(RAW + 1048576);  // 50*64*64*64 = 13107200 bf16
    __hip_bfloat16* WPK2 = A1c + 13107200;                    // 73728 bf16
    __hip_bfloat16* WPK1 = WPK2 + 73728;                      // 2048 bf16
    __hip_bfloat16* IM   = WPK1 + 2048;                       // 204800*32 = 6553600 bf16

    wpack2_kernel<<<dim3(288), dim3(256), 0, stream>>>(w2, WPK2);
    wpack1_kernel<<<dim3(8), dim3(256), 0, stream>>>(w1, WPK1);
    im2col1_kernel<<<dim3(800), dim3(256), 0, stream>>>(images, IM);
    conv1_mfma<<<dim3(800), dim3(256), 0, stream>>>(IM, WPK1, b1, A1c);
    conv2_mfma<<<dim3(8, NVV), dim3(256), 0, stream>>>(A1c, WPK2, b2, A2);
    mean_kernel<<<dim3(512), dim3(256), 0, stream>>>(A2, XB);
    conv3_kernel<<<dim3(4, 128), dim3(32, 8), 0, stream>>>(XB, w3, b3, VOL);
    mlp_kernel<<<dim3(1024), dim3(256), 0, stream>>>(VOL, rays, mw1, mb1, mw2, mb2, mw3, mb3, RAW);
    render_kernel<<<dim3(16), dim3(256), 0, stream>>>(RAW, rays, out);
}

// Round 4
// 268.807 us; speedup vs baseline: 3.9131x; 1.7654x over previous
//
#include <hip/hip_runtime.h>
#include <hip/hip_bf16.h>

#define NVV 50
#define C1 64
#define C2 128
#define HW1 64
#define HW2 32

typedef short bf16x8 __attribute__((ext_vector_type(8)));
typedef short s16x4 __attribute__((ext_vector_type(4)));
typedef float f32x4 __attribute__((ext_vector_type(4)));
typedef int i32x4 __attribute__((ext_vector_type(4)));

__device__ inline short f2bf(float x) {
    unsigned u = __builtin_bit_cast(unsigned, x);
    unsigned r = (u + 0x7FFFu + ((u >> 16) & 1u)) >> 16;
    return (short)r;
}
__device__ inline float bf2f(short x) {
    unsigned u = ((unsigned)(unsigned short)x) << 16;
    return __builtin_bit_cast(float, u);
}

// ---------------- im2col for conv1: (50,3,128,128) fp32 -> (204800 px, 32 K) bf16 ----------------
__global__ __launch_bounds__(256) void im2col1_kernel(const float* __restrict__ img,
                                                      __hip_bfloat16* __restrict__ IM) {
    int p = blockIdx.x * 256 + threadIdx.x;   // 204800
    int v = p >> 12;
    int rem = p & 4095;
    int oy = rem >> 6, ox = rem & 63;
    const float* ip = img + (size_t)v * 3 * 128 * 128;
    bf16x8 ov[4];
    #pragma unroll
    for (int k = 0; k < 32; ++k) {
        float x = 0.f;
        if (k < 27) {
            int ic = k / 9, r = k % 9;
            int ky = r / 3, kx = r % 3;
            int iy = 2 * oy + ky, ix = 2 * ox + kx;
            if (iy < 128 && ix < 128) x = ip[(ic * 128 + iy) * 128 + ix];
        }
        ov[k >> 3][k & 7] = f2bf(x);
    }
    bf16x8* op = (bf16x8*)((short*)IM + (size_t)p * 32);
    #pragma unroll
    for (int q = 0; q < 4; ++q) op[q] = ov[q];
}

// ---------------- w1 repack -> A-frag order bf16 [mtile4][lane64][8] ----------------
__global__ __launch_bounds__(256) void wpack1_kernel(const float* __restrict__ w1,
                                                     __hip_bfloat16* __restrict__ wpack) {
    int i = blockIdx.x * 256 + threadIdx.x;   // 2048
    int j = i & 7;
    int l = (i >> 3) & 63;
    int mf = i >> 9;
    int oc = mf * 16 + (l & 15);
    int k = (l >> 4) * 8 + j;
    wpack[i] = __float2bfloat16(k < 27 ? w1[oc * 27 + k] : 0.f);
}

// ---------------- conv1 as GEMM: M=64 oc, K=32, N=204800 px ----------------
__global__ __launch_bounds__(256) void conv1_mfma(const __hip_bfloat16* __restrict__ IM,
                                                  const __hip_bfloat16* __restrict__ wpack,
                                                  const float* __restrict__ b1,
                                                  __hip_bfloat16* __restrict__ out) {
    int tid = threadIdx.x;
    int l = tid & 63;
    int w = tid >> 6;
    int lane16 = l & 15, lgrp = l >> 4;
    int px0 = blockIdx.x * 256 + w * 64;

    bf16x8 a[4];
    #pragma unroll
    for (int mf = 0; mf < 4; ++mf)
        a[mf] = *(const bf16x8*)((const short*)wpack + (mf * 64 + l) * 8);

    f32x4 acc[4][4];
    #pragma unroll
    for (int mf = 0; mf < 4; ++mf)
        #pragma unroll
        for (int nf = 0; nf < 4; ++nf)
            acc[mf][nf] = (f32x4){0.f, 0.f, 0.f, 0.f};

    #pragma unroll
    for (int nf = 0; nf < 4; ++nf) {
        bf16x8 b = *(const bf16x8*)((const short*)IM + (size_t)(px0 + nf * 16 + lane16) * 32 + lgrp * 8);
        #pragma unroll
        for (int mf = 0; mf < 4; ++mf)
            acc[mf][nf] = __builtin_amdgcn_mfma_f32_16x16x32_bf16(a[mf], b, acc[mf][nf], 0, 0, 0);
    }

    #pragma unroll
    for (int mf = 0; mf < 4; ++mf) {
        #pragma unroll
        for (int nf = 0; nf < 4; ++nf) {
            int px = px0 + nf * 16 + lane16;
            s16x4 sv;
            #pragma unroll
            for (int r = 0; r < 4; ++r) {
                int oc = mf * 16 + lgrp * 4 + r;
                sv[r] = f2bf(fmaxf(acc[mf][nf][r] + b1[oc], 0.f));
            }
            *(s16x4*)((short*)out + (size_t)px * 64 + mf * 16 + lgrp * 4) = sv;
        }
    }
}

// ---------------- w2 repack -> MFMA A-fragment order bf16 ----------------
__global__ __launch_bounds__(256) void wpack2_kernel(const float* __restrict__ w2,
                                                     __hip_bfloat16* __restrict__ wpack) {
    int i = blockIdx.x * 256 + threadIdx.x;    // 73728
    int j = i & 7;
    int l = (i >> 3) & 63;
    int rest = i >> 9;
    int mtile = rest & 7;
    rest >>= 3;
    int icb = rest & 1;
    int kk = rest >> 1;                        // 0..8
    int oc = mtile * 16 + (l & 15);
    int ic = icb * 32 + (l >> 4) * 8 + j;
    int ky = kk / 3, kx = kk % 3;
    wpack[i] = __float2bfloat16(w2[((oc * 64 + ic) * 3 + ky) * 3 + kx]);
}

// ---------------- conv2 implicit GEMM: M=128 oc, N=128 px/block, K=576 ----------------
__global__ __launch_bounds__(256) void conv2_mfma(const __hip_bfloat16* __restrict__ A1c,
                                                  const __hip_bfloat16* __restrict__ wpack,
                                                  const float* __restrict__ b2,
                                                  float* __restrict__ out) {
    int v   = blockIdx.y;
    int oyb = blockIdx.x;
    int tid = threadIdx.x;
    int l = tid & 63;
    int w = tid >> 6;
    int wm = w >> 1, wn = w & 1;
    int lane16 = l & 15, lgrp = l >> 4;

    int oxv[4], oyv[4];
    #pragma unroll
    for (int nf = 0; nf < 4; ++nf) {
        int px = wn * 64 + nf * 16 + lane16;
        int dy = px >> 5, ox = px & 31;
        oxv[nf] = ox;
        oyv[nf] = oyb * 4 + dy;
    }

    f32x4 acc[4][4];
    #pragma unroll
    for (int mf = 0; mf < 4; ++mf)
        #pragma unroll
        for (int nf = 0; nf < 4; ++nf)
            acc[mf][nf] = (f32x4){0.f, 0.f, 0.f, 0.f};

    const __hip_bfloat16* ibase = A1c + (size_t)v * 64 * 64 * 64;

    for (int kk = 0; kk < 9; ++kk) {
        int ky = kk / 3, kx = kk % 3;
        #pragma unroll
        for (int icb = 0; icb < 2; ++icb) {
            bf16x8 a[4];
            const __hip_bfloat16* wb = wpack + ((size_t)((kk * 2 + icb) * 8 + wm * 4)) * 512 + l * 8;
            #pragma unroll
            for (int mf = 0; mf < 4; ++mf)
                a[mf] = *(const bf16x8*)(wb + mf * 512);

            bf16x8 b[4];
            #pragma unroll
            for (int nf = 0; nf < 4; ++nf) {
                int iy = 2 * oyv[nf] + ky;
                int ix = 2 * oxv[nf] + kx;
                if (iy >= 64 || ix >= 64) {
                    b[nf] = (bf16x8){0, 0, 0, 0, 0, 0, 0, 0};
                } else {
                    b[nf] = *(const bf16x8*)(ibase + ((size_t)(iy * 64 + ix)) * 64 + icb * 32 + lgrp * 8);
                }
            }
            #pragma unroll
            for (int mf = 0; mf < 4; ++mf)
                #pragma unroll
                for (int nf = 0; nf < 4; ++nf)
                    acc[mf][nf] = __builtin_amdgcn_mfma_f32_16x16x32_bf16(a[mf], b[nf], acc[mf][nf], 0, 0, 0);
        }
    }

    #pragma unroll
    for (int mf = 0; mf < 4; ++mf) {
        #pragma unroll
        for (int nf = 0; nf < 4; ++nf) {
            int ox = oxv[nf], oy = oyv[nf];
            #pragma unroll
            for (int r = 0; r < 4; ++r) {
                int oc = wm * 64 + mf * 16 + lgrp * 4 + r;
                float val = acc[mf][nf][r] + b2[oc];
                out[(((size_t)v * C2 + oc) * HW2 + oy) * HW2 + ox] = fmaxf(val, 0.f);
            }
        }
    }
}

// ---------------- mean over views ----------------
__global__ __launch_bounds__(256) void mean_kernel(const float* __restrict__ in, float* __restrict__ out) {
    int i = blockIdx.x * 256 + threadIdx.x;
    float acc = 0.f;
    for (int v = 0; v < NVV; ++v) acc += in[(size_t)v * C2 * HW2 * HW2 + i];
    out[i] = acc * (1.0f / NVV);
}

// ---------------- conv3: (128,32,32) -> channels-last bf16 VOLc[(z*32+y)*32+x][16] ----------------
__global__ __launch_bounds__(256) void conv3_kernel(const float* __restrict__ in,
                                                    const float* __restrict__ w3,
                                                    const float* __restrict__ b3,
                                                    __hip_bfloat16* __restrict__ VOLc) {
    __shared__ f32x4 wsm4[1152];
    int tid = threadIdx.y * 32 + threadIdx.x;
    int oc0 = blockIdx.y * 4;
    for (int i = tid; i < 1152; i += 256) {
        f32x4 wv;
        wv[0] = w3[(size_t)(oc0 + 0) * 1152 + i];
        wv[1] = w3[(size_t)(oc0 + 1) * 1152 + i];
        wv[2] = w3[(size_t)(oc0 + 2) * 1152 + i];
        wv[3] = w3[(size_t)(oc0 + 3) * 1152 + i];
        wsm4[i] = wv;
    }
    __syncthreads();
    int ox = threadIdx.x;
    int oy = blockIdx.x * 8 + threadIdx.y;
    f32x4 acc;
    acc[0] = b3[oc0]; acc[1] = b3[oc0 + 1]; acc[2] = b3[oc0 + 2]; acc[3] = b3[oc0 + 3];
    for (int ic = 0; ic < 128; ++ic) {
        #pragma unroll
        for (int ky = 0; ky < 3; ++ky) {
            int iy = oy + ky - 1;
            if (iy < 0 || iy >= 32) continue;
            #pragma unroll
            for (int kx = 0; kx < 3; ++kx) {
                int ix = ox + kx - 1;
                if (ix < 0 || ix >= 32) continue;
                float x = in[(ic * 32 + iy) * 32 + ix];
                acc += x * wsm4[ic * 9 + ky * 3 + kx];
            }
        }
    }
    // oc = c*32 + iz ; write channels-last
    int c = oc0 >> 5;
    int iz0 = oc0 & 31;
    #pragma unroll
    for (int q = 0; q < 4; ++q)
        VOLc[((size_t)(((iz0 + q) * 32 + oy) * 32 + ox)) * 16 + c] = __float2bfloat16(acc[q]);
}

// ---------------- MLP weight pack (all three layers) ----------------
__global__ __launch_bounds__(256) void packmlp_kernel(const float* __restrict__ mw1, const float* __restrict__ mb1,
                                                      const float* __restrict__ mw2, const float* __restrict__ mw3,
                                                      __hip_bfloat16* __restrict__ wpm1,
                                                      __hip_bfloat16* __restrict__ wpm2,
                                                      __hip_bfloat16* __restrict__ wpm3) {
    int i = blockIdx.x * 256 + threadIdx.x;   // 7168
    if (i < 2048) {
        int j = i & 7, l = (i >> 3) & 63, mf = i >> 9;
        int nn = mf * 16 + (l & 15);
        int ch = (l >> 4) * 8 + j;
        float v = ch < 16 ? mw1[ch * 64 + nn] : (ch == 16 ? mb1[nn] : 0.f);
        wpm1[i] = __float2bfloat16(v);
    } else if (i < 6144) {
        int q = i - 2048;
        int j = q & 7, l = (q >> 3) & 63, f = q >> 9;
        int kb = f >> 2, mf = f & 3;
        int nn = mf * 16 + (l & 15);
        int k = kb * 32 + (l >> 4) * 8 + j;
        wpm2[q] = __float2bfloat16(mw2[k * 64 + nn]);
    } else if (i < 7168) {
        int q = i - 6144;
        int j = q & 7, l = (q >> 3) & 63, kb = q >> 9;
        int m = l & 15;
        int k = kb * 32 + (l >> 4) * 8 + j;
        wpm3[q] = __float2bfloat16(m < 4 ? mw3[k * 4 + m] : 0.f);
    }
}

// ---------------- fused trilinear + 3-layer MLP via MFMA: -> raw (S*H*W, 4) f32 ----------------
// 4 waves/block, 32 points/wave, wave-private LDS tile [32][72] bf16 (h1 then h2).
__global__ __launch_bounds__(256) void mlp_mfma(const __hip_bfloat16* __restrict__ VOLc,
                                                const float* __restrict__ rays,
                                                const __hip_bfloat16* __restrict__ wpm1,
                                                const __hip_bfloat16* __restrict__ wpm2,
                                                const __hip_bfloat16* __restrict__ wpm3,
                                                const float* __restrict__ mb2,
                                                const float* __restrict__ mb3,
                                                float* __restrict__ raw) {
    __shared__ short hbuf[4][32 * 72];
    int tid = threadIdx.x;
    int w = tid >> 6, l = tid & 63;
    int lane16 = l & 15, lgrp = l >> 4;
    int P0 = blockIdx.x * 128 + w * 32;
    short* hb = hbuf[w];

    // ---- gather: lane l -> point (l>>5)*16+lane16, channels ((l>>4)&1)*8 .. +8
    int nfg = l >> 5, hf = (l >> 4) & 1;
    int n = P0 + nfg * 16 + lane16;
    int pix = n & 4095, s = n >> 12;
    float o0 = rays[pix], o1 = rays[4096 + pix], o2 = rays[2 * 4096 + pix];
    float d0 = rays[3 * 4096 + pix], d1 = rays[4 * 4096 + pix], d2 = rays[5 * 4096 + pix];
    float nearv = rays[6 * 4096 + pix], farv = rays[7 * 4096 + pix];
    float t = (float)s / 63.0f;
    float z = nearv + (farv - nearv) * t;
    float px = o0 + d0 * z, py = o1 + d1 * z, pz = o2 + d2 * z;
    float cx = fminf(fmaxf((px + 1.f) * 15.5f, 0.f), 31.f);
    float cy = fminf(fmaxf((py + 1.f) * 15.5f, 0.f), 31.f);
    float cz = fminf(fmaxf((pz + 1.f) * 15.5f, 0.f), 31.f);
    int ix = min((int)floorf(cx), 30);
    int iy = min((int)floorf(cy), 30);
    int iz = min((int)floorf(cz), 30);
    float fx = cx - (float)ix, fy = cy - (float)iy, fz = cz - (float)iz;
    float gx = 1.f - fx, gy = 1.f - fy, gz = 1.f - fz;
    float wv[8] = {gz * gy * gx, gz * gy * fx, gz * fy * gx, gz * fy * fx,
                   fz * gy * gx, fz * gy * fx, fz * fy * gx, fz * fy * fx};
    const int co[8] = {0, 16, 512, 528, 16384, 16400, 16896, 16912};
    int base = (iz * 32 + iy) * 32 + ix;
    const short* vp = (const short*)VOLc + (size_t)base * 16 + hf * 8;

    float f8[8] = {0.f, 0.f, 0.f, 0.f, 0.f, 0.f, 0.f, 0.f};
    #pragma unroll
    for (int c = 0; c < 8; ++c) {
        bf16x8 cv = *(const bf16x8*)(vp + co[c]);
        #pragma unroll
        for (int j = 0; j < 8; ++j) f8[j] += wv[c] * bf2f(cv[j]);
    }
    bf16x8 own;
    #pragma unroll
    for (int j = 0; j < 8; ++j) own[j] = f2bf(f8[j]);

    // redistribute: other half's gather (nf flipped)
    i32x4 oi = __builtin_bit_cast(i32x4, own);
    i32x4 si;
    si[0] = __shfl_xor(oi[0], 32);
    si[1] = __shfl_xor(oi[1], 32);
    si[2] = __shfl_xor(oi[2], 32);
    si[3] = __shfl_xor(oi[3], 32);
    bf16x8 swf = __builtin_bit_cast(bf16x8, si);

    bf16x8 bz = (bf16x8){0, 0, 0, 0, 0, 0, 0, 0};
    bf16x8 bbias = (bf16x8){(short)0x3F80, 0, 0, 0, 0, 0, 0, 0};  // ch16 = 1.0 (bias channel)
    bf16x8 b0 = (lgrp < 2) ? own : ((lgrp == 2) ? bbias : bz);
    bf16x8 b1 = (lgrp < 2) ? swf : ((lgrp == 2) ? bbias : bz);

    // ---- layer 1: M=64 neurons, K=32 (16 feat + bias ch), N=32 pts
    bf16x8 a1[4];
    #pragma unroll
    for (int mf = 0; mf < 4; ++mf)
        a1[mf] = *(const bf16x8*)((const short*)wpm1 + (mf * 64 + l) * 8);
    f32x4 acc1[4][2];
    #pragma unroll
    for (int mf = 0; mf < 4; ++mf) {
        acc1[mf][0] = (f32x4){0.f, 0.f, 0.f, 0.f};
        acc1[mf][1] = (f32x4){0.f, 0.f, 0.f, 0.f};
        acc1[mf][0] = __builtin_amdgcn_mfma_f32_16x16x32_bf16(a1[mf], b0, acc1[mf][0], 0, 0, 0);
        acc1[mf][1] = __builtin_amdgcn_mfma_f32_16x16x32_bf16(a1[mf], b1, acc1[mf][1], 0, 0, 0);
    }
    // relu -> bf16 -> LDS h1[pt][neuron]
    #pragma unroll
    for (int mf = 0; mf < 4; ++mf) {
        #pragma unroll
        for (int nf = 0; nf < 2; ++nf) {
            s16x4 sv;
            #pragma unroll
            for (int r = 0; r < 4; ++r) sv[r] = f2bf(fmaxf(acc1[mf][nf][r], 0.f));
            *(s16x4*)(hb + (nf * 16 + lane16) * 72 + mf * 16 + lgrp * 4) = sv;
        }
    }

    // ---- layer 2: M=64, K=64, N=32
    bf16x8 a2[2][4];
    #pragma unroll
    for (int kb = 0; kb < 2; ++kb)
        #pragma unroll
        for (int mf = 0; mf < 4; ++mf)
            a2[kb][mf] = *(const bf16x8*)((const short*)wpm2 + ((kb * 4 + mf) * 64 + l) * 8);
    f32x4 acc2[4][2];
    #pragma unroll
    for (int mf = 0; mf < 4; ++mf) {
        acc2[mf][0] = (f32x4){0.f, 0.f, 0.f, 0.f};
        acc2[mf][1] = (f32x4){0.f, 0.f, 0.f, 0.f};
    }
    #pragma unroll
    for (int nf = 0; nf < 2; ++nf) {
        #pragma unroll
        for (int kb = 0; kb < 2; ++kb) {
            bf16x8 bh = *(const bf16x8*)(hb + (nf * 16 + lane16) * 72 + kb * 32 + lgrp * 8);
            #pragma unroll
            for (int mf = 0; mf < 4; ++mf)
                acc2[mf][nf] = __builtin_amdgcn_mfma_f32_16x16x32_bf16(a2[kb][mf], bh, acc2[mf][nf], 0, 0, 0);
        }
    }
    // bias + relu -> bf16 -> LDS h2 (reuse hb; per-wave DS ops are in-order)
    #pragma unroll
    for (int mf = 0; mf < 4; ++mf) {
        f32x4 bv = *(const f32x4*)(mb2 + mf * 16 + lgrp * 4);
        #pragma unroll
        for (int nf = 0; nf < 2; ++nf) {
            s16x4 sv;
            #pragma unroll
            for (int r = 0; r < 4; ++r) sv[r] = f2bf(fmaxf(acc2[mf][nf][r] + bv[r], 0.f));
            *(s16x4*)(hb + (nf * 16 + lane16) * 72 + mf * 16 + lgrp * 4) = sv;
        }
    }

    // ---- layer 3: M=16 (4 valid), K=64, N=32
    bf16x8 a3[2];
    a3[0] = *(const bf16x8*)((const short*)wpm3 + (0 * 64 + l) * 8);
    a3[1] = *(const bf16x8*)((const short*)wpm3 + (1 * 64 + l) * 8);
    f32x4 acc3[2];
    acc3[0] = (f32x4){0.f, 0.f, 0.f, 0.f};
    acc3[1] = (f32x4){0.f, 0.f, 0.f, 0.f};
    #pragma unroll
    for (int nf = 0; nf < 2; ++nf) {
        #pragma unroll
        for (int kb = 0; kb < 2; ++kb) {
            bf16x8 bh = *(const bf16x8*)(hb + (nf * 16 + lane16) * 72 + kb * 32 + lgrp * 8);
            acc3[nf] = __builtin_amdgcn_mfma_f32_16x16x32_bf16(a3[kb], bh, acc3[nf], 0, 0, 0);
        }
    }
    if (lgrp == 0) {
        f32x4 b3v = *(const f32x4*)(mb3);
        #pragma unroll
        for (int nf = 0; nf < 2; ++nf) {
            f32x4 o = acc3[nf] + b3v;
            *(f32x4*)(raw + (size_t)(P0 + nf * 16 + lane16) * 4) = o;
        }
    }
}

// ---------------- volume rendering ----------------
__global__ __launch_bounds__(256) void render_kernel(const float* __restrict__ raw,
                                                     const float* __restrict__ rays,
                                                     float* __restrict__ out) {
    int pix = blockIdx.x * 256 + threadIdx.x;  // 4096
    float nearv = rays[6 * 4096 + pix], farv = rays[7 * 4096 + pix];
    float T = 1.f, r = 0.f, g = 0.f, b = 0.f, d = 0.f;
    float dz = (farv - nearv) * (1.f / 63.f);
    for (int s = 0; s < 64; ++s) {
        float t = (float)s / 63.0f;
        float z = nearv + (farv - nearv) * t;
        const float* rp = raw + ((size_t)(s * 4096) + pix) * 4;
        float r0 = rp[0], r1 = rp[1], r2 = rp[2], r3 = rp[3];
        float delta = (s == 63) ? 1e10f : dz;
        float sigma = fmaxf(r3, 0.f);
        float alpha = 1.f - expf(-sigma * delta);
        float wt = alpha * T;
        r += wt * (1.f / (1.f + expf(-r0)));
        g += wt * (1.f / (1.f + expf(-r1)));
        b += wt * (1.f / (1.f + expf(-r2)));
        d += wt * z;
        T *= (1.f - alpha + 1e-10f);
    }
    out[0 * 4096 + pix] = r;
    out[1 * 4096 + pix] = g;
    out[2 * 4096 + pix] = b;
    out[12288 + pix]    = d;
}

extern "C" void kernel_launch(void* const* d_in, const int* in_sizes, int n_in,
                              void* d_out, int out_size, void* d_ws, size_t ws_size,
                              hipStream_t stream) {
    const float* images = (const float*)d_in[0];
    const float* rays   = (const float*)d_in[1];
    const float* w1 = (const float*)d_in[2];
    const float* b1 = (const float*)d_in[3];
    const float* w2 = (const float*)d_in[4];
    const float* b2 = (const float*)d_in[5];
    const float* w3 = (const float*)d_in[6];
    const float* b3 = (const float*)d_in[7];
    const float* mw1 = (const float*)d_in[8];
    const float* mb1 = (const float*)d_in[9];
    const float* mw2 = (const float*)d_in[10];
    const float* mb2 = (const float*)d_in[11];
    const float* mw3 = (const float*)d_in[12];
    const float* mb3 = (const float*)d_in[13];
    float* out = (float*)d_out;

    // workspace layout
    float* ws  = (float*)d_ws;
    float* A2  = ws;                    // 50*128*32*32 = 6553600 f
    float* XB  = A2 + 6553600;          // 131072 f
    float* RAW = XB + 131072;           // 1048576 f
    __hip_bfloat16* A1c  = (__hip_bfloat16*)(RAW + 1048576);  // 13107200 bf16
    __hip_bfloat16* WPK2 = A1c + 13107200;                    // 73728
    __hip_bfloat16* WPK1 = WPK2 + 73728;                      // 2048
    __hip_bfloat16* IM   = WPK1 + 2048;                       // 6553600
    __hip_bfloat16* VOLc = IM + 6553600;                      // 524288
    __hip_bfloat16* WPM1 = VOLc + 524288;                     // 2048
    __hip_bfloat16* WPM2 = WPM1 + 2048;                       // 4096
    __hip_bfloat16* WPM3 = WPM2 + 4096;                       // 1024

    wpack2_kernel<<<dim3(288), dim3(256), 0, stream>>>(w2, WPK2);
    wpack1_kernel<<<dim3(8), dim3(256), 0, stream>>>(w1, WPK1);
    packmlp_kernel<<<dim3(28), dim3(256), 0, stream>>>(mw1, mb1, mw2, mw3, WPM1, WPM2, WPM3);
    im2col1_kernel<<<dim3(800), dim3(256), 0, stream>>>(images, IM);
    conv1_mfma<<<dim3(800), dim3(256), 0, stream>>>(IM, WPK1, b1, A1c);
    conv2_mfma<<<dim3(8, NVV), dim3(256), 0, stream>>>(A1c, WPK2, b2, A2);
    mean_kernel<<<dim3(512), dim3(256), 0, stream>>>(A2, XB);
    conv3_kernel<<<dim3(4, 128), dim3(32, 8), 0, stream>>>(XB, w3, b3, VOLc);
    mlp_mfma<<<dim3(2048), dim3(256), 0, stream>>>(VOLc, rays, WPM1, WPM2, WPM3, mb2, mb3, RAW);
    render_kernel<<<dim3(16), dim3(256), 0, stream>>>(RAW, rays, out);
}

// Round 5
// 140.660 us; speedup vs baseline: 7.4782x; 1.9110x over previous
//
#include <hip/hip_runtime.h>
#include <hip/hip_bf16.h>

#define NVV 50
#define C1 64
#define C2 128
#define HW1 64
#define HW2 32

typedef short bf16x8 __attribute__((ext_vector_type(8)));
typedef short s16x4 __attribute__((ext_vector_type(4)));
typedef float f32x4 __attribute__((ext_vector_type(4)));
typedef int i32x4 __attribute__((ext_vector_type(4)));

__device__ inline short f2bf(float x) {
    unsigned u = __builtin_bit_cast(unsigned, x);
    unsigned r = (u + 0x7FFFu + ((u >> 16) & 1u)) >> 16;
    return (short)r;
}
__device__ inline float bf2f(short x) {
    unsigned u = ((unsigned)(unsigned short)x) << 16;
    return __builtin_bit_cast(float, u);
}

// ---------------- im2col for conv1: (50,3,128,128) fp32 -> (204800 px, 32 K) bf16 ----------------
__global__ __launch_bounds__(256) void im2col1_kernel(const float* __restrict__ img,
                                                      __hip_bfloat16* __restrict__ IM) {
    int p = blockIdx.x * 256 + threadIdx.x;   // 204800
    int v = p >> 12;
    int rem = p & 4095;
    int oy = rem >> 6, ox = rem & 63;
    const float* ip = img + (size_t)v * 3 * 128 * 128;
    bf16x8 ov[4];
    #pragma unroll
    for (int k = 0; k < 32; ++k) {
        float x = 0.f;
        if (k < 27) {
            int ic = k / 9, r = k % 9;
            int ky = r / 3, kx = r % 3;
            int iy = 2 * oy + ky, ix = 2 * ox + kx;
            if (iy < 128 && ix < 128) x = ip[(ic * 128 + iy) * 128 + ix];
        }
        ov[k >> 3][k & 7] = f2bf(x);
    }
    bf16x8* op = (bf16x8*)((short*)IM + (size_t)p * 32);
    #pragma unroll
    for (int q = 0; q < 4; ++q) op[q] = ov[q];
}

// ---------------- w1 repack -> A-frag order bf16 [mtile4][lane64][8] ----------------
__global__ __launch_bounds__(256) void wpack1_kernel(const float* __restrict__ w1,
                                                     __hip_bfloat16* __restrict__ wpack) {
    int i = blockIdx.x * 256 + threadIdx.x;   // 2048
    int j = i & 7;
    int l = (i >> 3) & 63;
    int mf = i >> 9;
    int oc = mf * 16 + (l & 15);
    int k = (l >> 4) * 8 + j;
    wpack[i] = __float2bfloat16(k < 27 ? w1[oc * 27 + k] : 0.f);
}

// ---------------- conv1 as GEMM: M=64 oc, K=32, N=204800 px ----------------
__global__ __launch_bounds__(256) void conv1_mfma(const __hip_bfloat16* __restrict__ IM,
                                                  const __hip_bfloat16* __restrict__ wpack,
                                                  const float* __restrict__ b1,
                                                  __hip_bfloat16* __restrict__ out) {
    int tid = threadIdx.x;
    int l = tid & 63;
    int w = tid >> 6;
    int lane16 = l & 15, lgrp = l >> 4;
    int px0 = blockIdx.x * 256 + w * 64;

    bf16x8 a[4];
    #pragma unroll
    for (int mf = 0; mf < 4; ++mf)
        a[mf] = *(const bf16x8*)((const short*)wpack + (mf * 64 + l) * 8);

    f32x4 acc[4][4];
    #pragma unroll
    for (int mf = 0; mf < 4; ++mf)
        #pragma unroll
        for (int nf = 0; nf < 4; ++nf)
            acc[mf][nf] = (f32x4){0.f, 0.f, 0.f, 0.f};

    #pragma unroll
    for (int nf = 0; nf < 4; ++nf) {
        bf16x8 b = *(const bf16x8*)((const short*)IM + (size_t)(px0 + nf * 16 + lane16) * 32 + lgrp * 8);
        #pragma unroll
        for (int mf = 0; mf < 4; ++mf)
            acc[mf][nf] = __builtin_amdgcn_mfma_f32_16x16x32_bf16(a[mf], b, acc[mf][nf], 0, 0, 0);
    }

    #pragma unroll
    for (int mf = 0; mf < 4; ++mf) {
        #pragma unroll
        for (int nf = 0; nf < 4; ++nf) {
            int px = px0 + nf * 16 + lane16;
            s16x4 sv;
            #pragma unroll
            for (int r = 0; r < 4; ++r) {
                int oc = mf * 16 + lgrp * 4 + r;
                sv[r] = f2bf(fmaxf(acc[mf][nf][r] + b1[oc], 0.f));
            }
            *(s16x4*)((short*)out + (size_t)px * 64 + mf * 16 + lgrp * 4) = sv;
        }
    }
}

// ---------------- w2 repack -> MFMA A-fragment order bf16 ----------------
__global__ __launch_bounds__(256) void wpack2_kernel(const float* __restrict__ w2,
                                                     __hip_bfloat16* __restrict__ wpack) {
    int i = blockIdx.x * 256 + threadIdx.x;    // 73728
    int j = i & 7;
    int l = (i >> 3) & 63;
    int rest = i >> 9;
    int mtile = rest & 7;
    rest >>= 3;
    int icb = rest & 1;
    int kk = rest >> 1;                        // 0..8
    int oc = mtile * 16 + (l & 15);
    int ic = icb * 32 + (l >> 4) * 8 + j;
    int ky = kk / 3, kx = kk % 3;
    wpack[i] = __float2bfloat16(w2[((oc * 64 + ic) * 3 + ky) * 3 + kx]);
}

// ---------------- conv2 implicit GEMM: M=128 oc, N=128 px/block, K=576 -> A2c bf16 channels-last ----------------
__global__ __launch_bounds__(256) void conv2_mfma(const __hip_bfloat16* __restrict__ A1c,
                                                  const __hip_bfloat16* __restrict__ wpack,
                                                  const float* __restrict__ b2,
                                                  __hip_bfloat16* __restrict__ A2c) {
    int v   = blockIdx.y;
    int oyb = blockIdx.x;
    int tid = threadIdx.x;
    int l = tid & 63;
    int w = tid >> 6;
    int wm = w >> 1, wn = w & 1;
    int lane16 = l & 15, lgrp = l >> 4;

    int oxv[4], oyv[4];
    #pragma unroll
    for (int nf = 0; nf < 4; ++nf) {
        int px = wn * 64 + nf * 16 + lane16;
        int dy = px >> 5, ox = px & 31;
        oxv[nf] = ox;
        oyv[nf] = oyb * 4 + dy;
    }

    f32x4 acc[4][4];
    #pragma unroll
    for (int mf = 0; mf < 4; ++mf)
        #pragma unroll
        for (int nf = 0; nf < 4; ++nf)
            acc[mf][nf] = (f32x4){0.f, 0.f, 0.f, 0.f};

    const __hip_bfloat16* ibase = A1c + (size_t)v * 64 * 64 * 64;

    for (int kk = 0; kk < 9; ++kk) {
        int ky = kk / 3, kx = kk % 3;
        #pragma unroll
        for (int icb = 0; icb < 2; ++icb) {
            bf16x8 a[4];
            const __hip_bfloat16* wb = wpack + ((size_t)((kk * 2 + icb) * 8 + wm * 4)) * 512 + l * 8;
            #pragma unroll
            for (int mf = 0; mf < 4; ++mf)
                a[mf] = *(const bf16x8*)(wb + mf * 512);

            bf16x8 b[4];
            #pragma unroll
            for (int nf = 0; nf < 4; ++nf) {
                int iy = 2 * oyv[nf] + ky;
                int ix = 2 * oxv[nf] + kx;
                if (iy >= 64 || ix >= 64) {
                    b[nf] = (bf16x8){0, 0, 0, 0, 0, 0, 0, 0};
                } else {
                    b[nf] = *(const bf16x8*)(ibase + ((size_t)(iy * 64 + ix)) * 64 + icb * 32 + lgrp * 8);
                }
            }
            #pragma unroll
            for (int mf = 0; mf < 4; ++mf)
                #pragma unroll
                for (int nf = 0; nf < 4; ++nf)
                    acc[mf][nf] = __builtin_amdgcn_mfma_f32_16x16x32_bf16(a[mf], b[nf], acc[mf][nf], 0, 0, 0);
        }
    }

    // epilogue: bias+relu -> bf16 channels-last A2c[(v*1024+pix)*128 + oc]
    #pragma unroll
    for (int nf = 0; nf < 4; ++nf) {
        int pix = oyv[nf] * 32 + oxv[nf];
        short* ob = (short*)A2c + ((size_t)v * 1024 + pix) * 128 + wm * 64;
        #pragma unroll
        for (int mf = 0; mf < 4; ++mf) {
            f32x4 bv = *(const f32x4*)(b2 + wm * 64 + mf * 16 + lgrp * 4);
            s16x4 sv;
            #pragma unroll
            for (int r = 0; r < 4; ++r) sv[r] = f2bf(fmaxf(acc[mf][nf][r] + bv[r], 0.f));
            *(s16x4*)(ob + mf * 16 + lgrp * 4) = sv;
        }
    }
}

// ---------------- mean over views: A2c bf16 (50,1024,128) -> XBc bf16 (1024,128) ----------------
__global__ __launch_bounds__(256) void mean_kernel(const __hip_bfloat16* __restrict__ A2c,
                                                   __hip_bfloat16* __restrict__ XBc) {
    int i = blockIdx.x * 256 + threadIdx.x;   // 16384 = 1024 pix * 16 groups
    int g = i & 15, pix = i >> 4;
    float acc[8] = {0.f, 0.f, 0.f, 0.f, 0.f, 0.f, 0.f, 0.f};
    for (int v = 0; v < NVV; ++v) {
        bf16x8 x = *(const bf16x8*)((const short*)A2c + ((size_t)v * 1024 + pix) * 128 + g * 8);
        #pragma unroll
        for (int j = 0; j < 8; ++j) acc[j] += bf2f(x[j]);
    }
    bf16x8 o;
    #pragma unroll
    for (int j = 0; j < 8; ++j) o[j] = f2bf(acc[j] * (1.0f / NVV));
    *(bf16x8*)((short*)XBc + (size_t)pix * 128 + g * 8) = o;
}

// ---------------- w3 repack -> A-frag order bf16 [kk9][icb4][mtile32][lane64][8] ----------------
__global__ __launch_bounds__(256) void wpack3_kernel(const float* __restrict__ w3,
                                                     __hip_bfloat16* __restrict__ wpack) {
    int i = blockIdx.x * 256 + threadIdx.x;   // 589824
    int j = i & 7;
    int l = (i >> 3) & 63;
    int rest = i >> 9;                        // 1152
    int m = rest & 31;
    rest >>= 5;
    int icb = rest & 3;
    int kk = rest >> 2;                       // 0..8
    int oc = m * 16 + (l & 15);
    int ic = icb * 32 + (l >> 4) * 8 + j;
    int ky = kk / 3, kx = kk % 3;
    wpack[i] = __float2bfloat16(w3[((oc * 128 + ic) * 3 + ky) * 3 + kx]);
}

// ---------------- conv3 implicit GEMM: M=512 oc, N=1024 px, K=1152 -> VOLc channels-last bf16 ----------------
// grid (4,32), 4 waves/block (2M x 2N), wave = 64 oc x 16 px
__global__ __launch_bounds__(256) void conv3_mfma(const __hip_bfloat16* __restrict__ XBc,
                                                  const __hip_bfloat16* __restrict__ wpack,
                                                  const float* __restrict__ b3,
                                                  __hip_bfloat16* __restrict__ VOLc) {
    int tid = threadIdx.x;
    int l = tid & 63;
    int w = tid >> 6;
    int wm = w >> 1, wn = w & 1;
    int lane16 = l & 15, lgrp = l >> 4;

    int px = blockIdx.y * 32 + wn * 16 + lane16;   // 0..1023
    int y = px >> 5, x = px & 31;

    f32x4 acc[4];
    #pragma unroll
    for (int mf = 0; mf < 4; ++mf) acc[mf] = (f32x4){0.f, 0.f, 0.f, 0.f};

    for (int kk = 0; kk < 9; ++kk) {
        int ky = kk / 3, kx = kk % 3;
        int iy = y + ky - 1, ix = x + kx - 1;
        bool oob = (iy < 0) | (iy >= 32) | (ix < 0) | (ix >= 32);
        const short* bp = (const short*)XBc + (size_t)(iy * 32 + ix) * 128 + lgrp * 8;
        #pragma unroll
        for (int icb = 0; icb < 4; ++icb) {
            bf16x8 b = oob ? (bf16x8){0, 0, 0, 0, 0, 0, 0, 0}
                           : *(const bf16x8*)(bp + icb * 32);
            const short* ab = (const short*)wpack + ((size_t)((kk * 4 + icb) * 32 + blockIdx.x * 8 + wm * 4)) * 512 + l * 8;
            #pragma unroll
            for (int mf = 0; mf < 4; ++mf) {
                bf16x8 a = *(const bf16x8*)(ab + mf * 512);
                acc[mf] = __builtin_amdgcn_mfma_f32_16x16x32_bf16(a, b, acc[mf], 0, 0, 0);
            }
        }
    }

    // epilogue: oc = bx*128 + wm*64 + mf*16 + lgrp*4 + r; c=oc>>5, iz=oc&31; VOLc[((iz*32+y)*32+x)*16 + c]
    int oc_base = blockIdx.x * 128 + wm * 64;
    #pragma unroll
    for (int mf = 0; mf < 4; ++mf) {
        f32x4 bv = *(const f32x4*)(b3 + oc_base + mf * 16 + lgrp * 4);
        #pragma unroll
        for (int r = 0; r < 4; ++r) {
            int oc = oc_base + mf * 16 + lgrp * 4 + r;
            int c = oc >> 5, iz = oc & 31;
            VOLc[((size_t)((iz * 32 + y) * 32 + x)) * 16 + c] = __float2bfloat16(acc[mf][r] + bv[r]);
        }
    }
}

// ---------------- MLP weight pack (all three layers) ----------------
__global__ __launch_bounds__(256) void packmlp_kernel(const float* __restrict__ mw1, const float* __restrict__ mb1,
                                                      const float* __restrict__ mw2, const float* __restrict__ mw3,
                                                      __hip_bfloat16* __restrict__ wpm1,
                                                      __hip_bfloat16* __restrict__ wpm2,
                                                      __hip_bfloat16* __restrict__ wpm3) {
    int i = blockIdx.x * 256 + threadIdx.x;   // 7168
    if (i < 2048) {
        int j = i & 7, l = (i >> 3) & 63, mf = i >> 9;
        int nn = mf * 16 + (l & 15);
        int ch = (l >> 4) * 8 + j;
        float v = ch < 16 ? mw1[ch * 64 + nn] : (ch == 16 ? mb1[nn] : 0.f);
        wpm1[i] = __float2bfloat16(v);
    } else if (i < 6144) {
        int q = i - 2048;
        int j = q & 7, l = (q >> 3) & 63, f = q >> 9;
        int kb = f >> 2, mf = f & 3;
        int nn = mf * 16 + (l & 15);
        int k = kb * 32 + (l >> 4) * 8 + j;
        wpm2[q] = __float2bfloat16(mw2[k * 64 + nn]);
    } else if (i < 7168) {
        int q = i - 6144;
        int j = q & 7, l = (q >> 3) & 63, kb = q >> 9;
        int m = l & 15;
        int k = kb * 32 + (l >> 4) * 8 + j;
        wpm3[q] = __float2bfloat16(m < 4 ? mw3[k * 4 + m] : 0.f);
    }
}

// ---------------- fused trilinear + 3-layer MLP via MFMA: -> raw (S*H*W, 4) f32 ----------------
__global__ __launch_bounds__(256) void mlp_mfma(const __hip_bfloat16* __restrict__ VOLc,
                                                const float* __restrict__ rays,
                                                const __hip_bfloat16* __restrict__ wpm1,
                                                const __hip_bfloat16* __restrict__ wpm2,
                                                const __hip_bfloat16* __restrict__ wpm3,
                                                const float* __restrict__ mb2,
                                                const float* __restrict__ mb3,
                                                float* __restrict__ raw) {
    __shared__ short hbuf[4][32 * 72];
    int tid = threadIdx.x;
    int w = tid >> 6, l = tid & 63;
    int lane16 = l & 15, lgrp = l >> 4;
    int P0 = blockIdx.x * 128 + w * 32;
    short* hb = hbuf[w];

    int nfg = l >> 5, hf = (l >> 4) & 1;
    int n = P0 + nfg * 16 + lane16;
    int pix = n & 4095, s = n >> 12;
    float o0 = rays[pix], o1 = rays[4096 + pix], o2 = rays[2 * 4096 + pix];
    float d0 = rays[3 * 4096 + pix], d1 = rays[4 * 4096 + pix], d2 = rays[5 * 4096 + pix];
    float nearv = rays[6 * 4096 + pix], farv = rays[7 * 4096 + pix];
    float t = (float)s / 63.0f;
    float z = nearv + (farv - nearv) * t;
    float px = o0 + d0 * z, py = o1 + d1 * z, pz = o2 + d2 * z;
    float cx = fminf(fmaxf((px + 1.f) * 15.5f, 0.f), 31.f);
    float cy = fminf(fmaxf((py + 1.f) * 15.5f, 0.f), 31.f);
    float cz = fminf(fmaxf((pz + 1.f) * 15.5f, 0.f), 31.f);
    int ix = min((int)floorf(cx), 30);
    int iy = min((int)floorf(cy), 30);
    int iz = min((int)floorf(cz), 30);
    float fx = cx - (float)ix, fy = cy - (float)iy, fz = cz - (float)iz;
    float gx = 1.f - fx, gy = 1.f - fy, gz = 1.f - fz;
    float wv[8] = {gz * gy * gx, gz * gy * fx, gz * fy * gx, gz * fy * fx,
                   fz * gy * gx, fz * gy * fx, fz * fy * gx, fz * fy * fx};
    const int co[8] = {0, 16, 512, 528, 16384, 16400, 16896, 16912};
    int base = (iz * 32 + iy) * 32 + ix;
    const short* vp = (const short*)VOLc + (size_t)base * 16 + hf * 8;

    float f8[8] = {0.f, 0.f, 0.f, 0.f, 0.f, 0.f, 0.f, 0.f};
    #pragma unroll
    for (int c = 0; c < 8; ++c) {
        bf16x8 cv = *(const bf16x8*)(vp + co[c]);
        #pragma unroll
        for (int j = 0; j < 8; ++j) f8[j] += wv[c] * bf2f(cv[j]);
    }
    bf16x8 own;
    #pragma unroll
    for (int j = 0; j < 8; ++j) own[j] = f2bf(f8[j]);

    i32x4 oi = __builtin_bit_cast(i32x4, own);
    i32x4 si;
    si[0] = __shfl_xor(oi[0], 32);
    si[1] = __shfl_xor(oi[1], 32);
    si[2] = __shfl_xor(oi[2], 32);
    si[3] = __shfl_xor(oi[3], 32);
    bf16x8 swf = __builtin_bit_cast(bf16x8, si);

    bf16x8 bz = (bf16x8){0, 0, 0, 0, 0, 0, 0, 0};
    bf16x8 bbias = (bf16x8){(short)0x3F80, 0, 0, 0, 0, 0, 0, 0};
    bf16x8 b0 = (lgrp < 2) ? own : ((lgrp == 2) ? bbias : bz);
    bf16x8 b1 = (lgrp < 2) ? swf : ((lgrp == 2) ? bbias : bz);

    bf16x8 a1[4];
    #pragma unroll
    for (int mf = 0; mf < 4; ++mf)
        a1[mf] = *(const bf16x8*)((const short*)wpm1 + (mf * 64 + l) * 8);
    f32x4 acc1[4][2];
    #pragma unroll
    for (int mf = 0; mf < 4; ++mf) {
        acc1[mf][0] = (f32x4){0.f, 0.f, 0.f, 0.f};
        acc1[mf][1] = (f32x4){0.f, 0.f, 0.f, 0.f};
        acc1[mf][0] = __builtin_amdgcn_mfma_f32_16x16x32_bf16(a1[mf], b0, acc1[mf][0], 0, 0, 0);
        acc1[mf][1] = __builtin_amdgcn_mfma_f32_16x16x32_bf16(a1[mf], b1, acc1[mf][1], 0, 0, 0);
    }
    #pragma unroll
    for (int mf = 0; mf < 4; ++mf) {
        #pragma unroll
        for (int nf = 0; nf < 2; ++nf) {
            s16x4 sv;
            #pragma unroll
            for (int r = 0; r < 4; ++r) sv[r] = f2bf(fmaxf(acc1[mf][nf][r], 0.f));
            *(s16x4*)(hb + (nf * 16 + lane16) * 72 + mf * 16 + lgrp * 4) = sv;
        }
    }

    bf16x8 a2[2][4];
    #pragma unroll
    for (int kb = 0; kb < 2; ++kb)
        #pragma unroll
        for (int mf = 0; mf < 4; ++mf)
            a2[kb][mf] = *(const bf16x8*)((const short*)wpm2 + ((kb * 4 + mf) * 64 + l) * 8);
    f32x4 acc2[4][2];
    #pragma unroll
    for (int mf = 0; mf < 4; ++mf) {
        acc2[mf][0] = (f32x4){0.f, 0.f, 0.f, 0.f};
        acc2[mf][1] = (f32x4){0.f, 0.f, 0.f, 0.f};
    }
    #pragma unroll
    for (int nf = 0; nf < 2; ++nf) {
        #pragma unroll
        for (int kb = 0; kb < 2; ++kb) {
            bf16x8 bh = *(const bf16x8*)(hb + (nf * 16 + lane16) * 72 + kb * 32 + lgrp * 8);
            #pragma unroll
            for (int mf = 0; mf < 4; ++mf)
                acc2[mf][nf] = __builtin_amdgcn_mfma_f32_16x16x32_bf16(a2[kb][mf], bh, acc2[mf][nf], 0, 0, 0);
        }
    }
    #pragma unroll
    for (int mf = 0; mf < 4; ++mf) {
        f32x4 bv = *(const f32x4*)(mb2 + mf * 16 + lgrp * 4);
        #pragma unroll
        for (int nf = 0; nf < 2; ++nf) {
            s16x4 sv;
            #pragma unroll
            for (int r = 0; r < 4; ++r) sv[r] = f2bf(fmaxf(acc2[mf][nf][r] + bv[r], 0.f));
            *(s16x4*)(hb + (nf * 16 + lane16) * 72 + mf * 16 + lgrp * 4) = sv;
        }
    }

    bf16x8 a3[2];
    a3[0] = *(const bf16x8*)((const short*)wpm3 + (0 * 64 + l) * 8);
    a3[1] = *(const bf16x8*)((const short*)wpm3 + (1 * 64 + l) * 8);
    f32x4 acc3[2];
    acc3[0] = (f32x4){0.f, 0.f, 0.f, 0.f};
    acc3[1] = (f32x4){0.f, 0.f, 0.f, 0.f};
    #pragma unroll
    for (int nf = 0; nf < 2; ++nf) {
        #pragma unroll
        for (int kb = 0; kb < 2; ++kb) {
            bf16x8 bh = *(const bf16x8*)(hb + (nf * 16 + lane16) * 72 + kb * 32 + lgrp * 8);
            acc3[nf] = __builtin_amdgcn_mfma_f32_16x16x32_bf16(a3[kb], bh, acc3[nf], 0, 0, 0);
        }
    }
    if (lgrp == 0) {
        f32x4 b3v = *(const f32x4*)(mb3);
        #pragma unroll
        for (int nf = 0; nf < 2; ++nf) {
            f32x4 o = acc3[nf] + b3v;
            *(f32x4*)(raw + (size_t)(P0 + nf * 16 + lane16) * 4) = o;
        }
    }
}

// ---------------- volume rendering ----------------
__global__ __launch_bounds__(256) void render_kernel(const float* __restrict__ raw,
                                                     const float* __restrict__ rays,
                                                     float* __restrict__ out) {
    int pix = blockIdx.x * 256 + threadIdx.x;  // 4096
    float nearv = rays[6 * 4096 + pix], farv = rays[7 * 4096 + pix];
    float T = 1.f, r = 0.f, g = 0.f, b = 0.f, d = 0.f;
    float dz = (farv - nearv) * (1.f / 63.f);
    for (int s = 0; s < 64; ++s) {
        float t = (float)s / 63.0f;
        float z = nearv + (farv - nearv) * t;
        const float* rp = raw + ((size_t)(s * 4096) + pix) * 4;
        float r0 = rp[0], r1 = rp[1], r2 = rp[2], r3 = rp[3];
        float delta = (s == 63) ? 1e10f : dz;
        float sigma = fmaxf(r3, 0.f);
        float alpha = 1.f - expf(-sigma * delta);
        float wt = alpha * T;
        r += wt * (1.f / (1.f + expf(-r0)));
        g += wt * (1.f / (1.f + expf(-r1)));
        b += wt * (1.f / (1.f + expf(-r2)));
        d += wt * z;
        T *= (1.f - alpha + 1e-10f);
    }
    out[0 * 4096 + pix] = r;
    out[1 * 4096 + pix] = g;
    out[2 * 4096 + pix] = b;
    out[12288 + pix]    = d;
}

extern "C" void kernel_launch(void* const* d_in, const int* in_sizes, int n_in,
                              void* d_out, int out_size, void* d_ws, size_t ws_size,
                              hipStream_t stream) {
    const float* images = (const float*)d_in[0];
    const float* rays   = (const float*)d_in[1];
    const float* w1 = (const float*)d_in[2];
    const float* b1 = (const float*)d_in[3];
    const float* w2 = (const float*)d_in[4];
    const float* b2 = (const float*)d_in[5];
    const float* w3 = (const float*)d_in[6];
    const float* b3 = (const float*)d_in[7];
    const float* mw1 = (const float*)d_in[8];
    const float* mb1 = (const float*)d_in[9];
    const float* mw2 = (const float*)d_in[10];
    const float* mb2 = (const float*)d_in[11];
    const float* mw3 = (const float*)d_in[12];
    const float* mb3 = (const float*)d_in[13];
    float* out = (float*)d_out;

    // workspace layout
    float* ws  = (float*)d_ws;
    float* RAW = ws;                                           // 1048576 f
    __hip_bfloat16* A1c  = (__hip_bfloat16*)(RAW + 1048576);   // 13107200 bf16
    __hip_bfloat16* WPK2 = A1c + 13107200;                     // 73728
    __hip_bfloat16* WPK1 = WPK2 + 73728;                       // 2048
    __hip_bfloat16* IM   = WPK1 + 2048;                        // 6553600
    __hip_bfloat16* VOLc = IM + 6553600;                       // 524288
    __hip_bfloat16* WPM1 = VOLc + 524288;                      // 2048
    __hip_bfloat16* WPM2 = WPM1 + 2048;                        // 4096
    __hip_bfloat16* WPM3 = WPM2 + 4096;                        // 1024
    __hip_bfloat16* A2c  = WPM3 + 1024;                        // 6553600
    __hip_bfloat16* XBc  = A2c + 6553600;                      // 131072
    __hip_bfloat16* WPK3 = XBc + 131072;                       // 589824

    wpack2_kernel<<<dim3(288), dim3(256), 0, stream>>>(w2, WPK2);
    wpack1_kernel<<<dim3(8), dim3(256), 0, stream>>>(w1, WPK1);
    wpack3_kernel<<<dim3(2304), dim3(256), 0, stream>>>(w3, WPK3);
    packmlp_kernel<<<dim3(28), dim3(256), 0, stream>>>(mw1, mb1, mw2, mw3, WPM1, WPM2, WPM3);
    im2col1_kernel<<<dim3(800), dim3(256), 0, stream>>>(images, IM);
    conv1_mfma<<<dim3(800), dim3(256), 0, stream>>>(IM, WPK1, b1, A1c);
    conv2_mfma<<<dim3(8, NVV), dim3(256), 0, stream>>>(A1c, WPK2, b2, A2c);
    mean_kernel<<<dim3(64), dim3(256), 0, stream>>>(A2c, XBc);
    conv3_mfma<<<dim3(4, 32), dim3(256), 0, stream>>>(XBc, WPK3, b3, VOLc);
    mlp_mfma<<<dim3(2048), dim3(256), 0, stream>>>(VOLc, rays, WPM1, WPM2, WPM3, mb2, mb3, RAW);
    render_kernel<<<dim3(16), dim3(256), 0, stream>>>(RAW, rays, out);
}

// Round 6
// 128.508 us; speedup vs baseline: 8.1853x; 1.0946x over previous
//
#include <hip/hip_runtime.h>
#include <hip/hip_bf16.h>

#define NVV 50
#define C1 64
#define C2 128
#define HW1 64
#define HW2 32

typedef short bf16x8 __attribute__((ext_vector_type(8)));
typedef short s16x4 __attribute__((ext_vector_type(4)));
typedef float f32x4 __attribute__((ext_vector_type(4)));
typedef int i32x4 __attribute__((ext_vector_type(4)));

__device__ inline short f2bf(float x) {
    unsigned u = __builtin_bit_cast(unsigned, x);
    unsigned r = (u + 0x7FFFu + ((u >> 16) & 1u)) >> 16;
    return (short)r;
}
__device__ inline float bf2f(short x) {
    unsigned u = ((unsigned)(unsigned short)x) << 16;
    return __builtin_bit_cast(float, u);
}

// ---------------- pack_all: all weight repacks in one kernel ----------------
// [0,2048)            : w1 -> A-frag  [mtile4][lane64][8]
// [2048,75776)        : w2 -> A-frag  [kk9][icb2][mtile8][lane64][8]
// [75776,665600)      : w3 -> A-frag  [kk9][icb4][mtile32][lane64][8]
// [665600,672768)     : mlp weights (mw1+mb1 fused, mw2, mw3)
__global__ __launch_bounds__(256) void pack_all(const float* __restrict__ w1,
                                                const float* __restrict__ w2,
                                                const float* __restrict__ w3,
                                                const float* __restrict__ mw1, const float* __restrict__ mb1,
                                                const float* __restrict__ mw2, const float* __restrict__ mw3,
                                                __hip_bfloat16* __restrict__ WPK1,
                                                __hip_bfloat16* __restrict__ WPK2,
                                                __hip_bfloat16* __restrict__ WPK3,
                                                __hip_bfloat16* __restrict__ WPM1,
                                                __hip_bfloat16* __restrict__ WPM2,
                                                __hip_bfloat16* __restrict__ WPM3) {
    int i = blockIdx.x * 256 + threadIdx.x;
    if (i < 2048) {
        int j = i & 7, l = (i >> 3) & 63, mf = i >> 9;
        int oc = mf * 16 + (l & 15);
        int k = (l >> 4) * 8 + j;
        WPK1[i] = __float2bfloat16(k < 27 ? w1[oc * 27 + k] : 0.f);
    } else if (i < 75776) {
        int q = i - 2048;
        int j = q & 7, l = (q >> 3) & 63;
        int rest = q >> 9;
        int mtile = rest & 7;
        rest >>= 3;
        int icb = rest & 1;
        int kk = rest >> 1;
        int oc = mtile * 16 + (l & 15);
        int ic = icb * 32 + (l >> 4) * 8 + j;
        int ky = kk / 3, kx = kk % 3;
        WPK2[q] = __float2bfloat16(w2[((oc * 64 + ic) * 3 + ky) * 3 + kx]);
    } else if (i < 665600) {
        int q = i - 75776;
        int j = q & 7, l = (q >> 3) & 63;
        int rest = q >> 9;
        int m = rest & 31;
        rest >>= 5;
        int icb = rest & 3;
        int kk = rest >> 2;
        int oc = m * 16 + (l & 15);
        int ic = icb * 32 + (l >> 4) * 8 + j;
        int ky = kk / 3, kx = kk % 3;
        WPK3[q] = __float2bfloat16(w3[((oc * 128 + ic) * 3 + ky) * 3 + kx]);
    } else if (i < 672768) {
        int q = i - 665600;   // [0,7168)
        if (q < 2048) {
            int j = q & 7, l = (q >> 3) & 63, mf = q >> 9;
            int nn = mf * 16 + (l & 15);
            int ch = (l >> 4) * 8 + j;
            float v = ch < 16 ? mw1[ch * 64 + nn] : (ch == 16 ? mb1[nn] : 0.f);
            WPM1[q] = __float2bfloat16(v);
        } else if (q < 6144) {
            int p = q - 2048;
            int j = p & 7, l = (p >> 3) & 63, f = p >> 9;
            int kb = f >> 2, mf = f & 3;
            int nn = mf * 16 + (l & 15);
            int k = kb * 32 + (l >> 4) * 8 + j;
            WPM2[p] = __float2bfloat16(mw2[k * 64 + nn]);
        } else {
            int p = q - 6144;
            int j = p & 7, l = (p >> 3) & 63, kb = p >> 9;
            int m = l & 15;
            int k = kb * 32 + (l >> 4) * 8 + j;
            WPM3[p] = __float2bfloat16(m < 4 ? mw3[k * 4 + m] : 0.f);
        }
    }
}

// ---------------- conv1 fused (im2col in LDS) : (50,3,128,128) fp32 -> A1c bf16 (v,y,x,64ch) ----------------
// grid (16 rowblocks, 50 views); block 256 = 4 waves; wave w -> output row oy = oyb*4 + w.
__global__ __launch_bounds__(256) void conv1_fused(const float* __restrict__ img,
                                                   const __hip_bfloat16* __restrict__ wpack,
                                                   const float* __restrict__ b1,
                                                   __hip_bfloat16* __restrict__ out) {
    __shared__ float tile[3 * 9 * 132];
    int oyb = blockIdx.x, v = blockIdx.y;
    int tid = threadIdx.x;
    const float* ip = img + (size_t)v * 3 * 128 * 128;
    int iy0 = oyb * 8;
    for (int idx = tid; idx < 3456; idx += 256) {
        int ix = idx & 127;
        int t = idx >> 7;              // 0..26
        int iyl = t % 9, ic = t / 9;
        int iy = iy0 + iyl;
        tile[(ic * 9 + iyl) * 132 + ix] = (iy < 128) ? ip[(ic * 128 + iy) * 128 + ix] : 0.f;
    }
    if (tid < 108) {
        int c = tid & 3;
        int t = tid >> 2;              // 0..26
        int iyl = t % 9, ic = t / 9;
        tile[(ic * 9 + iyl) * 132 + 128 + c] = 0.f;
    }
    __syncthreads();

    int l = tid & 63, w = tid >> 6;
    int lane16 = l & 15, lgrp = l >> 4;
    int oy = oyb * 4 + w;

    // per-j tap decomposition (k = lgrp*8 + j)
    int offj[8];
    bool okj[8];
    #pragma unroll
    for (int j = 0; j < 8; ++j) {
        int k = lgrp * 8 + j;
        bool ok = k < 27;
        int kc = ok ? k : 0;
        int ic = kc / 9, r = kc % 9;
        int ky = r / 3, kx = r % 3;
        offj[j] = (ic * 9 + 2 * w + ky) * 132 + kx;
        okj[j] = ok;
    }

    bf16x8 a[4];
    #pragma unroll
    for (int mf = 0; mf < 4; ++mf)
        a[mf] = *(const bf16x8*)((const short*)wpack + (mf * 64 + l) * 8);

    f32x4 acc[4][4];
    #pragma unroll
    for (int mf = 0; mf < 4; ++mf)
        #pragma unroll
        for (int nf = 0; nf < 4; ++nf)
            acc[mf][nf] = (f32x4){0.f, 0.f, 0.f, 0.f};

    #pragma unroll
    for (int nf = 0; nf < 4; ++nf) {
        int ox = nf * 16 + lane16;
        bf16x8 b;
        #pragma unroll
        for (int j = 0; j < 8; ++j) {
            float x = tile[offj[j] + 2 * ox];
            b[j] = okj[j] ? f2bf(x) : (short)0;
        }
        #pragma unroll
        for (int mf = 0; mf < 4; ++mf)
            acc[mf][nf] = __builtin_amdgcn_mfma_f32_16x16x32_bf16(a[mf], b, acc[mf][nf], 0, 0, 0);
    }

    #pragma unroll
    for (int mf = 0; mf < 4; ++mf) {
        #pragma unroll
        for (int nf = 0; nf < 4; ++nf) {
            int px = (v * 64 + oy) * 64 + nf * 16 + lane16;
            s16x4 sv;
            #pragma unroll
            for (int r = 0; r < 4; ++r) {
                int oc = mf * 16 + lgrp * 4 + r;
                sv[r] = f2bf(fmaxf(acc[mf][nf][r] + b1[oc], 0.f));
            }
            *(s16x4*)((short*)out + (size_t)px * 64 + mf * 16 + lgrp * 4) = sv;
        }
    }
}

// ---------------- conv2 implicit GEMM: M=128 oc, N=128 px/block, K=576 -> A2c bf16 channels-last ----------------
__global__ __launch_bounds__(256) void conv2_mfma(const __hip_bfloat16* __restrict__ A1c,
                                                  const __hip_bfloat16* __restrict__ wpack,
                                                  const float* __restrict__ b2,
                                                  __hip_bfloat16* __restrict__ A2c) {
    int v   = blockIdx.y;
    int oyb = blockIdx.x;
    int tid = threadIdx.x;
    int l = tid & 63;
    int w = tid >> 6;
    int wm = w >> 1, wn = w & 1;
    int lane16 = l & 15, lgrp = l >> 4;

    int oxv[4], oyv[4];
    #pragma unroll
    for (int nf = 0; nf < 4; ++nf) {
        int px = wn * 64 + nf * 16 + lane16;
        int dy = px >> 5, ox = px & 31;
        oxv[nf] = ox;
        oyv[nf] = oyb * 4 + dy;
    }

    f32x4 acc[4][4];
    #pragma unroll
    for (int mf = 0; mf < 4; ++mf)
        #pragma unroll
        for (int nf = 0; nf < 4; ++nf)
            acc[mf][nf] = (f32x4){0.f, 0.f, 0.f, 0.f};

    const __hip_bfloat16* ibase = A1c + (size_t)v * 64 * 64 * 64;

    for (int kk = 0; kk < 9; ++kk) {
        int ky = kk / 3, kx = kk % 3;
        #pragma unroll
        for (int icb = 0; icb < 2; ++icb) {
            bf16x8 a[4];
            const __hip_bfloat16* wb = wpack + ((size_t)((kk * 2 + icb) * 8 + wm * 4)) * 512 + l * 8;
            #pragma unroll
            for (int mf = 0; mf < 4; ++mf)
                a[mf] = *(const bf16x8*)(wb + mf * 512);

            bf16x8 b[4];
            #pragma unroll
            for (int nf = 0; nf < 4; ++nf) {
                int iy = 2 * oyv[nf] + ky;
                int ix = 2 * oxv[nf] + kx;
                if (iy >= 64 || ix >= 64) {
                    b[nf] = (bf16x8){0, 0, 0, 0, 0, 0, 0, 0};
                } else {
                    b[nf] = *(const bf16x8*)(ibase + ((size_t)(iy * 64 + ix)) * 64 + icb * 32 + lgrp * 8);
                }
            }
            #pragma unroll
            for (int mf = 0; mf < 4; ++mf)
                #pragma unroll
                for (int nf = 0; nf < 4; ++nf)
                    acc[mf][nf] = __builtin_amdgcn_mfma_f32_16x16x32_bf16(a[mf], b[nf], acc[mf][nf], 0, 0, 0);
        }
    }

    #pragma unroll
    for (int nf = 0; nf < 4; ++nf) {
        int pix = oyv[nf] * 32 + oxv[nf];
        short* ob = (short*)A2c + ((size_t)v * 1024 + pix) * 128 + wm * 64;
        #pragma unroll
        for (int mf = 0; mf < 4; ++mf) {
            f32x4 bv = *(const f32x4*)(b2 + wm * 64 + mf * 16 + lgrp * 4);
            s16x4 sv;
            #pragma unroll
            for (int r = 0; r < 4; ++r) sv[r] = f2bf(fmaxf(acc[mf][nf][r] + bv[r], 0.f));
            *(s16x4*)(ob + mf * 16 + lgrp * 4) = sv;
        }
    }
}

// ---------------- mean over views: A2c bf16 (50,1024,128) -> XBc bf16 (1024,128) ----------------
__global__ __launch_bounds__(256) void mean_kernel(const __hip_bfloat16* __restrict__ A2c,
                                                   __hip_bfloat16* __restrict__ XBc) {
    int i = blockIdx.x * 256 + threadIdx.x;   // 16384
    int g = i & 15, pix = i >> 4;
    float acc[8] = {0.f, 0.f, 0.f, 0.f, 0.f, 0.f, 0.f, 0.f};
    for (int v = 0; v < NVV; ++v) {
        bf16x8 x = *(const bf16x8*)((const short*)A2c + ((size_t)v * 1024 + pix) * 128 + g * 8);
        #pragma unroll
        for (int j = 0; j < 8; ++j) acc[j] += bf2f(x[j]);
    }
    bf16x8 o;
    #pragma unroll
    for (int j = 0; j < 8; ++j) o[j] = f2bf(acc[j] * (1.0f / NVV));
    *(bf16x8*)((short*)XBc + (size_t)pix * 128 + g * 8) = o;
}

// ---------------- conv3 implicit GEMM: M=512 oc, N=1024 px, K=1152 -> VOLc channels-last bf16 ----------------
__global__ __launch_bounds__(256) void conv3_mfma(const __hip_bfloat16* __restrict__ XBc,
                                                  const __hip_bfloat16* __restrict__ wpack,
                                                  const float* __restrict__ b3,
                                                  __hip_bfloat16* __restrict__ VOLc) {
    int tid = threadIdx.x;
    int l = tid & 63;
    int w = tid >> 6;
    int wm = w >> 1, wn = w & 1;
    int lane16 = l & 15, lgrp = l >> 4;

    int px = blockIdx.y * 32 + wn * 16 + lane16;
    int y = px >> 5, x = px & 31;

    f32x4 acc[4];
    #pragma unroll
    for (int mf = 0; mf < 4; ++mf) acc[mf] = (f32x4){0.f, 0.f, 0.f, 0.f};

    for (int kk = 0; kk < 9; ++kk) {
        int ky = kk / 3, kx = kk % 3;
        int iy = y + ky - 1, ix = x + kx - 1;
        bool oob = (iy < 0) | (iy >= 32) | (ix < 0) | (ix >= 32);
        const short* bp = (const short*)XBc + (size_t)(iy * 32 + ix) * 128 + lgrp * 8;
        #pragma unroll
        for (int icb = 0; icb < 4; ++icb) {
            bf16x8 b = oob ? (bf16x8){0, 0, 0, 0, 0, 0, 0, 0}
                           : *(const bf16x8*)(bp + icb * 32);
            const short* ab = (const short*)wpack + ((size_t)((kk * 4 + icb) * 32 + blockIdx.x * 8 + wm * 4)) * 512 + l * 8;
            #pragma unroll
            for (int mf = 0; mf < 4; ++mf) {
                bf16x8 a = *(const bf16x8*)(ab + mf * 512);
                acc[mf] = __builtin_amdgcn_mfma_f32_16x16x32_bf16(a, b, acc[mf], 0, 0, 0);
            }
        }
    }

    int oc_base = blockIdx.x * 128 + wm * 64;
    #pragma unroll
    for (int mf = 0; mf < 4; ++mf) {
        f32x4 bv = *(const f32x4*)(b3 + oc_base + mf * 16 + lgrp * 4);
        #pragma unroll
        for (int r = 0; r < 4; ++r) {
            int oc = oc_base + mf * 16 + lgrp * 4 + r;
            int c = oc >> 5, iz = oc & 31;
            VOLc[((size_t)((iz * 32 + y) * 32 + x)) * 16 + c] = __float2bfloat16(acc[mf][r] + bv[r]);
        }
    }
}

// ---------------- fused trilinear + 3-layer MLP via MFMA: -> raw (S*H*W, 4) f32 ----------------
__global__ __launch_bounds__(256) void mlp_mfma(const __hip_bfloat16* __restrict__ VOLc,
                                                const float* __restrict__ rays,
                                                const __hip_bfloat16* __restrict__ wpm1,
                                                const __hip_bfloat16* __restrict__ wpm2,
                                                const __hip_bfloat16* __restrict__ wpm3,
                                                const float* __restrict__ mb2,
                                                const float* __restrict__ mb3,
                                                float* __restrict__ raw) {
    __shared__ short hbuf[4][32 * 72];
    int tid = threadIdx.x;
    int w = tid >> 6, l = tid & 63;
    int lane16 = l & 15, lgrp = l >> 4;
    int P0 = blockIdx.x * 128 + w * 32;
    short* hb = hbuf[w];

    int nfg = l >> 5, hf = (l >> 4) & 1;
    int n = P0 + nfg * 16 + lane16;
    int pix = n & 4095, s = n >> 12;
    float o0 = rays[pix], o1 = rays[4096 + pix], o2 = rays[2 * 4096 + pix];
    float d0 = rays[3 * 4096 + pix], d1 = rays[4 * 4096 + pix], d2 = rays[5 * 4096 + pix];
    float nearv = rays[6 * 4096 + pix], farv = rays[7 * 4096 + pix];
    float t = (float)s / 63.0f;
    float z = nearv + (farv - nearv) * t;
    float px = o0 + d0 * z, py = o1 + d1 * z, pz = o2 + d2 * z;
    float cx = fminf(fmaxf((px + 1.f) * 15.5f, 0.f), 31.f);
    float cy = fminf(fmaxf((py + 1.f) * 15.5f, 0.f), 31.f);
    float cz = fminf(fmaxf((pz + 1.f) * 15.5f, 0.f), 31.f);
    int ix = min((int)floorf(cx), 30);
    int iy = min((int)floorf(cy), 30);
    int iz = min((int)floorf(cz), 30);
    float fx = cx - (float)ix, fy = cy - (float)iy, fz = cz - (float)iz;
    float gx = 1.f - fx, gy = 1.f - fy, gz = 1.f - fz;
    float wv[8] = {gz * gy * gx, gz * gy * fx, gz * fy * gx, gz * fy * fx,
                   fz * gy * gx, fz * gy * fx, fz * fy * gx, fz * fy * fx};
    const int co[8] = {0, 16, 512, 528, 16384, 16400, 16896, 16912};
    int base = (iz * 32 + iy) * 32 + ix;
    const short* vp = (const short*)VOLc + (size_t)base * 16 + hf * 8;

    float f8[8] = {0.f, 0.f, 0.f, 0.f, 0.f, 0.f, 0.f, 0.f};
    #pragma unroll
    for (int c = 0; c < 8; ++c) {
        bf16x8 cv = *(const bf16x8*)(vp + co[c]);
        #pragma unroll
        for (int j = 0; j < 8; ++j) f8[j] += wv[c] * bf2f(cv[j]);
    }
    bf16x8 own;
    #pragma unroll
    for (int j = 0; j < 8; ++j) own[j] = f2bf(f8[j]);

    i32x4 oi = __builtin_bit_cast(i32x4, own);
    i32x4 si;
    si[0] = __shfl_xor(oi[0], 32);
    si[1] = __shfl_xor(oi[1], 32);
    si[2] = __shfl_xor(oi[2], 32);
    si[3] = __shfl_xor(oi[3], 32);
    bf16x8 swf = __builtin_bit_cast(bf16x8, si);

    bf16x8 bz = (bf16x8){0, 0, 0, 0, 0, 0, 0, 0};
    bf16x8 bbias = (bf16x8){(short)0x3F80, 0, 0, 0, 0, 0, 0, 0};
    bf16x8 b0 = (lgrp < 2) ? own : ((lgrp == 2) ? bbias : bz);
    bf16x8 b1 = (lgrp < 2) ? swf : ((lgrp == 2) ? bbias : bz);

    bf16x8 a1[4];
    #pragma unroll
    for (int mf = 0; mf < 4; ++mf)
        a1[mf] = *(const bf16x8*)((const short*)wpm1 + (mf * 64 + l) * 8);
    f32x4 acc1[4][2];
    #pragma unroll
    for (int mf = 0; mf < 4; ++mf) {
        acc1[mf][0] = (f32x4){0.f, 0.f, 0.f, 0.f};
        acc1[mf][1] = (f32x4){0.f, 0.f, 0.f, 0.f};
        acc1[mf][0] = __builtin_amdgcn_mfma_f32_16x16x32_bf16(a1[mf], b0, acc1[mf][0], 0, 0, 0);
        acc1[mf][1] = __builtin_amdgcn_mfma_f32_16x16x32_bf16(a1[mf], b1, acc1[mf][1], 0, 0, 0);
    }
    #pragma unroll
    for (int mf = 0; mf < 4; ++mf) {
        #pragma unroll
        for (int nf = 0; nf < 2; ++nf) {
            s16x4 sv;
            #pragma unroll
            for (int r = 0; r < 4; ++r) sv[r] = f2bf(fmaxf(acc1[mf][nf][r], 0.f));
            *(s16x4*)(hb + (nf * 16 + lane16) * 72 + mf * 16 + lgrp * 4) = sv;
        }
    }

    bf16x8 a2[2][4];
    #pragma unroll
    for (int kb = 0; kb < 2; ++kb)
        #pragma unroll
        for (int mf = 0; mf < 4; ++mf)
            a2[kb][mf] = *(const bf16x8*)((const short*)wpm2 + ((kb * 4 + mf) * 64 + l) * 8);
    f32x4 acc2[4][2];
    #pragma unroll
    for (int mf = 0; mf < 4; ++mf) {
        acc2[mf][0] = (f32x4){0.f, 0.f, 0.f, 0.f};
        acc2[mf][1] = (f32x4){0.f, 0.f, 0.f, 0.f};
    }
    #pragma unroll
    for (int nf = 0; nf < 2; ++nf) {
        #pragma unroll
        for (int kb = 0; kb < 2; ++kb) {
            bf16x8 bh = *(const bf16x8*)(hb + (nf * 16 + lane16) * 72 + kb * 32 + lgrp * 8);
            #pragma unroll
            for (int mf = 0; mf < 4; ++mf)
                acc2[mf][nf] = __builtin_amdgcn_mfma_f32_16x16x32_bf16(a2[kb][mf], bh, acc2[mf][nf], 0, 0, 0);
        }
    }
    #pragma unroll
    for (int mf = 0; mf < 4; ++mf) {
        f32x4 bv = *(const f32x4*)(mb2 + mf * 16 + lgrp * 4);
        #pragma unroll
        for (int nf = 0; nf < 2; ++nf) {
            s16x4 sv;
            #pragma unroll
            for (int r = 0; r < 4; ++r) sv[r] = f2bf(fmaxf(acc2[mf][nf][r] + bv[r], 0.f));
            *(s16x4*)(hb + (nf * 16 + lane16) * 72 + mf * 16 + lgrp * 4) = sv;
        }
    }

    bf16x8 a3[2];
    a3[0] = *(const bf16x8*)((const short*)wpm3 + (0 * 64 + l) * 8);
    a3[1] = *(const bf16x8*)((const short*)wpm3 + (1 * 64 + l) * 8);
    f32x4 acc3[2];
    acc3[0] = (f32x4){0.f, 0.f, 0.f, 0.f};
    acc3[1] = (f32x4){0.f, 0.f, 0.f, 0.f};
    #pragma unroll
    for (int nf = 0; nf < 2; ++nf) {
        #pragma unroll
        for (int kb = 0; kb < 2; ++kb) {
            bf16x8 bh = *(const bf16x8*)(hb + (nf * 16 + lane16) * 72 + kb * 32 + lgrp * 8);
            acc3[nf] = __builtin_amdgcn_mfma_f32_16x16x32_bf16(a3[kb], bh, acc3[nf], 0, 0, 0);
        }
    }
    if (lgrp == 0) {
        f32x4 b3v = *(const f32x4*)(mb3);
        #pragma unroll
        for (int nf = 0; nf < 2; ++nf) {
            f32x4 o = acc3[nf] + b3v;
            *(f32x4*)(raw + (size_t)(P0 + nf * 16 + lane16) * 4) = o;
        }
    }
}

// ---------------- volume rendering ----------------
__global__ __launch_bounds__(64) void render_kernel(const float* __restrict__ raw,
                                                    const float* __restrict__ rays,
                                                    float* __restrict__ out) {
    int pix = blockIdx.x * 64 + threadIdx.x;  // 4096
    float nearv = rays[6 * 4096 + pix], farv = rays[7 * 4096 + pix];
    float T = 1.f, r = 0.f, g = 0.f, b = 0.f, d = 0.f;
    float dz = (farv - nearv) * (1.f / 63.f);
    for (int s = 0; s < 64; ++s) {
        float t = (float)s / 63.0f;
        float z = nearv + (farv - nearv) * t;
        const float* rp = raw + ((size_t)(s * 4096) + pix) * 4;
        float r0 = rp[0], r1 = rp[1], r2 = rp[2], r3 = rp[3];
        float delta = (s == 63) ? 1e10f : dz;
        float sigma = fmaxf(r3, 0.f);
        float alpha = 1.f - __expf(-sigma * delta);
        float wt = alpha * T;
        r += wt * (1.f / (1.f + __expf(-r0)));
        g += wt * (1.f / (1.f + __expf(-r1)));
        b += wt * (1.f / (1.f + __expf(-r2)));
        d += wt * z;
        T *= (1.f - alpha + 1e-10f);
    }
    out[0 * 4096 + pix] = r;
    out[1 * 4096 + pix] = g;
    out[2 * 4096 + pix] = b;
    out[12288 + pix]    = d;
}

extern "C" void kernel_launch(void* const* d_in, const int* in_sizes, int n_in,
                              void* d_out, int out_size, void* d_ws, size_t ws_size,
                              hipStream_t stream) {
    const float* images = (const float*)d_in[0];
    const float* rays   = (const float*)d_in[1];
    const float* w1 = (const float*)d_in[2];
    const float* b1 = (const float*)d_in[3];
    const float* w2 = (const float*)d_in[4];
    const float* b2 = (const float*)d_in[5];
    const float* w3 = (const float*)d_in[6];
    const float* b3 = (const float*)d_in[7];
    const float* mw1 = (const float*)d_in[8];
    const float* mb1 = (const float*)d_in[9];
    const float* mw2 = (const float*)d_in[10];
    const float* mb2 = (const float*)d_in[11];
    const float* mw3 = (const float*)d_in[12];
    const float* mb3 = (const float*)d_in[13];
    float* out = (float*)d_out;

    // workspace layout
    float* ws  = (float*)d_ws;
    float* RAW = ws;                                           // 1048576 f
    __hip_bfloat16* A1c  = (__hip_bfloat16*)(RAW + 1048576);   // 13107200 bf16
    __hip_bfloat16* WPK2 = A1c + 13107200;                     // 73728
    __hip_bfloat16* WPK1 = WPK2 + 73728;                       // 2048
    __hip_bfloat16* VOLc = WPK1 + 2048;                        // 524288
    __hip_bfloat16* WPM1 = VOLc + 524288;                      // 2048
    __hip_bfloat16* WPM2 = WPM1 + 2048;                        // 4096
    __hip_bfloat16* WPM3 = WPM2 + 4096;                        // 1024
    __hip_bfloat16* A2c  = WPM3 + 1024;                        // 6553600
    __hip_bfloat16* XBc  = A2c + 6553600;                      // 131072
    __hip_bfloat16* WPK3 = XBc + 131072;                       // 589824

    pack_all<<<dim3(2628), dim3(256), 0, stream>>>(w1, w2, w3, mw1, mb1, mw2, mw3,
                                                   WPK1, WPK2, WPK3, WPM1, WPM2, WPM3);
    conv1_fused<<<dim3(16, NVV), dim3(256), 0, stream>>>(images, WPK1, b1, A1c);
    conv2_mfma<<<dim3(8, NVV), dim3(256), 0, stream>>>(A1c, WPK2, b2, A2c);
    mean_kernel<<<dim3(64), dim3(256), 0, stream>>>(A2c, XBc);
    conv3_mfma<<<dim3(4, 32), dim3(256), 0, stream>>>(XBc, WPK3, b3, VOLc);
    mlp_mfma<<<dim3(2048), dim3(256), 0, stream>>>(VOLc, rays, WPM1, WPM2, WPM3, mb2, mb3, RAW);
    render_kernel<<<dim3(64), dim3(64), 0, stream>>>(RAW, rays, out);
}

// Round 7
// 115.987 us; speedup vs baseline: 9.0689x; 1.1079x over previous
//
#include <hip/hip_runtime.h>
#include <hip/hip_bf16.h>

#define NVV 50
#define C1 64
#define C2 128
#define HW1 64
#define HW2 32

typedef short bf16x8 __attribute__((ext_vector_type(8)));
typedef short s16x4 __attribute__((ext_vector_type(4)));
typedef float f32x4 __attribute__((ext_vector_type(4)));
typedef int i32x4 __attribute__((ext_vector_type(4)));

__device__ inline short f2bf(float x) {
    unsigned u = __builtin_bit_cast(unsigned, x);
    unsigned r = (u + 0x7FFFu + ((u >> 16) & 1u)) >> 16;
    return (short)r;
}
__device__ inline float bf2f(short x) {
    unsigned u = ((unsigned)(unsigned short)x) << 16;
    return __builtin_bit_cast(float, u);
}

// ---------------- pack_all: all weight repacks in one kernel ----------------
__global__ __launch_bounds__(256) void pack_all(const float* __restrict__ w1,
                                                const float* __restrict__ w2,
                                                const float* __restrict__ w3,
                                                const float* __restrict__ mw1, const float* __restrict__ mb1,
                                                const float* __restrict__ mw2, const float* __restrict__ mw3,
                                                __hip_bfloat16* __restrict__ WPK1,
                                                __hip_bfloat16* __restrict__ WPK2,
                                                __hip_bfloat16* __restrict__ WPK3,
                                                __hip_bfloat16* __restrict__ WPM1,
                                                __hip_bfloat16* __restrict__ WPM2,
                                                __hip_bfloat16* __restrict__ WPM3) {
    int i = blockIdx.x * 256 + threadIdx.x;
    if (i < 2048) {
        int j = i & 7, l = (i >> 3) & 63, mf = i >> 9;
        int oc = mf * 16 + (l & 15);
        int k = (l >> 4) * 8 + j;
        WPK1[i] = __float2bfloat16(k < 27 ? w1[oc * 27 + k] : 0.f);
    } else if (i < 75776) {
        int q = i - 2048;
        int j = q & 7, l = (q >> 3) & 63;
        int rest = q >> 9;
        int mtile = rest & 7;
        rest >>= 3;
        int icb = rest & 1;
        int kk = rest >> 1;
        int oc = mtile * 16 + (l & 15);
        int ic = icb * 32 + (l >> 4) * 8 + j;
        int ky = kk / 3, kx = kk % 3;
        WPK2[q] = __float2bfloat16(w2[((oc * 64 + ic) * 3 + ky) * 3 + kx]);
    } else if (i < 665600) {
        int q = i - 75776;
        int j = q & 7, l = (q >> 3) & 63;
        int rest = q >> 9;
        int m = rest & 31;
        rest >>= 5;
        int icb = rest & 3;
        int kk = rest >> 2;
        int oc = m * 16 + (l & 15);
        int ic = icb * 32 + (l >> 4) * 8 + j;
        int ky = kk / 3, kx = kk % 3;
        WPK3[q] = __float2bfloat16(w3[((oc * 128 + ic) * 3 + ky) * 3 + kx]);
    } else if (i < 672768) {
        int q = i - 665600;
        if (q < 2048) {
            int j = q & 7, l = (q >> 3) & 63, mf = q >> 9;
            int nn = mf * 16 + (l & 15);
            int ch = (l >> 4) * 8 + j;
            float v = ch < 16 ? mw1[ch * 64 + nn] : (ch == 16 ? mb1[nn] : 0.f);
            WPM1[q] = __float2bfloat16(v);
        } else if (q < 6144) {
            int p = q - 2048;
            int j = p & 7, l = (p >> 3) & 63, f = p >> 9;
            int kb = f >> 2, mf = f & 3;
            int nn = mf * 16 + (l & 15);
            int k = kb * 32 + (l >> 4) * 8 + j;
            WPM2[p] = __float2bfloat16(mw2[k * 64 + nn]);
        } else {
            int p = q - 6144;
            int j = p & 7, l = (p >> 3) & 63, kb = p >> 9;
            int m = l & 15;
            int k = kb * 32 + (l >> 4) * 8 + j;
            WPM3[p] = __float2bfloat16(m < 4 ? mw3[k * 4 + m] : 0.f);
        }
    }
}

// ---------------- conv1 fused (im2col in LDS) : (50,3,128,128) fp32 -> A1c bf16 (v,y,x,64ch) ----------------
__global__ __launch_bounds__(256) void conv1_fused(const float* __restrict__ img,
                                                   const __hip_bfloat16* __restrict__ wpack,
                                                   const float* __restrict__ b1,
                                                   __hip_bfloat16* __restrict__ out) {
    __shared__ float tile[3 * 9 * 132];
    int oyb = blockIdx.x, v = blockIdx.y;
    int tid = threadIdx.x;
    const float* ip = img + (size_t)v * 3 * 128 * 128;
    int iy0 = oyb * 8;
    for (int idx = tid; idx < 3456; idx += 256) {
        int ix = idx & 127;
        int t = idx >> 7;
        int iyl = t % 9, ic = t / 9;
        int iy = iy0 + iyl;
        tile[(ic * 9 + iyl) * 132 + ix] = (iy < 128) ? ip[(ic * 128 + iy) * 128 + ix] : 0.f;
    }
    if (tid < 108) {
        int c = tid & 3;
        int t = tid >> 2;
        int iyl = t % 9, ic = t / 9;
        tile[(ic * 9 + iyl) * 132 + 128 + c] = 0.f;
    }
    __syncthreads();

    int l = tid & 63, w = tid >> 6;
    int lane16 = l & 15, lgrp = l >> 4;
    int oy = oyb * 4 + w;

    int offj[8];
    bool okj[8];
    #pragma unroll
    for (int j = 0; j < 8; ++j) {
        int k = lgrp * 8 + j;
        bool ok = k < 27;
        int kc = ok ? k : 0;
        int ic = kc / 9, r = kc % 9;
        int ky = r / 3, kx = r % 3;
        offj[j] = (ic * 9 + 2 * w + ky) * 132 + kx;
        okj[j] = ok;
    }

    bf16x8 a[4];
    #pragma unroll
    for (int mf = 0; mf < 4; ++mf)
        a[mf] = *(const bf16x8*)((const short*)wpack + (mf * 64 + l) * 8);

    f32x4 acc[4][4];
    #pragma unroll
    for (int mf = 0; mf < 4; ++mf)
        #pragma unroll
        for (int nf = 0; nf < 4; ++nf)
            acc[mf][nf] = (f32x4){0.f, 0.f, 0.f, 0.f};

    #pragma unroll
    for (int nf = 0; nf < 4; ++nf) {
        int ox = nf * 16 + lane16;
        bf16x8 b;
        #pragma unroll
        for (int j = 0; j < 8; ++j) {
            float x = tile[offj[j] + 2 * ox];
            b[j] = okj[j] ? f2bf(x) : (short)0;
        }
        #pragma unroll
        for (int mf = 0; mf < 4; ++mf)
            acc[mf][nf] = __builtin_amdgcn_mfma_f32_16x16x32_bf16(a[mf], b, acc[mf][nf], 0, 0, 0);
    }

    #pragma unroll
    for (int mf = 0; mf < 4; ++mf) {
        #pragma unroll
        for (int nf = 0; nf < 4; ++nf) {
            int px = (v * 64 + oy) * 64 + nf * 16 + lane16;
            s16x4 sv;
            #pragma unroll
            for (int r = 0; r < 4; ++r) {
                int oc = mf * 16 + lgrp * 4 + r;
                sv[r] = f2bf(fmaxf(acc[mf][nf][r] + b1[oc], 0.f));
            }
            *(s16x4*)((short*)out + (size_t)px * 64 + mf * 16 + lgrp * 4) = sv;
        }
    }
}

// ---------------- conv2 implicit GEMM (fully unrolled K): M=128 oc, N=128 px/block, K=576 ----------------
__global__ __launch_bounds__(256) void conv2_mfma(const __hip_bfloat16* __restrict__ A1c,
                                                  const __hip_bfloat16* __restrict__ wpack,
                                                  const float* __restrict__ b2,
                                                  __hip_bfloat16* __restrict__ A2c) {
    int v   = blockIdx.y;
    int oyb = blockIdx.x;
    int tid = threadIdx.x;
    int l = tid & 63;
    int w = tid >> 6;
    int wm = w >> 1, wn = w & 1;
    int lane16 = l & 15, lgrp = l >> 4;

    int oxv[4], oyv[4];
    const short* pxb[4];
    bool rOOB[4], cOOB[4];
    const short* ibase = (const short*)A1c + (size_t)v * 64 * 64 * 64;
    #pragma unroll
    for (int nf = 0; nf < 4; ++nf) {
        int px = wn * 64 + nf * 16 + lane16;
        int dy = px >> 5, ox = px & 31;
        oxv[nf] = ox;
        oyv[nf] = oyb * 4 + dy;
        pxb[nf] = ibase + ((size_t)(2 * oyv[nf]) * 64 + 2 * ox) * 64 + lgrp * 8;
        rOOB[nf] = (oyv[nf] == 31);
        cOOB[nf] = (ox == 31);
    }

    f32x4 acc[4][4];
    #pragma unroll
    for (int mf = 0; mf < 4; ++mf)
        #pragma unroll
        for (int nf = 0; nf < 4; ++nf)
            acc[mf][nf] = (f32x4){0.f, 0.f, 0.f, 0.f};

    const short* ab = (const short*)wpack + wm * 4 * 512 + l * 8;
    const bf16x8 bz = (bf16x8){0, 0, 0, 0, 0, 0, 0, 0};

    #pragma unroll
    for (int kk = 0; kk < 9; ++kk) {
        const int ky = kk / 3, kx = kk % 3;
        #pragma unroll
        for (int icb = 0; icb < 2; ++icb) {
            bf16x8 a[4];
            #pragma unroll
            for (int mf = 0; mf < 4; ++mf)
                a[mf] = *(const bf16x8*)(ab + ((kk * 2 + icb) * 8 + mf) * 512);

            bf16x8 b[4];
            #pragma unroll
            for (int nf = 0; nf < 4; ++nf) {
                bf16x8 t = *(const bf16x8*)(pxb[nf] + (ky * 64 + kx) * 64 + icb * 32);
                bool dead = (ky == 2 && rOOB[nf]) || (kx == 2 && cOOB[nf]);
                b[nf] = dead ? bz : t;
            }
            #pragma unroll
            for (int mf = 0; mf < 4; ++mf)
                #pragma unroll
                for (int nf = 0; nf < 4; ++nf)
                    acc[mf][nf] = __builtin_amdgcn_mfma_f32_16x16x32_bf16(a[mf], b[nf], acc[mf][nf], 0, 0, 0);
        }
    }

    #pragma unroll
    for (int nf = 0; nf < 4; ++nf) {
        int pix = oyv[nf] * 32 + oxv[nf];
        short* ob = (short*)A2c + ((size_t)v * 1024 + pix) * 128 + wm * 64;
        #pragma unroll
        for (int mf = 0; mf < 4; ++mf) {
            f32x4 bv = *(const f32x4*)(b2 + wm * 64 + mf * 16 + lgrp * 4);
            s16x4 sv;
            #pragma unroll
            for (int r = 0; r < 4; ++r) sv[r] = f2bf(fmaxf(acc[mf][nf][r] + bv[r], 0.f));
            *(s16x4*)(ob + mf * 16 + lgrp * 4) = sv;
        }
    }
}

// ---------------- mean over views: A2c bf16 (50,1024,128) -> XBc bf16 (1024,128) ----------------
__global__ __launch_bounds__(256) void mean_kernel(const __hip_bfloat16* __restrict__ A2c,
                                                   __hip_bfloat16* __restrict__ XBc) {
    int i = blockIdx.x * 256 + threadIdx.x;   // 16384
    int g = i & 15, pix = i >> 4;
    float acc[8] = {0.f, 0.f, 0.f, 0.f, 0.f, 0.f, 0.f, 0.f};
    for (int v = 0; v < NVV; ++v) {
        bf16x8 x = *(const bf16x8*)((const short*)A2c + ((size_t)v * 1024 + pix) * 128 + g * 8);
        #pragma unroll
        for (int j = 0; j < 8; ++j) acc[j] += bf2f(x[j]);
    }
    bf16x8 o;
    #pragma unroll
    for (int j = 0; j < 8; ++j) o[j] = f2bf(acc[j] * (1.0f / NVV));
    *(bf16x8*)((short*)XBc + (size_t)pix * 128 + g * 8) = o;
}

// ---------------- conv3 implicit GEMM (fully unrolled K): grid (8 oc-tiles, 32 px-tiles), 2 waves ----------------
__global__ __launch_bounds__(128) void conv3_mfma(const __hip_bfloat16* __restrict__ XBc,
                                                  const __hip_bfloat16* __restrict__ wpack,
                                                  const float* __restrict__ b3,
                                                  __hip_bfloat16* __restrict__ VOLc) {
    int tid = threadIdx.x;
    int l = tid & 63;
    int wn = tid >> 6;                 // 2 waves over px
    int lane16 = l & 15, lgrp = l >> 4;

    int px = blockIdx.y * 32 + wn * 16 + lane16;   // 0..1023
    int y = px >> 5, x = px & 31;

    const short* pxb = (const short*)XBc + ((ptrdiff_t)(y - 1) * 32 + (x - 1)) * 128 + lgrp * 8;
    bool tOOB = (y == 0), bOOB = (y == 31), lOOB = (x == 0), rOOB = (x == 31);

    f32x4 acc[4];
    #pragma unroll
    for (int mf = 0; mf < 4; ++mf) acc[mf] = (f32x4){0.f, 0.f, 0.f, 0.f};

    const short* ab = (const short*)wpack + (size_t)blockIdx.x * 4 * 512 + l * 8;
    const bf16x8 bzv = (bf16x8){0, 0, 0, 0, 0, 0, 0, 0};

    #pragma unroll
    for (int kk = 0; kk < 9; ++kk) {
        const int ky = kk / 3, kx = kk % 3;
        bool dead = (ky == 0 && tOOB) || (ky == 2 && bOOB) || (kx == 0 && lOOB) || (kx == 2 && rOOB);
        #pragma unroll
        for (int icb = 0; icb < 4; ++icb) {
            bf16x8 t = *(const bf16x8*)(pxb + (ky * 32 + kx) * 128 + icb * 32);
            bf16x8 b = dead ? bzv : t;
            #pragma unroll
            for (int mf = 0; mf < 4; ++mf) {
                bf16x8 a = *(const bf16x8*)(ab + (size_t)((kk * 4 + icb) * 32 + mf) * 512);
                acc[mf] = __builtin_amdgcn_mfma_f32_16x16x32_bf16(a, b, acc[mf], 0, 0, 0);
            }
        }
    }

    int oc_base = blockIdx.x * 64;
    #pragma unroll
    for (int mf = 0; mf < 4; ++mf) {
        f32x4 bv = *(const f32x4*)(b3 + oc_base + mf * 16 + lgrp * 4);
        #pragma unroll
        for (int r = 0; r < 4; ++r) {
            int oc = oc_base + mf * 16 + lgrp * 4 + r;
            int c = oc >> 5, iz = oc & 31;
            VOLc[((size_t)((iz * 32 + y) * 32 + x)) * 16 + c] = __float2bfloat16(acc[mf][r] + bv[r]);
        }
    }
}

// ---------------- fused trilinear + 3-layer MLP via MFMA: 64 pts/wave, -> raw (S*H*W, 4) f32 ----------------
__global__ __launch_bounds__(256) void mlp_mfma(const __hip_bfloat16* __restrict__ VOLc,
                                                const float* __restrict__ rays,
                                                const __hip_bfloat16* __restrict__ wpm1,
                                                const __hip_bfloat16* __restrict__ wpm2,
                                                const __hip_bfloat16* __restrict__ wpm3,
                                                const float* __restrict__ mb2,
                                                const float* __restrict__ mb3,
                                                float* __restrict__ raw) {
    __shared__ short hbuf[4][32 * 72];
    int tid = threadIdx.x;
    int w = tid >> 6, l = tid & 63;
    int lane16 = l & 15, lgrp = l >> 4;
    short* hb = hbuf[w];

    // hoisted weight fragments (reused across both reps)
    bf16x8 a1[4];
    #pragma unroll
    for (int mf = 0; mf < 4; ++mf)
        a1[mf] = *(const bf16x8*)((const short*)wpm1 + (mf * 64 + l) * 8);
    bf16x8 a2[2][4];
    #pragma unroll
    for (int kb = 0; kb < 2; ++kb)
        #pragma unroll
        for (int mf = 0; mf < 4; ++mf)
            a2[kb][mf] = *(const bf16x8*)((const short*)wpm2 + ((kb * 4 + mf) * 64 + l) * 8);
    bf16x8 a3[2];
    a3[0] = *(const bf16x8*)((const short*)wpm3 + (0 * 64 + l) * 8);
    a3[1] = *(const bf16x8*)((const short*)wpm3 + (1 * 64 + l) * 8);

    const bf16x8 bz = (bf16x8){0, 0, 0, 0, 0, 0, 0, 0};
    const bf16x8 bbias = (bf16x8){(short)0x3F80, 0, 0, 0, 0, 0, 0, 0};

    for (int rep = 0; rep < 2; ++rep) {
        int P0 = blockIdx.x * 256 + w * 64 + rep * 32;

        int nfg = l >> 5, hf = (l >> 4) & 1;
        int n = P0 + nfg * 16 + lane16;
        int pix = n & 4095, s = n >> 12;
        float o0 = rays[pix], o1 = rays[4096 + pix], o2 = rays[2 * 4096 + pix];
        float d0 = rays[3 * 4096 + pix], d1 = rays[4 * 4096 + pix], d2 = rays[5 * 4096 + pix];
        float nearv = rays[6 * 4096 + pix], farv = rays[7 * 4096 + pix];
        float t = (float)s / 63.0f;
        float z = nearv + (farv - nearv) * t;
        float px = o0 + d0 * z, py = o1 + d1 * z, pz = o2 + d2 * z;
        float cx = fminf(fmaxf((px + 1.f) * 15.5f, 0.f), 31.f);
        float cy = fminf(fmaxf((py + 1.f) * 15.5f, 0.f), 31.f);
        float cz = fminf(fmaxf((pz + 1.f) * 15.5f, 0.f), 31.f);
        int ix = min((int)floorf(cx), 30);
        int iy = min((int)floorf(cy), 30);
        int iz = min((int)floorf(cz), 30);
        float fx = cx - (float)ix, fy = cy - (float)iy, fz = cz - (float)iz;
        float gx = 1.f - fx, gy = 1.f - fy, gz = 1.f - fz;
        float wv[8] = {gz * gy * gx, gz * gy * fx, gz * fy * gx, gz * fy * fx,
                       fz * gy * gx, fz * gy * fx, fz * fy * gx, fz * fy * fx};
        const int co[8] = {0, 16, 512, 528, 16384, 16400, 16896, 16912};
        int base = (iz * 32 + iy) * 32 + ix;
        const short* vp = (const short*)VOLc + (size_t)base * 16 + hf * 8;

        float f8[8] = {0.f, 0.f, 0.f, 0.f, 0.f, 0.f, 0.f, 0.f};
        #pragma unroll
        for (int c = 0; c < 8; ++c) {
            bf16x8 cv = *(const bf16x8*)(vp + co[c]);
            #pragma unroll
            for (int j = 0; j < 8; ++j) f8[j] += wv[c] * bf2f(cv[j]);
        }
        bf16x8 own;
        #pragma unroll
        for (int j = 0; j < 8; ++j) own[j] = f2bf(f8[j]);

        i32x4 oi = __builtin_bit_cast(i32x4, own);
        i32x4 si;
        si[0] = __shfl_xor(oi[0], 32);
        si[1] = __shfl_xor(oi[1], 32);
        si[2] = __shfl_xor(oi[2], 32);
        si[3] = __shfl_xor(oi[3], 32);
        bf16x8 swf = __builtin_bit_cast(bf16x8, si);

        bf16x8 b0 = (lgrp < 2) ? own : ((lgrp == 2) ? bbias : bz);
        bf16x8 b1 = (lgrp < 2) ? swf : ((lgrp == 2) ? bbias : bz);

        f32x4 acc1[4][2];
        #pragma unroll
        for (int mf = 0; mf < 4; ++mf) {
            acc1[mf][0] = (f32x4){0.f, 0.f, 0.f, 0.f};
            acc1[mf][1] = (f32x4){0.f, 0.f, 0.f, 0.f};
            acc1[mf][0] = __builtin_amdgcn_mfma_f32_16x16x32_bf16(a1[mf], b0, acc1[mf][0], 0, 0, 0);
            acc1[mf][1] = __builtin_amdgcn_mfma_f32_16x16x32_bf16(a1[mf], b1, acc1[mf][1], 0, 0, 0);
        }
        #pragma unroll
        for (int mf = 0; mf < 4; ++mf) {
            #pragma unroll
            for (int nf = 0; nf < 2; ++nf) {
                s16x4 sv;
                #pragma unroll
                for (int r = 0; r < 4; ++r) sv[r] = f2bf(fmaxf(acc1[mf][nf][r], 0.f));
                *(s16x4*)(hb + (nf * 16 + lane16) * 72 + mf * 16 + lgrp * 4) = sv;
            }
        }

        f32x4 acc2[4][2];
        #pragma unroll
        for (int mf = 0; mf < 4; ++mf) {
            acc2[mf][0] = (f32x4){0.f, 0.f, 0.f, 0.f};
            acc2[mf][1] = (f32x4){0.f, 0.f, 0.f, 0.f};
        }
        #pragma unroll
        for (int nf = 0; nf < 2; ++nf) {
            #pragma unroll
            for (int kb = 0; kb < 2; ++kb) {
                bf16x8 bh = *(const bf16x8*)(hb + (nf * 16 + lane16) * 72 + kb * 32 + lgrp * 8);
                #pragma unroll
                for (int mf = 0; mf < 4; ++mf)
                    acc2[mf][nf] = __builtin_amdgcn_mfma_f32_16x16x32_bf16(a2[kb][mf], bh, acc2[mf][nf], 0, 0, 0);
            }
        }
        #pragma unroll
        for (int mf = 0; mf < 4; ++mf) {
            f32x4 bv = *(const f32x4*)(mb2 + mf * 16 + lgrp * 4);
            #pragma unroll
            for (int nf = 0; nf < 2; ++nf) {
                s16x4 sv;
                #pragma unroll
                for (int r = 0; r < 4; ++r) sv[r] = f2bf(fmaxf(acc2[mf][nf][r] + bv[r], 0.f));
                *(s16x4*)(hb + (nf * 16 + lane16) * 72 + mf * 16 + lgrp * 4) = sv;
            }
        }

        f32x4 acc3[2];
        acc3[0] = (f32x4){0.f, 0.f, 0.f, 0.f};
        acc3[1] = (f32x4){0.f, 0.f, 0.f, 0.f};
        #pragma unroll
        for (int nf = 0; nf < 2; ++nf) {
            #pragma unroll
            for (int kb = 0; kb < 2; ++kb) {
                bf16x8 bh = *(const bf16x8*)(hb + (nf * 16 + lane16) * 72 + kb * 32 + lgrp * 8);
                acc3[nf] = __builtin_amdgcn_mfma_f32_16x16x32_bf16(a3[kb], bh, acc3[nf], 0, 0, 0);
            }
        }
        if (lgrp == 0) {
            f32x4 b3v = *(const f32x4*)(mb3);
            #pragma unroll
            for (int nf = 0; nf < 2; ++nf) {
                f32x4 o = acc3[nf] + b3v;
                *(f32x4*)(raw + (size_t)(P0 + nf * 16 + lane16) * 4) = o;
            }
        }
    }
}

// ---------------- volume rendering ----------------
__global__ __launch_bounds__(64) void render_kernel(const float* __restrict__ raw,
                                                    const float* __restrict__ rays,
                                                    float* __restrict__ out) {
    int pix = blockIdx.x * 64 + threadIdx.x;  // 4096
    float nearv = rays[6 * 4096 + pix], farv = rays[7 * 4096 + pix];
    float T = 1.f, r = 0.f, g = 0.f, b = 0.f, d = 0.f;
    float dz = (farv - nearv) * (1.f / 63.f);
    for (int s = 0; s < 64; ++s) {
        float t = (float)s / 63.0f;
        float z = nearv + (farv - nearv) * t;
        const float* rp = raw + ((size_t)(s * 4096) + pix) * 4;
        float r0 = rp[0], r1 = rp[1], r2 = rp[2], r3 = rp[3];
        float delta = (s == 63) ? 1e10f : dz;
        float sigma = fmaxf(r3, 0.f);
        float alpha = 1.f - __expf(-sigma * delta);
        float wt = alpha * T;
        r += wt * (1.f / (1.f + __expf(-r0)));
        g += wt * (1.f / (1.f + __expf(-r1)));
        b += wt * (1.f / (1.f + __expf(-r2)));
        d += wt * z;
        T *= (1.f - alpha + 1e-10f);
    }
    out[0 * 4096 + pix] = r;
    out[1 * 4096 + pix] = g;
    out[2 * 4096 + pix] = b;
    out[12288 + pix]    = d;
}

extern "C" void kernel_launch(void* const* d_in, const int* in_sizes, int n_in,
                              void* d_out, int out_size, void* d_ws, size_t ws_size,
                              hipStream_t stream) {
    const float* images = (const float*)d_in[0];
    const float* rays   = (const float*)d_in[1];
    const float* w1 = (const float*)d_in[2];
    const float* b1 = (const float*)d_in[3];
    const float* w2 = (const float*)d_in[4];
    const float* b2 = (const float*)d_in[5];
    const float* w3 = (const float*)d_in[6];
    const float* b3 = (const float*)d_in[7];
    const float* mw1 = (const float*)d_in[8];
    const float* mb1 = (const float*)d_in[9];
    const float* mw2 = (const float*)d_in[10];
    const float* mb2 = (const float*)d_in[11];
    const float* mw3 = (const float*)d_in[12];
    const float* mb3 = (const float*)d_in[13];
    float* out = (float*)d_out;

    // workspace layout
    float* ws  = (float*)d_ws;
    float* RAW = ws;                                           // 1048576 f
    __hip_bfloat16* A1c  = (__hip_bfloat16*)(RAW + 1048576);   // 13107200 bf16
    __hip_bfloat16* WPK2 = A1c + 13107200;                     // 73728
    __hip_bfloat16* WPK1 = WPK2 + 73728;                       // 2048
    __hip_bfloat16* VOLc = WPK1 + 2048;                        // 524288
    __hip_bfloat16* WPM1 = VOLc + 524288;                      // 2048
    __hip_bfloat16* WPM2 = WPM1 + 2048;                        // 4096
    __hip_bfloat16* WPM3 = WPM2 + 4096;                        // 1024
    __hip_bfloat16* A2c  = WPM3 + 1024;                        // 6553600
    __hip_bfloat16* XBc  = A2c + 6553600;                      // 131072
    __hip_bfloat16* WPK3 = XBc + 131072;                       // 589824

    pack_all<<<dim3(2628), dim3(256), 0, stream>>>(w1, w2, w3, mw1, mb1, mw2, mw3,
                                                   WPK1, WPK2, WPK3, WPM1, WPM2, WPM3);
    conv1_fused<<<dim3(16, NVV), dim3(256), 0, stream>>>(images, WPK1, b1, A1c);
    conv2_mfma<<<dim3(8, NVV), dim3(256), 0, stream>>>(A1c, WPK2, b2, A2c);
    mean_kernel<<<dim3(64), dim3(256), 0, stream>>>(A2c, XBc);
    conv3_mfma<<<dim3(8, 32), dim3(128), 0, stream>>>(XBc, WPK3, b3, VOLc);
    mlp_mfma<<<dim3(1024), dim3(256), 0, stream>>>(VOLc, rays, WPM1, WPM2, WPM3, mb2, mb3, RAW);
    render_kernel<<<dim3(64), dim3(64), 0, stream>>>(RAW, rays, out);
}

// Round 9
// 90.893 us; speedup vs baseline: 11.5727x; 1.2761x over previous
//
#include <hip/hip_runtime.h>
#include <hip/hip_bf16.h>

#define NVV 50
#define C1 64
#define C2 128
#define HW1 64
#define HW2 32

typedef short bf16x8 __attribute__((ext_vector_type(8)));
typedef short s16x4 __attribute__((ext_vector_type(4)));
typedef float f32x4 __attribute__((ext_vector_type(4)));
typedef int i32x4 __attribute__((ext_vector_type(4)));

__device__ inline short f2bf(float x) {
    unsigned u = __builtin_bit_cast(unsigned, x);
    unsigned r = (u + 0x7FFFu + ((u >> 16) & 1u)) >> 16;
    return (short)r;
}
__device__ inline float bf2f(short x) {
    unsigned u = ((unsigned)(unsigned short)x) << 16;
    return __builtin_bit_cast(float, u);
}

// ---------------- pack_all: all weight repacks in one kernel ----------------
__global__ __launch_bounds__(256) void pack_all(const float* __restrict__ w1,
                                                const float* __restrict__ w2,
                                                const float* __restrict__ w3,
                                                const float* __restrict__ mw1, const float* __restrict__ mb1,
                                                const float* __restrict__ mw2, const float* __restrict__ mw3,
                                                __hip_bfloat16* __restrict__ WPK1,
                                                __hip_bfloat16* __restrict__ WPK2,
                                                __hip_bfloat16* __restrict__ WPK3,
                                                __hip_bfloat16* __restrict__ WPM1,
                                                __hip_bfloat16* __restrict__ WPM2,
                                                __hip_bfloat16* __restrict__ WPM3) {
    int i = blockIdx.x * 256 + threadIdx.x;
    if (i < 2048) {
        int j = i & 7, l = (i >> 3) & 63, mf = i >> 9;
        int oc = mf * 16 + (l & 15);
        int k = (l >> 4) * 8 + j;
        WPK1[i] = __float2bfloat16(k < 27 ? w1[oc * 27 + k] : 0.f);
    } else if (i < 75776) {
        int q = i - 2048;
        int j = q & 7, l = (q >> 3) & 63;
        int rest = q >> 9;
        int mtile = rest & 7;
        rest >>= 3;
        int icb = rest & 1;
        int kk = rest >> 1;
        int oc = mtile * 16 + (l & 15);
        int ic = icb * 32 + (l >> 4) * 8 + j;
        int ky = kk / 3, kx = kk % 3;
        WPK2[q] = __float2bfloat16(w2[((oc * 64 + ic) * 3 + ky) * 3 + kx]);
    } else if (i < 665600) {
        int q = i - 75776;
        int j = q & 7, l = (q >> 3) & 63;
        int rest = q >> 9;
        int m = rest & 31;
        rest >>= 5;
        int icb = rest & 3;
        int kk = rest >> 2;
        int oc = m * 16 + (l & 15);
        int ic = icb * 32 + (l >> 4) * 8 + j;
        int ky = kk / 3, kx = kk % 3;
        WPK3[q] = __float2bfloat16(w3[((oc * 128 + ic) * 3 + ky) * 3 + kx]);
    } else if (i < 672768) {
        int q = i - 665600;
        if (q < 2048) {
            int j = q & 7, l = (q >> 3) & 63, mf = q >> 9;
            int nn = mf * 16 + (l & 15);
            int ch = (l >> 4) * 8 + j;
            float v = ch < 16 ? mw1[ch * 64 + nn] : (ch == 16 ? mb1[nn] : 0.f);
            WPM1[q] = __float2bfloat16(v);
        } else if (q < 6144) {
            int p = q - 2048;
            int j = p & 7, l = (p >> 3) & 63, f = p >> 9;
            int kb = f >> 2, mf = f & 3;
            int nn = mf * 16 + (l & 15);
            int k = kb * 32 + (l >> 4) * 8 + j;
            WPM2[p] = __float2bfloat16(mw2[k * 64 + nn]);
        } else {
            int p = q - 6144;
            int j = p & 7, l = (p >> 3) & 63, kb = p >> 9;
            int m = l & 15;
            int k = kb * 32 + (l >> 4) * 8 + j;
            WPM3[p] = __float2bfloat16(m < 4 ? mw3[k * 4 + m] : 0.f);
        }
    }
}

// ---------------- conv1 fused (im2col in LDS) : (50,3,128,128) fp32 -> A1c bf16 (v,y,x,64ch) ----------------
__global__ __launch_bounds__(256) void conv1_fused(const float* __restrict__ img,
                                                   const __hip_bfloat16* __restrict__ wpack,
                                                   const float* __restrict__ b1,
                                                   __hip_bfloat16* __restrict__ out) {
    __shared__ float tile[3 * 9 * 132];
    int oyb = blockIdx.x, v = blockIdx.y;
    int tid = threadIdx.x;
    const float* ip = img + (size_t)v * 3 * 128 * 128;
    int iy0 = oyb * 8;
    for (int idx = tid; idx < 3456; idx += 256) {
        int ix = idx & 127;
        int t = idx >> 7;
        int iyl = t % 9, ic = t / 9;
        int iy = iy0 + iyl;
        tile[(ic * 9 + iyl) * 132 + ix] = (iy < 128) ? ip[(ic * 128 + iy) * 128 + ix] : 0.f;
    }
    if (tid < 108) {
        int c = tid & 3;
        int t = tid >> 2;
        int iyl = t % 9, ic = t / 9;
        tile[(ic * 9 + iyl) * 132 + 128 + c] = 0.f;
    }
    __syncthreads();

    int l = tid & 63, w = tid >> 6;
    int lane16 = l & 15, lgrp = l >> 4;
    int oy = oyb * 4 + w;

    int offj[8];
    bool okj[8];
    #pragma unroll
    for (int j = 0; j < 8; ++j) {
        int k = lgrp * 8 + j;
        bool ok = k < 27;
        int kc = ok ? k : 0;
        int ic = kc / 9, r = kc % 9;
        int ky = r / 3, kx = r % 3;
        offj[j] = (ic * 9 + 2 * w + ky) * 132 + kx;
        okj[j] = ok;
    }

    bf16x8 a[4];
    #pragma unroll
    for (int mf = 0; mf < 4; ++mf)
        a[mf] = *(const bf16x8*)((const short*)wpack + (mf * 64 + l) * 8);

    f32x4 acc[4][4];
    #pragma unroll
    for (int mf = 0; mf < 4; ++mf)
        #pragma unroll
        for (int nf = 0; nf < 4; ++nf)
            acc[mf][nf] = (f32x4){0.f, 0.f, 0.f, 0.f};

    #pragma unroll
    for (int nf = 0; nf < 4; ++nf) {
        int ox = nf * 16 + lane16;
        bf16x8 b;
        #pragma unroll
        for (int j = 0; j < 8; ++j) {
            float x = tile[offj[j] + 2 * ox];
            b[j] = okj[j] ? f2bf(x) : (short)0;
        }
        #pragma unroll
        for (int mf = 0; mf < 4; ++mf)
            acc[mf][nf] = __builtin_amdgcn_mfma_f32_16x16x32_bf16(a[mf], b, acc[mf][nf], 0, 0, 0);
    }

    #pragma unroll
    for (int mf = 0; mf < 4; ++mf) {
        #pragma unroll
        for (int nf = 0; nf < 4; ++nf) {
            int px = (v * 64 + oy) * 64 + nf * 16 + lane16;
            s16x4 sv;
            #pragma unroll
            for (int r = 0; r < 4; ++r) {
                int oc = mf * 16 + lgrp * 4 + r;
                sv[r] = f2bf(fmaxf(acc[mf][nf][r] + b1[oc], 0.f));
            }
            *(s16x4*)((short*)out + (size_t)px * 64 + mf * 16 + lgrp * 4) = sv;
        }
    }
}

// ---------------- conv2 implicit GEMM (fully unrolled K): grid (16,50), 2 waves, 128 oc x 64 px ----------------
__global__ __launch_bounds__(128) void conv2_mfma(const __hip_bfloat16* __restrict__ A1c,
                                                  const __hip_bfloat16* __restrict__ wpack,
                                                  const float* __restrict__ b2,
                                                  __hip_bfloat16* __restrict__ A2c) {
    int v   = blockIdx.y;
    int oyb = blockIdx.x;                 // 16 row-pairs
    int tid = threadIdx.x;
    int l = tid & 63;
    int wm = tid >> 6;                    // 0..1 over oc halves
    int lane16 = l & 15, lgrp = l >> 4;

    int oxv[4], oyv[4];
    const short* pxb[4];
    bool rOOB[4], cOOB[4];
    const short* ibase = (const short*)A1c + (size_t)v * 64 * 64 * 64;
    #pragma unroll
    for (int nf = 0; nf < 4; ++nf) {
        int px = nf * 16 + lane16;        // 0..63
        int dy = px >> 5, ox = px & 31;
        oxv[nf] = ox;
        oyv[nf] = oyb * 2 + dy;
        pxb[nf] = ibase + ((size_t)(2 * oyv[nf]) * 64 + 2 * ox) * 64 + lgrp * 8;
        rOOB[nf] = (oyv[nf] == 31);
        cOOB[nf] = (ox == 31);
    }

    f32x4 acc[4][4];
    #pragma unroll
    for (int mf = 0; mf < 4; ++mf)
        #pragma unroll
        for (int nf = 0; nf < 4; ++nf)
            acc[mf][nf] = (f32x4){0.f, 0.f, 0.f, 0.f};

    const short* ab = (const short*)wpack + wm * 4 * 512 + l * 8;
    const bf16x8 bz = (bf16x8){0, 0, 0, 0, 0, 0, 0, 0};

    #pragma unroll
    for (int kk = 0; kk < 9; ++kk) {
        const int ky = kk / 3, kx = kk % 3;
        #pragma unroll
        for (int icb = 0; icb < 2; ++icb) {
            bf16x8 a[4];
            #pragma unroll
            for (int mf = 0; mf < 4; ++mf)
                a[mf] = *(const bf16x8*)(ab + ((kk * 2 + icb) * 8 + mf) * 512);

            bf16x8 b[4];
            #pragma unroll
            for (int nf = 0; nf < 4; ++nf) {
                bf16x8 t = *(const bf16x8*)(pxb[nf] + (ky * 64 + kx) * 64 + icb * 32);
                bool dead = (ky == 2 && rOOB[nf]) || (kx == 2 && cOOB[nf]);
                b[nf] = dead ? bz : t;
            }
            #pragma unroll
            for (int mf = 0; mf < 4; ++mf)
                #pragma unroll
                for (int nf = 0; nf < 4; ++nf)
                    acc[mf][nf] = __builtin_amdgcn_mfma_f32_16x16x32_bf16(a[mf], b[nf], acc[mf][nf], 0, 0, 0);
        }
    }

    #pragma unroll
    for (int nf = 0; nf < 4; ++nf) {
        int pix = oyv[nf] * 32 + oxv[nf];
        short* ob = (short*)A2c + ((size_t)v * 1024 + pix) * 128 + wm * 64;
        #pragma unroll
        for (int mf = 0; mf < 4; ++mf) {
            f32x4 bv = *(const f32x4*)(b2 + wm * 64 + mf * 16 + lgrp * 4);
            s16x4 sv;
            #pragma unroll
            for (int r = 0; r < 4; ++r) sv[r] = f2bf(fmaxf(acc[mf][nf][r] + bv[r], 0.f));
            *(s16x4*)(ob + mf * 16 + lgrp * 4) = sv;
        }
    }
}

// ---------------- mean over views: A2c bf16 (50,1024,128) -> XBc bf16 (1024,128) ----------------
__global__ __launch_bounds__(256) void mean_kernel(const __hip_bfloat16* __restrict__ A2c,
                                                   __hip_bfloat16* __restrict__ XBc) {
    int i = blockIdx.x * 256 + threadIdx.x;   // 16384
    int g = i & 15, pix = i >> 4;
    float acc[8] = {0.f, 0.f, 0.f, 0.f, 0.f, 0.f, 0.f, 0.f};
    for (int v = 0; v < NVV; ++v) {
        bf16x8 x = *(const bf16x8*)((const short*)A2c + ((size_t)v * 1024 + pix) * 128 + g * 8);
        #pragma unroll
        for (int j = 0; j < 8; ++j) acc[j] += bf2f(x[j]);
    }
    bf16x8 o;
    #pragma unroll
    for (int j = 0; j < 8; ++j) o[j] = f2bf(acc[j] * (1.0f / NVV));
    *(bf16x8*)((short*)XBc + (size_t)pix * 128 + g * 8) = o;
}

// ---------------- conv3 implicit GEMM (fully unrolled K): grid (8 oc-tiles, 32 px-tiles), 2 waves ----------------
__global__ __launch_bounds__(128) void conv3_mfma(const __hip_bfloat16* __restrict__ XBc,
                                                  const __hip_bfloat16* __restrict__ wpack,
                                                  const float* __restrict__ b3,
                                                  __hip_bfloat16* __restrict__ VOLc) {
    int tid = threadIdx.x;
    int l = tid & 63;
    int wn = tid >> 6;
    int lane16 = l & 15, lgrp = l >> 4;

    int px = blockIdx.y * 32 + wn * 16 + lane16;
    int y = px >> 5, x = px & 31;

    const short* pxb = (const short*)XBc + ((ptrdiff_t)(y - 1) * 32 + (x - 1)) * 128 + lgrp * 8;
    bool tOOB = (y == 0), bOOB = (y == 31), lOOB = (x == 0), rOOB = (x == 31);

    f32x4 acc[4];
    #pragma unroll
    for (int mf = 0; mf < 4; ++mf) acc[mf] = (f32x4){0.f, 0.f, 0.f, 0.f};

    const short* ab = (const short*)wpack + (size_t)blockIdx.x * 4 * 512 + l * 8;
    const bf16x8 bzv = (bf16x8){0, 0, 0, 0, 0, 0, 0, 0};

    #pragma unroll
    for (int kk = 0; kk < 9; ++kk) {
        const int ky = kk / 3, kx = kk % 3;
        bool dead = (ky == 0 && tOOB) || (ky == 2 && bOOB) || (kx == 0 && lOOB) || (kx == 2 && rOOB);
        #pragma unroll
        for (int icb = 0; icb < 4; ++icb) {
            bf16x8 t = *(const bf16x8*)(pxb + (ky * 32 + kx) * 128 + icb * 32);
            bf16x8 b = dead ? bzv : t;
            #pragma unroll
            for (int mf = 0; mf < 4; ++mf) {
                bf16x8 a = *(const bf16x8*)(ab + (size_t)((kk * 4 + icb) * 32 + mf) * 512);
                acc[mf] = __builtin_amdgcn_mfma_f32_16x16x32_bf16(a, b, acc[mf], 0, 0, 0);
            }
        }
    }

    int oc_base = blockIdx.x * 64;
    #pragma unroll
    for (int mf = 0; mf < 4; ++mf) {
        f32x4 bv = *(const f32x4*)(b3 + oc_base + mf * 16 + lgrp * 4);
        #pragma unroll
        for (int r = 0; r < 4; ++r) {
            int oc = oc_base + mf * 16 + lgrp * 4 + r;
            int c = oc >> 5, iz = oc & 31;
            VOLc[((size_t)((iz * 32 + y) * 32 + x)) * 16 + c] = __float2bfloat16(acc[mf][r] + bv[r]);
        }
    }
}

// ---------------- fused trilinear + MLP + volume render: wave = 1 pixel x 64 samples ----------------
__global__ __launch_bounds__(256) void mlp_render(const __hip_bfloat16* __restrict__ VOLc,
                                                  const float* __restrict__ rays,
                                                  const __hip_bfloat16* __restrict__ wpm1,
                                                  const __hip_bfloat16* __restrict__ wpm2,
                                                  const __hip_bfloat16* __restrict__ wpm3,
                                                  const float* __restrict__ mb2,
                                                  const float* __restrict__ mb3,
                                                  float* __restrict__ out) {
    __shared__ short hbuf[4][32 * 72];
    __shared__ f32x4 rawb[4][64];
    int tid = threadIdx.x;
    int w = tid >> 6, l = tid & 63;
    int lane16 = l & 15, lgrp = l >> 4;
    short* hb = hbuf[w];
    int pix = blockIdx.x * 4 + w;          // wave-uniform pixel

    // hoisted weight fragments
    bf16x8 a1[4];
    #pragma unroll
    for (int mf = 0; mf < 4; ++mf)
        a1[mf] = *(const bf16x8*)((const short*)wpm1 + (mf * 64 + l) * 8);
    bf16x8 a2[2][4];
    #pragma unroll
    for (int kb = 0; kb < 2; ++kb)
        #pragma unroll
        for (int mf = 0; mf < 4; ++mf)
            a2[kb][mf] = *(const bf16x8*)((const short*)wpm2 + ((kb * 4 + mf) * 64 + l) * 8);
    bf16x8 a3[2];
    a3[0] = *(const bf16x8*)((const short*)wpm3 + (0 * 64 + l) * 8);
    a3[1] = *(const bf16x8*)((const short*)wpm3 + (1 * 64 + l) * 8);
    f32x4 b3v = *(const f32x4*)(mb3);

    const bf16x8 bz = (bf16x8){0, 0, 0, 0, 0, 0, 0, 0};
    const bf16x8 bbias = (bf16x8){(short)0x3F80, 0, 0, 0, 0, 0, 0, 0};

    // wave-uniform ray data
    float o0 = rays[pix], o1 = rays[4096 + pix], o2 = rays[2 * 4096 + pix];
    float d0 = rays[3 * 4096 + pix], d1 = rays[4 * 4096 + pix], d2 = rays[5 * 4096 + pix];
    float nearv = rays[6 * 4096 + pix], farv = rays[7 * 4096 + pix];

    int nfg = l >> 5, hf = (l >> 4) & 1;

    for (int rep = 0; rep < 2; ++rep) {
        int s = rep * 32 + nfg * 16 + lane16;     // this lane's sample
        float t = (float)s / 63.0f;
        float z = nearv + (farv - nearv) * t;
        float px = o0 + d0 * z, py = o1 + d1 * z, pz = o2 + d2 * z;
        float cx = fminf(fmaxf((px + 1.f) * 15.5f, 0.f), 31.f);
        float cy = fminf(fmaxf((py + 1.f) * 15.5f, 0.f), 31.f);
        float cz = fminf(fmaxf((pz + 1.f) * 15.5f, 0.f), 31.f);
        int ix = min((int)floorf(cx), 30);
        int iy = min((int)floorf(cy), 30);
        int iz = min((int)floorf(cz), 30);
        float fx = cx - (float)ix, fy = cy - (float)iy, fz = cz - (float)iz;
        float gx = 1.f - fx, gy = 1.f - fy, gz = 1.f - fz;
        float wv[8] = {gz * gy * gx, gz * gy * fx, gz * fy * gx, gz * fy * fx,
                       fz * gy * gx, fz * gy * fx, fz * fy * gx, fz * fy * fx};
        const int co[8] = {0, 16, 512, 528, 16384, 16400, 16896, 16912};
        int base = (iz * 32 + iy) * 32 + ix;
        const short* vp = (const short*)VOLc + (size_t)base * 16 + hf * 8;

        float f8[8] = {0.f, 0.f, 0.f, 0.f, 0.f, 0.f, 0.f, 0.f};
        #pragma unroll
        for (int c = 0; c < 8; ++c) {
            bf16x8 cv = *(const bf16x8*)(vp + co[c]);
            #pragma unroll
            for (int j = 0; j < 8; ++j) f8[j] += wv[c] * bf2f(cv[j]);
        }
        bf16x8 own;
        #pragma unroll
        for (int j = 0; j < 8; ++j) own[j] = f2bf(f8[j]);

        i32x4 oi = __builtin_bit_cast(i32x4, own);
        i32x4 si;
        si[0] = __shfl_xor(oi[0], 32);
        si[1] = __shfl_xor(oi[1], 32);
        si[2] = __shfl_xor(oi[2], 32);
        si[3] = __shfl_xor(oi[3], 32);
        bf16x8 swf = __builtin_bit_cast(bf16x8, si);

        bf16x8 b0 = (lgrp < 2) ? own : ((lgrp == 2) ? bbias : bz);
        bf16x8 b1 = (lgrp < 2) ? swf : ((lgrp == 2) ? bbias : bz);

        f32x4 acc1[4][2];
        #pragma unroll
        for (int mf = 0; mf < 4; ++mf) {
            acc1[mf][0] = (f32x4){0.f, 0.f, 0.f, 0.f};
            acc1[mf][1] = (f32x4){0.f, 0.f, 0.f, 0.f};
            acc1[mf][0] = __builtin_amdgcn_mfma_f32_16x16x32_bf16(a1[mf], b0, acc1[mf][0], 0, 0, 0);
            acc1[mf][1] = __builtin_amdgcn_mfma_f32_16x16x32_bf16(a1[mf], b1, acc1[mf][1], 0, 0, 0);
        }
        #pragma unroll
        for (int mf = 0; mf < 4; ++mf) {
            #pragma unroll
            for (int nf = 0; nf < 2; ++nf) {
                s16x4 sv;
                #pragma unroll
                for (int r = 0; r < 4; ++r) sv[r] = f2bf(fmaxf(acc1[mf][nf][r], 0.f));
                *(s16x4*)(hb + (nf * 16 + lane16) * 72 + mf * 16 + lgrp * 4) = sv;
            }
        }

        f32x4 acc2[4][2];
        #pragma unroll
        for (int mf = 0; mf < 4; ++mf) {
            acc2[mf][0] = (f32x4){0.f, 0.f, 0.f, 0.f};
            acc2[mf][1] = (f32x4){0.f, 0.f, 0.f, 0.f};
        }
        #pragma unroll
        for (int nf = 0; nf < 2; ++nf) {
            #pragma unroll
            for (int kb = 0; kb < 2; ++kb) {
                bf16x8 bh = *(const bf16x8*)(hb + (nf * 16 + lane16) * 72 + kb * 32 + lgrp * 8);
                #pragma unroll
                for (int mf = 0; mf < 4; ++mf)
                    acc2[mf][nf] = __builtin_amdgcn_mfma_f32_16x16x32_bf16(a2[kb][mf], bh, acc2[mf][nf], 0, 0, 0);
            }
        }
        #pragma unroll
        for (int mf = 0; mf < 4; ++mf) {
            f32x4 bv = *(const f32x4*)(mb2 + mf * 16 + lgrp * 4);
            #pragma unroll
            for (int nf = 0; nf < 2; ++nf) {
                s16x4 sv;
                #pragma unroll
                for (int r = 0; r < 4; ++r) sv[r] = f2bf(fmaxf(acc2[mf][nf][r] + bv[r], 0.f));
                *(s16x4*)(hb + (nf * 16 + lane16) * 72 + mf * 16 + lgrp * 4) = sv;
            }
        }

        f32x4 acc3[2];
        acc3[0] = (f32x4){0.f, 0.f, 0.f, 0.f};
        acc3[1] = (f32x4){0.f, 0.f, 0.f, 0.f};
        #pragma unroll
        for (int nf = 0; nf < 2; ++nf) {
            #pragma unroll
            for (int kb = 0; kb < 2; ++kb) {
                bf16x8 bh = *(const bf16x8*)(hb + (nf * 16 + lane16) * 72 + kb * 32 + lgrp * 8);
                acc3[nf] = __builtin_amdgcn_mfma_f32_16x16x32_bf16(a3[kb], bh, acc3[nf], 0, 0, 0);
            }
        }
        if (lgrp == 0) {
            #pragma unroll
            for (int nf = 0; nf < 2; ++nf)
                rawb[w][rep * 32 + nf * 16 + lane16] = acc3[nf] + b3v;
        }
    }

    // ---- wave-parallel volume rendering: lane l = sample s = l ----
    f32x4 rv = rawb[w][l];
    float dz = (farv - nearv) * (1.f / 63.f);
    float zl = nearv + (farv - nearv) * ((float)l / 63.0f);
    float delta = (l == 63) ? 1e10f : dz;
    float sigma = fmaxf(rv[3], 0.f);
    float alpha = 1.f - __expf(-sigma * delta);
    float la = __builtin_log2f(1.f - alpha + 1e-10f);

    // inclusive prefix sum of la over the wave
    float inc = la;
    #pragma unroll
    for (int off = 1; off < 64; off <<= 1) {
        float y = __shfl_up(inc, off);
        if (l >= off) inc += y;
    }
    float T = __builtin_exp2f(inc - la);    // exclusive product
    float wt = alpha * T;

    float cr = wt / (1.f + __expf(-rv[0]));
    float cg = wt / (1.f + __expf(-rv[1]));
    float cb = wt / (1.f + __expf(-rv[2]));
    float cd = wt * zl;

    #pragma unroll
    for (int off = 32; off > 0; off >>= 1) {
        cr += __shfl_down(cr, off);
        cg += __shfl_down(cg, off);
        cb += __shfl_down(cb, off);
        cd += __shfl_down(cd, off);
    }
    if (l == 0) {
        out[pix]             = cr;
        out[4096 + pix]      = cg;
        out[2 * 4096 + pix]  = cb;
        out[12288 + pix]     = cd;
    }
}

extern "C" void kernel_launch(void* const* d_in, const int* in_sizes, int n_in,
                              void* d_out, int out_size, void* d_ws, size_t ws_size,
                              hipStream_t stream) {
    const float* images = (const float*)d_in[0];
    const float* rays   = (const float*)d_in[1];
    const float* w1 = (const float*)d_in[2];
    const float* b1 = (const float*)d_in[3];
    const float* w2 = (const float*)d_in[4];
    const float* b2 = (const float*)d_in[5];
    const float* w3 = (const float*)d_in[6];
    const float* b3 = (const float*)d_in[7];
    const float* mw1 = (const float*)d_in[8];
    const float* mb1 = (const float*)d_in[9];
    const float* mw2 = (const float*)d_in[10];
    const float* mb2 = (const float*)d_in[11];
    const float* mw3 = (const float*)d_in[12];
    const float* mb3 = (const float*)d_in[13];
    float* out = (float*)d_out;

    // workspace layout (bf16 region)
    __hip_bfloat16* A1c  = (__hip_bfloat16*)d_ws;              // 13107200 bf16
    __hip_bfloat16* WPK2 = A1c + 13107200;                     // 73728
    __hip_bfloat16* WPK1 = WPK2 + 73728;                       // 2048
    __hip_bfloat16* VOLc = WPK1 + 2048;                        // 524288
    __hip_bfloat16* WPM1 = VOLc + 524288;                      // 2048
    __hip_bfloat16* WPM2 = WPM1 + 2048;                        // 4096
    __hip_bfloat16* WPM3 = WPM2 + 4096;                        // 1024
    __hip_bfloat16* A2c  = WPM3 + 1024;                        // 6553600
    __hip_bfloat16* XBc  = A2c + 6553600;                      // 131072
    __hip_bfloat16* WPK3 = XBc + 131072;                       // 589824

    pack_all<<<dim3(2628), dim3(256), 0, stream>>>(w1, w2, w3, mw1, mb1, mw2, mw3,
                                                   WPK1, WPK2, WPK3, WPM1, WPM2, WPM3);
    conv1_fused<<<dim3(16, NVV), dim3(256), 0, stream>>>(images, WPK1, b1, A1c);
    conv2_mfma<<<dim3(16, NVV), dim3(128), 0, stream>>>(A1c, WPK2, b2, A2c);
    mean_kernel<<<dim3(64), dim3(256), 0, stream>>>(A2c, XBc);
    conv3_mfma<<<dim3(8, 32), dim3(128), 0, stream>>>(XBc, WPK3, b3, VOLc);
    mlp_render<<<dim3(1024), dim3(256), 0, stream>>>(VOLc, rays, WPM1, WPM2, WPM3, mb2, mb3, out);
}

// Round 10
// 86.777 us; speedup vs baseline: 12.1215x; 1.0474x over previous
//
#include <hip/hip_runtime.h>
#include <hip/hip_bf16.h>

#define NVV 50
#define C1 64
#define C2 128
#define HW1 64
#define HW2 32

typedef short bf16x8 __attribute__((ext_vector_type(8)));
typedef short s16x4 __attribute__((ext_vector_type(4)));
typedef float f32x4 __attribute__((ext_vector_type(4)));
typedef int i32x4 __attribute__((ext_vector_type(4)));

__device__ inline short f2bf(float x) {
    unsigned u = __builtin_bit_cast(unsigned, x);
    unsigned r = (u + 0x7FFFu + ((u >> 16) & 1u)) >> 16;
    return (short)r;
}
__device__ inline float bf2f(short x) {
    unsigned u = ((unsigned)(unsigned short)x) << 16;
    return __builtin_bit_cast(float, u);
}

// ---------------- pack_all: all weight repacks in one kernel ----------------
__global__ __launch_bounds__(256) void pack_all(const float* __restrict__ w1,
                                                const float* __restrict__ w2,
                                                const float* __restrict__ w3,
                                                const float* __restrict__ mw1, const float* __restrict__ mb1,
                                                const float* __restrict__ mw2, const float* __restrict__ mw3,
                                                __hip_bfloat16* __restrict__ WPK1,
                                                __hip_bfloat16* __restrict__ WPK2,
                                                __hip_bfloat16* __restrict__ WPK3,
                                                __hip_bfloat16* __restrict__ WPM1,
                                                __hip_bfloat16* __restrict__ WPM2,
                                                __hip_bfloat16* __restrict__ WPM3) {
    int i = blockIdx.x * 256 + threadIdx.x;
    if (i < 2048) {
        int j = i & 7, l = (i >> 3) & 63, mf = i >> 9;
        int oc = mf * 16 + (l & 15);
        int k = (l >> 4) * 8 + j;
        WPK1[i] = __float2bfloat16(k < 27 ? w1[oc * 27 + k] : 0.f);
    } else if (i < 75776) {
        int q = i - 2048;
        int j = q & 7, l = (q >> 3) & 63;
        int rest = q >> 9;
        int mtile = rest & 7;
        rest >>= 3;
        int icb = rest & 1;
        int kk = rest >> 1;
        int oc = mtile * 16 + (l & 15);
        int ic = icb * 32 + (l >> 4) * 8 + j;
        int ky = kk / 3, kx = kk % 3;
        WPK2[q] = __float2bfloat16(w2[((oc * 64 + ic) * 3 + ky) * 3 + kx]);
    } else if (i < 665600) {
        int q = i - 75776;
        int j = q & 7, l = (q >> 3) & 63;
        int rest = q >> 9;
        int m = rest & 31;
        rest >>= 5;
        int icb = rest & 3;
        int kk = rest >> 2;
        int oc = m * 16 + (l & 15);
        int ic = icb * 32 + (l >> 4) * 8 + j;
        int ky = kk / 3, kx = kk % 3;
        WPK3[q] = __float2bfloat16(w3[((oc * 128 + ic) * 3 + ky) * 3 + kx]);
    } else if (i < 672768) {
        int q = i - 665600;
        if (q < 2048) {
            int j = q & 7, l = (q >> 3) & 63, mf = q >> 9;
            int nn = mf * 16 + (l & 15);
            int ch = (l >> 4) * 8 + j;
            float v = ch < 16 ? mw1[ch * 64 + nn] : (ch == 16 ? mb1[nn] : 0.f);
            WPM1[q] = __float2bfloat16(v);
        } else if (q < 6144) {
            int p = q - 2048;
            int j = p & 7, l = (p >> 3) & 63, f = p >> 9;
            int kb = f >> 2, mf = f & 3;
            int nn = mf * 16 + (l & 15);
            int k = kb * 32 + (l >> 4) * 8 + j;
            WPM2[p] = __float2bfloat16(mw2[k * 64 + nn]);
        } else {
            int p = q - 6144;
            int j = p & 7, l = (p >> 3) & 63, kb = p >> 9;
            int m = l & 15;
            int k = kb * 32 + (l >> 4) * 8 + j;
            WPM3[p] = __float2bfloat16(m < 4 ? mw3[k * 4 + m] : 0.f);
        }
    }
}

// XCD-locality grid: b = xcd + 8*slot; view v = xcd + 8*(slot/16); all of view v's
// blocks land on XCD v%8 (assumes standard round-robin blockIdx->XCD). Grid = 896.

// ---------------- conv1 fused (im2col in LDS) : (50,3,128,128) fp32 -> A1c bf16 (v,y,x,64ch) ----------------
__global__ __launch_bounds__(256) void conv1_fused(const float* __restrict__ img,
                                                   const __hip_bfloat16* __restrict__ wpack,
                                                   const float* __restrict__ b1,
                                                   __hip_bfloat16* __restrict__ out) {
    __shared__ float tile[3 * 9 * 132];
    int b = blockIdx.x;
    int xcd = b & 7, slot = b >> 3;
    int v = xcd + 8 * (slot >> 4);
    int oyb = slot & 15;
    if (v >= NVV) return;
    int tid = threadIdx.x;
    const float* ip = img + (size_t)v * 3 * 128 * 128;
    int iy0 = oyb * 8;
    for (int idx = tid; idx < 3456; idx += 256) {
        int ix = idx & 127;
        int t = idx >> 7;
        int iyl = t % 9, ic = t / 9;
        int iy = iy0 + iyl;
        tile[(ic * 9 + iyl) * 132 + ix] = (iy < 128) ? ip[(ic * 128 + iy) * 128 + ix] : 0.f;
    }
    if (tid < 108) {
        int c = tid & 3;
        int t = tid >> 2;
        int iyl = t % 9, ic = t / 9;
        tile[(ic * 9 + iyl) * 132 + 128 + c] = 0.f;
    }
    __syncthreads();

    int l = tid & 63, w = tid >> 6;
    int lane16 = l & 15, lgrp = l >> 4;
    int oy = oyb * 4 + w;

    int offj[8];
    bool okj[8];
    #pragma unroll
    for (int j = 0; j < 8; ++j) {
        int k = lgrp * 8 + j;
        bool ok = k < 27;
        int kc = ok ? k : 0;
        int ic = kc / 9, r = kc % 9;
        int ky = r / 3, kx = r % 3;
        offj[j] = (ic * 9 + 2 * w + ky) * 132 + kx;
        okj[j] = ok;
    }

    bf16x8 a[4];
    #pragma unroll
    for (int mf = 0; mf < 4; ++mf)
        a[mf] = *(const bf16x8*)((const short*)wpack + (mf * 64 + l) * 8);

    f32x4 acc[4][4];
    #pragma unroll
    for (int mf = 0; mf < 4; ++mf)
        #pragma unroll
        for (int nf = 0; nf < 4; ++nf)
            acc[mf][nf] = (f32x4){0.f, 0.f, 0.f, 0.f};

    #pragma unroll
    for (int nf = 0; nf < 4; ++nf) {
        int ox = nf * 16 + lane16;
        bf16x8 bb;
        #pragma unroll
        for (int j = 0; j < 8; ++j) {
            float x = tile[offj[j] + 2 * ox];
            bb[j] = okj[j] ? f2bf(x) : (short)0;
        }
        #pragma unroll
        for (int mf = 0; mf < 4; ++mf)
            acc[mf][nf] = __builtin_amdgcn_mfma_f32_16x16x32_bf16(a[mf], bb, acc[mf][nf], 0, 0, 0);
    }

    #pragma unroll
    for (int mf = 0; mf < 4; ++mf) {
        #pragma unroll
        for (int nf = 0; nf < 4; ++nf) {
            int px = (v * 64 + oy) * 64 + nf * 16 + lane16;
            s16x4 sv;
            #pragma unroll
            for (int r = 0; r < 4; ++r) {
                int oc = mf * 16 + lgrp * 4 + r;
                sv[r] = f2bf(fmaxf(acc[mf][nf][r] + b1[oc], 0.f));
            }
            *(s16x4*)((short*)out + (size_t)px * 64 + mf * 16 + lgrp * 4) = sv;
        }
    }
}

// ---------------- conv2 implicit GEMM (fully unrolled K): 2 waves, 128 oc x 64 px ----------------
__global__ __launch_bounds__(128) void conv2_mfma(const __hip_bfloat16* __restrict__ A1c,
                                                  const __hip_bfloat16* __restrict__ wpack,
                                                  const float* __restrict__ b2,
                                                  __hip_bfloat16* __restrict__ A2c) {
    int b = blockIdx.x;
    int xcd = b & 7, slot = b >> 3;
    int v = xcd + 8 * (slot >> 4);
    int oyb = slot & 15;                  // 16 row-pairs
    if (v >= NVV) return;
    int tid = threadIdx.x;
    int l = tid & 63;
    int wm = tid >> 6;                    // 0..1 over oc halves
    int lane16 = l & 15, lgrp = l >> 4;

    int oxv[4], oyv[4];
    const short* pxb[4];
    bool rOOB[4], cOOB[4];
    const short* ibase = (const short*)A1c + (size_t)v * 64 * 64 * 64;
    #pragma unroll
    for (int nf = 0; nf < 4; ++nf) {
        int px = nf * 16 + lane16;        // 0..63
        int dy = px >> 5, ox = px & 31;
        oxv[nf] = ox;
        oyv[nf] = oyb * 2 + dy;
        pxb[nf] = ibase + ((size_t)(2 * oyv[nf]) * 64 + 2 * ox) * 64 + lgrp * 8;
        rOOB[nf] = (oyv[nf] == 31);
        cOOB[nf] = (ox == 31);
    }

    f32x4 acc[4][4];
    #pragma unroll
    for (int mf = 0; mf < 4; ++mf)
        #pragma unroll
        for (int nf = 0; nf < 4; ++nf)
            acc[mf][nf] = (f32x4){0.f, 0.f, 0.f, 0.f};

    const short* ab = (const short*)wpack + wm * 4 * 512 + l * 8;
    const bf16x8 bz = (bf16x8){0, 0, 0, 0, 0, 0, 0, 0};

    #pragma unroll
    for (int kk = 0; kk < 9; ++kk) {
        const int ky = kk / 3, kx = kk % 3;
        #pragma unroll
        for (int icb = 0; icb < 2; ++icb) {
            bf16x8 a[4];
            #pragma unroll
            for (int mf = 0; mf < 4; ++mf)
                a[mf] = *(const bf16x8*)(ab + ((kk * 2 + icb) * 8 + mf) * 512);

            bf16x8 bb[4];
            #pragma unroll
            for (int nf = 0; nf < 4; ++nf) {
                bf16x8 t = *(const bf16x8*)(pxb[nf] + (ky * 64 + kx) * 64 + icb * 32);
                bool dead = (ky == 2 && rOOB[nf]) || (kx == 2 && cOOB[nf]);
                bb[nf] = dead ? bz : t;
            }
            #pragma unroll
            for (int mf = 0; mf < 4; ++mf)
                #pragma unroll
                for (int nf = 0; nf < 4; ++nf)
                    acc[mf][nf] = __builtin_amdgcn_mfma_f32_16x16x32_bf16(a[mf], bb[nf], acc[mf][nf], 0, 0, 0);
        }
    }

    #pragma unroll
    for (int nf = 0; nf < 4; ++nf) {
        int pix = oyv[nf] * 32 + oxv[nf];
        short* ob = (short*)A2c + ((size_t)v * 1024 + pix) * 128 + wm * 64;
        #pragma unroll
        for (int mf = 0; mf < 4; ++mf) {
            f32x4 bv = *(const f32x4*)(b2 + wm * 64 + mf * 16 + lgrp * 4);
            s16x4 sv;
            #pragma unroll
            for (int r = 0; r < 4; ++r) sv[r] = f2bf(fmaxf(acc[mf][nf][r] + bv[r], 0.f));
            *(s16x4*)(ob + mf * 16 + lgrp * 4) = sv;
        }
    }
}

// ---------------- mean over views: A2c bf16 (50,1024,128) -> XBc bf16 (1024,128) ----------------
__global__ __launch_bounds__(256) void mean_kernel(const __hip_bfloat16* __restrict__ A2c,
                                                   __hip_bfloat16* __restrict__ XBc) {
    int i = blockIdx.x * 256 + threadIdx.x;   // 16384
    int g = i & 15, pix = i >> 4;
    float acc[8] = {0.f, 0.f, 0.f, 0.f, 0.f, 0.f, 0.f, 0.f};
    for (int v = 0; v < NVV; ++v) {
        bf16x8 x = *(const bf16x8*)((const short*)A2c + ((size_t)v * 1024 + pix) * 128 + g * 8);
        #pragma unroll
        for (int j = 0; j < 8; ++j) acc[j] += bf2f(x[j]);
    }
    bf16x8 o;
    #pragma unroll
    for (int j = 0; j < 8; ++j) o[j] = f2bf(acc[j] * (1.0f / NVV));
    *(bf16x8*)((short*)XBc + (size_t)pix * 128 + g * 8) = o;
}

// ---------------- conv3 implicit GEMM (fully unrolled K): grid (8 oc-tiles, 32 px-tiles), 2 waves ----------------
__global__ __launch_bounds__(128) void conv3_mfma(const __hip_bfloat16* __restrict__ XBc,
                                                  const __hip_bfloat16* __restrict__ wpack,
                                                  const float* __restrict__ b3,
                                                  __hip_bfloat16* __restrict__ VOLc) {
    int tid = threadIdx.x;
    int l = tid & 63;
    int wn = tid >> 6;
    int lane16 = l & 15, lgrp = l >> 4;

    int px = blockIdx.y * 32 + wn * 16 + lane16;
    int y = px >> 5, x = px & 31;

    const short* pxb = (const short*)XBc + ((ptrdiff_t)(y - 1) * 32 + (x - 1)) * 128 + lgrp * 8;
    bool tOOB = (y == 0), bOOB = (y == 31), lOOB = (x == 0), rOOB = (x == 31);

    f32x4 acc[4];
    #pragma unroll
    for (int mf = 0; mf < 4; ++mf) acc[mf] = (f32x4){0.f, 0.f, 0.f, 0.f};

    const short* ab = (const short*)wpack + (size_t)blockIdx.x * 4 * 512 + l * 8;
    const bf16x8 bzv = (bf16x8){0, 0, 0, 0, 0, 0, 0, 0};

    #pragma unroll
    for (int kk = 0; kk < 9; ++kk) {
        const int ky = kk / 3, kx = kk % 3;
        bool dead = (ky == 0 && tOOB) || (ky == 2 && bOOB) || (kx == 0 && lOOB) || (kx == 2 && rOOB);
        #pragma unroll
        for (int icb = 0; icb < 4; ++icb) {
            bf16x8 t = *(const bf16x8*)(pxb + (ky * 32 + kx) * 128 + icb * 32);
            bf16x8 bb = dead ? bzv : t;
            #pragma unroll
            for (int mf = 0; mf < 4; ++mf) {
                bf16x8 a = *(const bf16x8*)(ab + (size_t)((kk * 4 + icb) * 32 + mf) * 512);
                acc[mf] = __builtin_amdgcn_mfma_f32_16x16x32_bf16(a, bb, acc[mf], 0, 0, 0);
            }
        }
    }

    int oc_base = blockIdx.x * 64;
    #pragma unroll
    for (int mf = 0; mf < 4; ++mf) {
        f32x4 bv = *(const f32x4*)(b3 + oc_base + mf * 16 + lgrp * 4);
        #pragma unroll
        for (int r = 0; r < 4; ++r) {
            int oc = oc_base + mf * 16 + lgrp * 4 + r;
            int c = oc >> 5, iz = oc & 31;
            VOLc[((size_t)((iz * 32 + y) * 32 + x)) * 16 + c] = __float2bfloat16(acc[mf][r] + bv[r]);
        }
    }
}

// ---------------- fused trilinear + MLP + volume render: wave = 1 pixel x 64 samples ----------------
__global__ __launch_bounds__(256) void mlp_render(const __hip_bfloat16* __restrict__ VOLc,
                                                  const float* __restrict__ rays,
                                                  const __hip_bfloat16* __restrict__ wpm1,
                                                  const __hip_bfloat16* __restrict__ wpm2,
                                                  const __hip_bfloat16* __restrict__ wpm3,
                                                  const float* __restrict__ mb2,
                                                  const float* __restrict__ mb3,
                                                  float* __restrict__ out) {
    __shared__ short hbuf[4][32 * 72];
    __shared__ f32x4 rawb[4][64];
    int tid = threadIdx.x;
    int w = tid >> 6, l = tid & 63;
    int lane16 = l & 15, lgrp = l >> 4;
    short* hb = hbuf[w];
    int pix = blockIdx.x * 4 + w;          // wave-uniform pixel

    // hoisted weight fragments
    bf16x8 a1[4];
    #pragma unroll
    for (int mf = 0; mf < 4; ++mf)
        a1[mf] = *(const bf16x8*)((const short*)wpm1 + (mf * 64 + l) * 8);
    bf16x8 a2[2][4];
    #pragma unroll
    for (int kb = 0; kb < 2; ++kb)
        #pragma unroll
        for (int mf = 0; mf < 4; ++mf)
            a2[kb][mf] = *(const bf16x8*)((const short*)wpm2 + ((kb * 4 + mf) * 64 + l) * 8);
    bf16x8 a3[2];
    a3[0] = *(const bf16x8*)((const short*)wpm3 + (0 * 64 + l) * 8);
    a3[1] = *(const bf16x8*)((const short*)wpm3 + (1 * 64 + l) * 8);
    f32x4 b3v = *(const f32x4*)(mb3);

    const bf16x8 bz = (bf16x8){0, 0, 0, 0, 0, 0, 0, 0};
    const bf16x8 bbias = (bf16x8){(short)0x3F80, 0, 0, 0, 0, 0, 0, 0};

    // wave-uniform ray data
    float o0 = rays[pix], o1 = rays[4096 + pix], o2 = rays[2 * 4096 + pix];
    float d0 = rays[3 * 4096 + pix], d1 = rays[4 * 4096 + pix], d2 = rays[5 * 4096 + pix];
    float nearv = rays[6 * 4096 + pix], farv = rays[7 * 4096 + pix];

    int nfg = l >> 5, hf = (l >> 4) & 1;

    for (int rep = 0; rep < 2; ++rep) {
        int s = rep * 32 + nfg * 16 + lane16;     // this lane's sample
        float t = (float)s / 63.0f;
        float z = nearv + (farv - nearv) * t;
        float px = o0 + d0 * z, py = o1 + d1 * z, pz = o2 + d2 * z;
        float cx = fminf(fmaxf((px + 1.f) * 15.5f, 0.f), 31.f);
        float cy = fminf(fmaxf((py + 1.f) * 15.5f, 0.f), 31.f);
        float cz = fminf(fmaxf((pz + 1.f) * 15.5f, 0.f), 31.f);
        int ix = min((int)floorf(cx), 30);
        int iy = min((int)floorf(cy), 30);
        int iz = min((int)floorf(cz), 30);
        float fx = cx - (float)ix, fy = cy - (float)iy, fz = cz - (float)iz;
        float gx = 1.f - fx, gy = 1.f - fy, gz = 1.f - fz;
        float wv[8] = {gz * gy * gx, gz * gy * fx, gz * fy * gx, gz * fy * fx,
                       fz * gy * gx, fz * gy * fx, fz * fy * gx, fz * fy * fx};
        const int co[8] = {0, 16, 512, 528, 16384, 16400, 16896, 16912};
        int base = (iz * 32 + iy) * 32 + ix;
        const short* vp = (const short*)VOLc + (size_t)base * 16 + hf * 8;

        float f8[8] = {0.f, 0.f, 0.f, 0.f, 0.f, 0.f, 0.f, 0.f};
        #pragma unroll
        for (int c = 0; c < 8; ++c) {
            bf16x8 cv = *(const bf16x8*)(vp + co[c]);
            #pragma unroll
            for (int j = 0; j < 8; ++j) f8[j] += wv[c] * bf2f(cv[j]);
        }
        bf16x8 own;
        #pragma unroll
        for (int j = 0; j < 8; ++j) own[j] = f2bf(f8[j]);

        i32x4 oi = __builtin_bit_cast(i32x4, own);
        i32x4 si;
        si[0] = __shfl_xor(oi[0], 32);
        si[1] = __shfl_xor(oi[1], 32);
        si[2] = __shfl_xor(oi[2], 32);
        si[3] = __shfl_xor(oi[3], 32);
        bf16x8 swf = __builtin_bit_cast(bf16x8, si);

        bf16x8 b0 = (lgrp < 2) ? own : ((lgrp == 2) ? bbias : bz);
        bf16x8 b1 = (lgrp < 2) ? swf : ((lgrp == 2) ? bbias : bz);

        f32x4 acc1[4][2];
        #pragma unroll
        for (int mf = 0; mf < 4; ++mf) {
            acc1[mf][0] = (f32x4){0.f, 0.f, 0.f, 0.f};
            acc1[mf][1] = (f32x4){0.f, 0.f, 0.f, 0.f};
            acc1[mf][0] = __builtin_amdgcn_mfma_f32_16x16x32_bf16(a1[mf], b0, acc1[mf][0], 0, 0, 0);
            acc1[mf][1] = __builtin_amdgcn_mfma_f32_16x16x32_bf16(a1[mf], b1, acc1[mf][1], 0, 0, 0);
        }
        #pragma unroll
        for (int mf = 0; mf < 4; ++mf) {
            #pragma unroll
            for (int nf = 0; nf < 2; ++nf) {
                s16x4 sv;
                #pragma unroll
                for (int r = 0; r < 4; ++r) sv[r] = f2bf(fmaxf(acc1[mf][nf][r], 0.f));
                *(s16x4*)(hb + (nf * 16 + lane16) * 72 + mf * 16 + lgrp * 4) = sv;
            }
        }

        f32x4 acc2[4][2];
        #pragma unroll
        for (int mf = 0; mf < 4; ++mf) {
            acc2[mf][0] = (f32x4){0.f, 0.f, 0.f, 0.f};
            acc2[mf][1] = (f32x4){0.f, 0.f, 0.f, 0.f};
        }
        #pragma unroll
        for (int nf = 0; nf < 2; ++nf) {
            #pragma unroll
            for (int kb = 0; kb < 2; ++kb) {
                bf16x8 bh = *(const bf16x8*)(hb + (nf * 16 + lane16) * 72 + kb * 32 + lgrp * 8);
                #pragma unroll
                for (int mf = 0; mf < 4; ++mf)
                    acc2[mf][nf] = __builtin_amdgcn_mfma_f32_16x16x32_bf16(a2[kb][mf], bh, acc2[mf][nf], 0, 0, 0);
            }
        }
        #pragma unroll
        for (int mf = 0; mf < 4; ++mf) {
            f32x4 bv = *(const f32x4*)(mb2 + mf * 16 + lgrp * 4);
            #pragma unroll
            for (int nf = 0; nf < 2; ++nf) {
                s16x4 sv;
                #pragma unroll
                for (int r = 0; r < 4; ++r) sv[r] = f2bf(fmaxf(acc2[mf][nf][r] + bv[r], 0.f));
                *(s16x4*)(hb + (nf * 16 + lane16) * 72 + mf * 16 + lgrp * 4) = sv;
            }
        }

        f32x4 acc3[2];
        acc3[0] = (f32x4){0.f, 0.f, 0.f, 0.f};
        acc3[1] = (f32x4){0.f, 0.f, 0.f, 0.f};
        #pragma unroll
        for (int nf = 0; nf < 2; ++nf) {
            #pragma unroll
            for (int kb = 0; kb < 2; ++kb) {
                bf16x8 bh = *(const bf16x8*)(hb + (nf * 16 + lane16) * 72 + kb * 32 + lgrp * 8);
                acc3[nf] = __builtin_amdgcn_mfma_f32_16x16x32_bf16(a3[kb], bh, acc3[nf], 0, 0, 0);
            }
        }
        if (lgrp == 0) {
            #pragma unroll
            for (int nf = 0; nf < 2; ++nf)
                rawb[w][rep * 32 + nf * 16 + lane16] = acc3[nf] + b3v;
        }
    }

    // ---- wave-parallel volume rendering: lane l = sample s = l ----
    f32x4 rv = rawb[w][l];
    float dz = (farv - nearv) * (1.f / 63.f);
    float zl = nearv + (farv - nearv) * ((float)l / 63.0f);
    float delta = (l == 63) ? 1e10f : dz;
    float sigma = fmaxf(rv[3], 0.f);
    float alpha = 1.f - __expf(-sigma * delta);
    float la = __builtin_log2f(1.f - alpha + 1e-10f);

    // inclusive prefix sum of la over the wave
    float inc = la;
    #pragma unroll
    for (int off = 1; off < 64; off <<= 1) {
        float y = __shfl_up(inc, off);
        if (l >= off) inc += y;
    }
    float T = __builtin_exp2f(inc - la);    // exclusive product
    float wt = alpha * T;

    float cr = wt / (1.f + __expf(-rv[0]));
    float cg = wt / (1.f + __expf(-rv[1]));
    float cb = wt / (1.f + __expf(-rv[2]));
    float cd = wt * zl;

    #pragma unroll
    for (int off = 32; off > 0; off >>= 1) {
        cr += __shfl_down(cr, off);
        cg += __shfl_down(cg, off);
        cb += __shfl_down(cb, off);
        cd += __shfl_down(cd, off);
    }
    if (l == 0) {
        out[pix]             = cr;
        out[4096 + pix]      = cg;
        out[2 * 4096 + pix]  = cb;
        out[12288 + pix]     = cd;
    }
}

extern "C" void kernel_launch(void* const* d_in, const int* in_sizes, int n_in,
                              void* d_out, int out_size, void* d_ws, size_t ws_size,
                              hipStream_t stream) {
    const float* images = (const float*)d_in[0];
    const float* rays   = (const float*)d_in[1];
    const float* w1 = (const float*)d_in[2];
    const float* b1 = (const float*)d_in[3];
    const float* w2 = (const float*)d_in[4];
    const float* b2 = (const float*)d_in[5];
    const float* w3 = (const float*)d_in[6];
    const float* b3 = (const float*)d_in[7];
    const float* mw1 = (const float*)d_in[8];
    const float* mb1 = (const float*)d_in[9];
    const float* mw2 = (const float*)d_in[10];
    const float* mb2 = (const float*)d_in[11];
    const float* mw3 = (const float*)d_in[12];
    const float* mb3 = (const float*)d_in[13];
    float* out = (float*)d_out;

    // workspace layout (bf16 region)
    __hip_bfloat16* A1c  = (__hip_bfloat16*)d_ws;              // 13107200 bf16
    __hip_bfloat16* WPK2 = A1c + 13107200;                     // 73728
    __hip_bfloat16* WPK1 = WPK2 + 73728;                       // 2048
    __hip_bfloat16* VOLc = WPK1 + 2048;                        // 524288
    __hip_bfloat16* WPM1 = VOLc + 524288;                      // 2048
    __hip_bfloat16* WPM2 = WPM1 + 2048;                        // 4096
    __hip_bfloat16* WPM3 = WPM2 + 4096;                        // 1024
    __hip_bfloat16* A2c  = WPM3 + 1024;                        // 6553600
    __hip_bfloat16* XBc  = A2c + 6553600;                      // 131072
    __hip_bfloat16* WPK3 = XBc + 131072;                       // 589824

    pack_all<<<dim3(2628), dim3(256), 0, stream>>>(w1, w2, w3, mw1, mb1, mw2, mw3,
                                                   WPK1, WPK2, WPK3, WPM1, WPM2, WPM3);
    conv1_fused<<<dim3(896), dim3(256), 0, stream>>>(images, WPK1, b1, A1c);
    conv2_mfma<<<dim3(896), dim3(128), 0, stream>>>(A1c, WPK2, b2, A2c);
    mean_kernel<<<dim3(64), dim3(256), 0, stream>>>(A2c, XBc);
    conv3_mfma<<<dim3(8, 32), dim3(128), 0, stream>>>(XBc, WPK3, b3, VOLc);
    mlp_render<<<dim3(1024), dim3(256), 0, stream>>>(VOLc, rays, WPM1, WPM2, WPM3, mb2, mb3, out);
}